// Round 1
// baseline (3079.724 us; speedup 1.0000x reference)
//
#include <hip/hip_runtime.h>
#include <hip/hip_bf16.h>
#include <math.h>

#define BB 2
#define TT 2048
#define EE 2048
#define HH 16
#define DD 128
#define CC 2048
#define KCONV 4
#define CHUNK 128
#define NC 16          // TT / CHUNK
#define GN_EPS 1e-5f

// ---------------------------------------------------------------------------
// GEMM (NT: C[m,n] = sum_k A[m,k]*B[n,k]) with fused causal dwconv + silu.
// Each block computes 64 pre-activation rows (t0-3 .. t0+60) x 64 cols and
// emits 61 conv+silu output rows (t0 .. t0+60). Grid: (C/64, ceil(T/61), B).
// ---------------------------------------------------------------------------
__global__ __launch_bounds__(256)
void gemm_conv_silu(const float* __restrict__ x, const float* __restrict__ W,
                    const float* __restrict__ wconv, float* __restrict__ out,
                    float scale)
{
  const int b = blockIdx.z;
  const int t0 = blockIdx.y * 61;
  const int n0 = blockIdx.x * 64;
  const int tid = threadIdx.x;
  const int ty = tid >> 4, tx = tid & 15;

  __shared__ float As[16][64];   // [k][row], K-major for float4 compute reads
  __shared__ float Bs[16][64];
  __shared__ float pre[64][65];
  __shared__ float wsh[64][4];

  float acc[4][4] = {};

  const int arow = tid >> 2;          // 0..63
  const int ak = (tid & 3) * 4;       // 0,4,8,12
  const int at = t0 - 3 + arow;
  const bool avalid = (at >= 0 && at < TT);
  const float* aptr = x + ((size_t)b * TT + (avalid ? at : 0)) * EE + ak;
  const float* bptr = W + (size_t)(n0 + arow) * EE + ak;

  for (int k0 = 0; k0 < EE; k0 += 16) {
    float4 a4 = make_float4(0.f, 0.f, 0.f, 0.f);
    if (avalid) a4 = *(const float4*)(aptr + k0);
    const float4 b4 = *(const float4*)(bptr + k0);
    __syncthreads();
    As[ak + 0][arow] = a4.x; As[ak + 1][arow] = a4.y;
    As[ak + 2][arow] = a4.z; As[ak + 3][arow] = a4.w;
    Bs[ak + 0][arow] = b4.x; Bs[ak + 1][arow] = b4.y;
    Bs[ak + 2][arow] = b4.z; Bs[ak + 3][arow] = b4.w;
    __syncthreads();
#pragma unroll
    for (int kk = 0; kk < 16; ++kk) {
      float aa[4], bb[4];
      *(float4*)&aa[0] = *(const float4*)&As[kk][ty * 4];
      *(float4*)&bb[0] = *(const float4*)&Bs[kk][tx * 4];
#pragma unroll
      for (int i = 0; i < 4; ++i)
#pragma unroll
        for (int j = 0; j < 4; ++j)
          acc[i][j] = fmaf(aa[i], bb[j], acc[i][j]);
    }
  }

  __syncthreads();
#pragma unroll
  for (int i = 0; i < 4; ++i)
#pragma unroll
    for (int j = 0; j < 4; ++j)
      pre[ty * 4 + i][tx * 4 + j] = acc[i][j];
  wsh[tid >> 2][tid & 3] = wconv[(size_t)(n0 + (tid >> 2)) * KCONV + (tid & 3)];
  __syncthreads();

  for (int idx = tid; idx < 61 * 64; idx += 256) {
    const int r = idx >> 6;        // 0..60
    const int cc = idx & 63;
    const int t = t0 + r;
    if (t < TT) {
      // output t uses pre rows r..r+3 == times t-3..t ; w[j] * u[t-3+j]
      float v = wsh[cc][0] * pre[r][cc] + wsh[cc][1] * pre[r + 1][cc]
              + wsh[cc][2] * pre[r + 2][cc] + wsh[cc][3] * pre[r + 3][cc];
      const float s = v / (1.f + expf(-v));   // silu
      out[((size_t)b * TT + t) * CC + n0 + cc] = s * scale;
    }
  }
}

// ---------------------------------------------------------------------------
// Generic GEMM NT: C[m,n] = act(sum_k A[m,k]*B[n,k]); ldc = N.
// ACT: 0 = none, 1 = sigmoid. M must be a multiple of 64, K of 16.
// ---------------------------------------------------------------------------
template <int ACT>
__global__ __launch_bounds__(256)
void gemm_nt(const float* __restrict__ A, const float* __restrict__ Bm,
             float* __restrict__ Cm, int M, int N, int Kd)
{
  const int m0 = blockIdx.y * 64;
  const int n0 = blockIdx.x * 64;
  const int tid = threadIdx.x;
  const int ty = tid >> 4, tx = tid & 15;

  __shared__ float As[16][64];
  __shared__ float Bs[16][64];

  float acc[4][4] = {};

  const int arow = tid >> 2;
  const int ak = (tid & 3) * 4;
  const float* aptr = A + (size_t)(m0 + arow) * Kd + ak;
  const int brow = n0 + arow;
  const bool bvalid = brow < N;
  const float* bptr = Bm + (size_t)(bvalid ? brow : 0) * Kd + ak;

  for (int k0 = 0; k0 < Kd; k0 += 16) {
    const float4 a4 = *(const float4*)(aptr + k0);
    float4 b4 = make_float4(0.f, 0.f, 0.f, 0.f);
    if (bvalid) b4 = *(const float4*)(bptr + k0);
    __syncthreads();
    As[ak + 0][arow] = a4.x; As[ak + 1][arow] = a4.y;
    As[ak + 2][arow] = a4.z; As[ak + 3][arow] = a4.w;
    Bs[ak + 0][arow] = b4.x; Bs[ak + 1][arow] = b4.y;
    Bs[ak + 2][arow] = b4.z; Bs[ak + 3][arow] = b4.w;
    __syncthreads();
#pragma unroll
    for (int kk = 0; kk < 16; ++kk) {
      float aa[4], bb[4];
      *(float4*)&aa[0] = *(const float4*)&As[kk][ty * 4];
      *(float4*)&bb[0] = *(const float4*)&Bs[kk][tx * 4];
#pragma unroll
      for (int i = 0; i < 4; ++i)
#pragma unroll
        for (int j = 0; j < 4; ++j)
          acc[i][j] = fmaf(aa[i], bb[j], acc[i][j]);
    }
  }

#pragma unroll
  for (int i = 0; i < 4; ++i) {
    const int m = m0 + ty * 4 + i;
#pragma unroll
    for (int j = 0; j < 4; ++j) {
      const int n = n0 + tx * 4 + j;
      if (n < N) {
        float v = acc[i][j];
        if (ACT == 1) v = 1.f / (1.f + expf(-v));
        Cm[(size_t)m * N + n] = v;
      }
    }
  }
}

// ---------------------------------------------------------------------------
// Phase A: per-chunk contribution  contrib[d][e] = sum_s b_s e^{Lend-Lc_s} k_s[d] v_s[e]
// and chunk decay = e^{Lend}. Grid: (NC, H, B), 256 threads.
// ---------------------------------------------------------------------------
__global__ __launch_bounds__(256)
void phaseA(const float* __restrict__ kbuf, const float* __restrict__ vbuf,
            const float* __restrict__ beta, float* __restrict__ contrib,
            float* __restrict__ decay)
{
  const int c = blockIdx.x, h = blockIdx.y, b = blockIdx.z;
  const int tid = threadIdx.x;
  const int ty = tid >> 4, tx = tid & 15;

  __shared__ float lc[CHUNK], bsh[CHUNK], wgt[CHUNK];
  __shared__ float ks[16][128], vs[16][128];

  if (tid < CHUNK) {
    const float bv = beta[(size_t)(b * TT + c * CHUNK + tid) * HH + h];
    bsh[tid] = bv;
    lc[tid] = log1pf(-bv);
  }
  __syncthreads();
  for (int off = 1; off < CHUNK; off <<= 1) {   // Hillis-Steele inclusive scan
    float add = 0.f;
    if (tid < CHUNK && tid >= off) add = lc[tid - off];
    __syncthreads();
    if (tid < CHUNK) lc[tid] += add;
    __syncthreads();
  }
  const float lend = lc[CHUNK - 1];
  if (tid < CHUNK) wgt[tid] = bsh[tid] * expf(lend - lc[tid]);
  if (tid == 0) decay[(size_t)(b * HH + h) * NC + c] = expf(lend);
  __syncthreads();

  float acc[8][8] = {};
  const int srow = tid >> 4;           // 0..15
  const int d8 = (tid & 15) * 8;
  for (int s0 = 0; s0 < CHUNK; s0 += 16) {
    const size_t base = ((size_t)(b * TT + c * CHUNK + s0 + srow)) * CC + h * DD + d8;
    const float w = wgt[s0 + srow];
    const float4 ka0 = *(const float4*)(kbuf + base);
    const float4 ka1 = *(const float4*)(kbuf + base + 4);
    const float4 va0 = *(const float4*)(vbuf + base);
    const float4 va1 = *(const float4*)(vbuf + base + 4);
    __syncthreads();
    *(float4*)&ks[srow][d8]     = make_float4(ka0.x * w, ka0.y * w, ka0.z * w, ka0.w * w);
    *(float4*)&ks[srow][d8 + 4] = make_float4(ka1.x * w, ka1.y * w, ka1.z * w, ka1.w * w);
    *(float4*)&vs[srow][d8]     = va0;
    *(float4*)&vs[srow][d8 + 4] = va1;
    __syncthreads();
#pragma unroll
    for (int ss = 0; ss < 16; ++ss) {
      float ka[8], va[8];
      *(float4*)&ka[0] = *(const float4*)&ks[ss][ty * 8];
      *(float4*)&ka[4] = *(const float4*)&ks[ss][ty * 8 + 4];
      *(float4*)&va[0] = *(const float4*)&vs[ss][tx * 8];
      *(float4*)&va[4] = *(const float4*)&vs[ss][tx * 8 + 4];
#pragma unroll
      for (int i = 0; i < 8; ++i)
#pragma unroll
        for (int j = 0; j < 8; ++j)
          acc[i][j] = fmaf(ka[i], va[j], acc[i][j]);
    }
  }
  float* cp = contrib + ((size_t)((b * HH + h) * NC + c)) * DD * DD;
#pragma unroll
  for (int i = 0; i < 8; ++i)
#pragma unroll
    for (int j = 0; j < 8; ++j)
      cp[(size_t)(ty * 8 + i) * DD + tx * 8 + j] = acc[i][j];
}

// ---------------------------------------------------------------------------
// Phase B: inter-chunk state recurrence, elementwise-parallel.
// states[bh][c] = state at START of chunk c;  s' = decay_c*s + contrib_c.
// ---------------------------------------------------------------------------
__global__ __launch_bounds__(256)
void phaseB(const float* __restrict__ state0, const float* __restrict__ contrib,
            const float* __restrict__ decay, float* __restrict__ states,
            float* __restrict__ stateOut)
{
  const size_t gid = (size_t)blockIdx.x * 256 + threadIdx.x;  // < B*H*D*D
  const int bh = (int)(gid >> 14);
  const int de = (int)(gid & 16383);
  float s = state0[gid];
  const float* dc = decay + (size_t)bh * NC;
#pragma unroll
  for (int c = 0; c < NC; ++c) {
    const size_t off = ((size_t)bh * NC + c) * (DD * DD) + de;
    states[off] = s;
    s = fmaf(dc[c], s, contrib[off]);
  }
  stateOut[gid] = s;
}

// ---------------------------------------------------------------------------
// Phase C: per-chunk output
//   P[t][s] = (q_t . k_s) * b_s * e^{Lc_t - Lc_s}  (s<=t), 0 otherwise
//   o[t][e] = sum_s P[t][s] v_s[e] + e^{Lc_t} sum_d q_t[d] S0[d][e]
// Grid: (NC, H, B), 256 threads. att layout = (B,T,H,D) contiguous.
// ---------------------------------------------------------------------------
__global__ __launch_bounds__(256)
void phaseC(const float* __restrict__ qbuf, const float* __restrict__ kbuf,
            const float* __restrict__ vbuf, const float* __restrict__ beta,
            const float* __restrict__ states, float* __restrict__ att)
{
  const int c = blockIdx.x, h = blockIdx.y, b = blockIdx.z;
  const int tid = threadIdx.x;
  const int ty = tid >> 4, tx = tid & 15;

  __shared__ float lc[CHUNK], bsh[CHUNK];
  __shared__ float sa[16][128], sb[16][128];
  __shared__ float Pm[CHUNK][CHUNK + 1];

  if (tid < CHUNK) {
    const float bv = beta[(size_t)(b * TT + c * CHUNK + tid) * HH + h];
    bsh[tid] = bv;
    lc[tid] = log1pf(-bv);
  }
  __syncthreads();
  for (int off = 1; off < CHUNK; off <<= 1) {
    float add = 0.f;
    if (tid < CHUNK && tid >= off) add = lc[tid - off];
    __syncthreads();
    if (tid < CHUNK) lc[tid] += add;
    __syncthreads();
  }
  __syncthreads();

  // ---- scores: acc[i][j] = q[t=ty*8+i] . k[s=tx*8+j]
  float acc[8][8] = {};
  const int strow = tid >> 1;          // 0..127 (t or s index for staging)
  const int sd8 = (tid & 1) * 8;       // which 8 of the 16 d's
  for (int d0 = 0; d0 < DD; d0 += 16) {
    float qa[8], kk8[8];
    const size_t base = ((size_t)(b * TT + c * CHUNK + strow)) * CC + h * DD + d0 + sd8;
    *(float4*)&qa[0]  = *(const float4*)(qbuf + base);
    *(float4*)&qa[4]  = *(const float4*)(qbuf + base + 4);
    *(float4*)&kk8[0] = *(const float4*)(kbuf + base);
    *(float4*)&kk8[4] = *(const float4*)(kbuf + base + 4);
    __syncthreads();
#pragma unroll
    for (int l = 0; l < 8; ++l) { sa[sd8 + l][strow] = qa[l]; sb[sd8 + l][strow] = kk8[l]; }
    __syncthreads();
#pragma unroll
    for (int dd = 0; dd < 16; ++dd) {
      float a8[8], b8[8];
      *(float4*)&a8[0] = *(const float4*)&sa[dd][ty * 8];
      *(float4*)&a8[4] = *(const float4*)&sa[dd][ty * 8 + 4];
      *(float4*)&b8[0] = *(const float4*)&sb[dd][tx * 8];
      *(float4*)&b8[4] = *(const float4*)&sb[dd][tx * 8 + 4];
#pragma unroll
      for (int i = 0; i < 8; ++i)
#pragma unroll
        for (int j = 0; j < 8; ++j)
          acc[i][j] = fmaf(a8[i], b8[j], acc[i][j]);
    }
  }

  // decay + causal mask -> Pm
#pragma unroll
  for (int i = 0; i < 8; ++i) {
    const int t = ty * 8 + i;
    const float lct = lc[t];
#pragma unroll
    for (int j = 0; j < 8; ++j) {
      const int s = tx * 8 + j;
      float p = 0.f;
      if (s <= t) p = acc[i][j] * bsh[s] * expf(lct - lc[s]);
      Pm[t][s] = p;
    }
  }

  // ---- o = P @ V  (contract s)
  float acc2[8][8] = {};
  const int vrow = tid >> 4;           // 0..15
  const int ve8 = (tid & 15) * 8;
  for (int s0 = 0; s0 < CHUNK; s0 += 16) {
    const size_t vbase = ((size_t)(b * TT + c * CHUNK + s0 + vrow)) * CC + h * DD + ve8;
    const float4 v0 = *(const float4*)(vbuf + vbase);
    const float4 v1 = *(const float4*)(vbuf + vbase + 4);
    __syncthreads();
    *(float4*)&sa[vrow][ve8]     = v0;
    *(float4*)&sa[vrow][ve8 + 4] = v1;
    __syncthreads();
#pragma unroll
    for (int ss = 0; ss < 16; ++ss) {
      float pv[8], vv[8];
#pragma unroll
      for (int i = 0; i < 8; ++i) pv[i] = Pm[ty * 8 + i][s0 + ss];
      *(float4*)&vv[0] = *(const float4*)&sa[ss][tx * 8];
      *(float4*)&vv[4] = *(const float4*)&sa[ss][tx * 8 + 4];
#pragma unroll
      for (int i = 0; i < 8; ++i)
#pragma unroll
        for (int j = 0; j < 8; ++j)
          acc2[i][j] = fmaf(pv[i], vv[j], acc2[i][j]);
    }
  }

  // ---- o += diag(e^{Lc}) Q @ S0  (contract d)
  for (int d0 = 0; d0 < DD; d0 += 16) {
    float qa[8];
    const size_t qbase = ((size_t)(b * TT + c * CHUNK + strow)) * CC + h * DD + d0 + sd8;
    *(float4*)&qa[0] = *(const float4*)(qbuf + qbase);
    *(float4*)&qa[4] = *(const float4*)(qbuf + qbase + 4);
    const float sc = expf(lc[strow]);
    const size_t sbase = ((size_t)((b * HH + h) * NC + c)) * (DD * DD) + (size_t)(d0 + vrow) * DD + ve8;
    const float4 st0 = *(const float4*)(states + sbase);
    const float4 st1 = *(const float4*)(states + sbase + 4);
    __syncthreads();
#pragma unroll
    for (int l = 0; l < 8; ++l) sa[sd8 + l][strow] = qa[l] * sc;
    *(float4*)&sb[vrow][ve8]     = st0;
    *(float4*)&sb[vrow][ve8 + 4] = st1;
    __syncthreads();
#pragma unroll
    for (int dd = 0; dd < 16; ++dd) {
      float a8[8], b8[8];
      *(float4*)&a8[0] = *(const float4*)&sa[dd][ty * 8];
      *(float4*)&a8[4] = *(const float4*)&sa[dd][ty * 8 + 4];
      *(float4*)&b8[0] = *(const float4*)&sb[dd][tx * 8];
      *(float4*)&b8[4] = *(const float4*)&sb[dd][tx * 8 + 4];
#pragma unroll
      for (int i = 0; i < 8; ++i)
#pragma unroll
        for (int j = 0; j < 8; ++j)
          acc2[i][j] = fmaf(a8[i], b8[j], acc2[i][j]);
    }
  }

  // store att (B,T,H,D)
#pragma unroll
  for (int i = 0; i < 8; ++i) {
    const int t = ty * 8 + i;
    const size_t obase = ((size_t)(b * TT + c * CHUNK + t)) * CC + h * DD + tx * 8;
    *(float4*)(att + obase)     = make_float4(acc2[i][0], acc2[i][1], acc2[i][2], acc2[i][3]);
    *(float4*)(att + obase + 4) = make_float4(acc2[i][4], acc2[i][5], acc2[i][6], acc2[i][7]);
  }
}

// ---------------------------------------------------------------------------
// GroupNorm stats per (b,h) over (T,D). Grid: 32 blocks.
// ---------------------------------------------------------------------------
__global__ __launch_bounds__(256)
void gn_stats(const float* __restrict__ att, float* __restrict__ stats)
{
  const int bh = blockIdx.x;
  const int b = bh >> 4, h = bh & 15;
  const int tid = threadIdx.x;
  float sum = 0.f, sq = 0.f;
  for (int idx = tid; idx < TT * DD / 4; idx += 256) {
    const int t = idx / (DD / 4);
    const int e4 = (idx % (DD / 4)) * 4;
    const float4 v = *(const float4*)(att + ((size_t)(b * TT + t)) * CC + h * DD + e4);
    sum += v.x + v.y + v.z + v.w;
    sq += v.x * v.x + v.y * v.y + v.z * v.z + v.w * v.w;
  }
  __shared__ float s1[256], s2[256];
  s1[tid] = sum; s2[tid] = sq;
  __syncthreads();
  for (int off = 128; off; off >>= 1) {
    if (tid < off) { s1[tid] += s1[tid + off]; s2[tid] += s2[tid + off]; }
    __syncthreads();
  }
  if (tid == 0) {
    const float n = (float)(TT * DD);
    const float mean = s1[0] / n;
    const float var = s2[0] / n - mean * mean;
    stats[bh * 2] = mean;
    stats[bh * 2 + 1] = rsqrtf(var + GN_EPS);
  }
}

// ---------------------------------------------------------------------------
// normalize + gate: g = (att - mean)*rstd * gate. Elementwise float4.
// ---------------------------------------------------------------------------
__global__ __launch_bounds__(256)
void norm_gate(const float* __restrict__ att, const float* __restrict__ gate,
               const float* __restrict__ stats, float* __restrict__ g)
{
  const size_t gid = ((size_t)blockIdx.x * 256 + threadIdx.x) * 4;
  if (gid >= (size_t)BB * TT * CC) return;
  const int cpos = (int)(gid % CC);
  const int b = (int)(gid / ((size_t)TT * CC));
  const int bh = b * HH + (cpos >> 7);
  const float mean = stats[bh * 2], rstd = stats[bh * 2 + 1];
  const float4 a = *(const float4*)(att + gid);
  const float4 gt = *(const float4*)(gate + gid);
  float4 o;
  o.x = (a.x - mean) * rstd * gt.x;
  o.y = (a.y - mean) * rstd * gt.y;
  o.z = (a.z - mean) * rstd * gt.z;
  o.w = (a.w - mean) * rstd * gt.w;
  *(float4*)(g + gid) = o;
}

// ---------------------------------------------------------------------------
extern "C" void kernel_launch(void* const* d_in, const int* in_sizes, int n_in,
                              void* d_out, int out_size, void* d_ws, size_t ws_size,
                              hipStream_t stream)
{
  const float* x      = (const float*)d_in[0];
  const float* st0    = (const float*)d_in[1];
  const float* Wq     = (const float*)d_in[2];
  const float* Wk     = (const float*)d_in[3];
  const float* Wv     = (const float*)d_in[4];
  const float* Wbeta  = (const float*)d_in[5];
  const float* Wgate  = (const float*)d_in[6];
  const float* Wo     = (const float*)d_in[7];
  const float* wqc    = (const float*)d_in[8];
  const float* wkc    = (const float*)d_in[9];
  const float* wvc    = (const float*)d_in[10];

  float* ws = (float*)d_ws;
  float* q      = ws;                       // 8388608
  float* k      = ws + 8388608;             // 8388608
  float* v      = ws + 16777216;            // 8388608
  float* betab  = ws + 25165824;            // 65536
  float* decay  = ws + 25231360;            // 512
  float* stats  = ws + 25231872;            // 64
  float* contrib= ws + 25231936;            // 8388608
  float* states = ws + 33620544;            // 8388608  (total 42009152 floats)

  float* y_out  = (float*)d_out;            // (B,T,E) — also used as att scratch
  float* st_out = (float*)d_out + (size_t)BB * TT * EE;

  const dim3 blk(256);
  const dim3 g_conv(CC / 64, (TT + 60) / 61, BB);   // 32 x 34 x 2
  const float qscale = 0.08838834764831845f;        // D^-0.5

  // projections with fused conv+silu
  gemm_conv_silu<<<g_conv, blk, 0, stream>>>(x, Wq, wqc, q, qscale);
  gemm_conv_silu<<<g_conv, blk, 0, stream>>>(x, Wk, wkc, k, 1.f);
  gemm_conv_silu<<<g_conv, blk, 0, stream>>>(x, Wv, wvc, v, 1.f);

  // beta = sigmoid(x @ Wbeta^T), (B*T,16)
  gemm_nt<1><<<dim3(1, (BB * TT) / 64), blk, 0, stream>>>(x, Wbeta, betab, BB * TT, HH, EE);

  // chunked delta scan
  phaseA<<<dim3(NC, HH, BB), blk, 0, stream>>>(k, v, betab, contrib, decay);
  phaseB<<<dim3((BB * HH * DD * DD) / 256), blk, 0, stream>>>(st0, contrib, decay, states, st_out);
  phaseC<<<dim3(NC, HH, BB), blk, 0, stream>>>(q, k, v, betab, states, y_out /*att*/);

  // gate = sigmoid(x @ Wgate^T) — k buffer is dead now, reuse it
  float* gatebuf = k;
  gemm_nt<1><<<dim3(CC / 64, (BB * TT) / 64), blk, 0, stream>>>(x, Wgate, gatebuf, BB * TT, CC, EE);

  // groupnorm stats + normalize*gate (in place into gatebuf)
  gn_stats<<<dim3(BB * HH), blk, 0, stream>>>(y_out, stats);
  norm_gate<<<dim3((BB * TT * CC) / (256 * 4)), blk, 0, stream>>>(y_out, gatebuf, stats, gatebuf);

  // y = g @ Wo^T (overwrites att region; att no longer read)
  gemm_nt<0><<<dim3(EE / 64, (BB * TT) / 64), blk, 0, stream>>>(gatebuf, Wo, y_out, BB * TT, EE, CC);
}

// Round 2
// 818.926 us; speedup vs baseline: 3.7607x; 3.7607x over previous
//
#include <hip/hip_runtime.h>
#include <hip/hip_bf16.h>
#include <math.h>

#define BB 2
#define TT 2048
#define EE 2048
#define HH 16
#define DD 128
#define CC 2048
#define KCONV 4
#define CHUNK 128
#define NC 16          // TT / CHUNK
#define GN_EPS 1e-5f

typedef __bf16 bf16x8 __attribute__((ext_vector_type(8)));
typedef __bf16 bf16x4 __attribute__((ext_vector_type(4)));
typedef float  f32x4  __attribute__((ext_vector_type(4)));

#define GLD16(gp, lp)                                                          \
  __builtin_amdgcn_global_load_lds(                                            \
      (const __attribute__((address_space(1))) void*)(gp),                     \
      (__attribute__((address_space(3))) void*)(lp), 16, 0, 0)

// ---------------------------------------------------------------------------
// f32 -> bf16 conversion, float4-vectorized.
// ---------------------------------------------------------------------------
__global__ __launch_bounds__(256)
void f2b(const float* __restrict__ in, __bf16* __restrict__ out, int n)
{
  const int i = (blockIdx.x * 256 + threadIdx.x) * 4;
  if (i >= n) return;
  const float4 v = *(const float4*)(in + i);
  bf16x4 o;
  o[0] = (__bf16)v.x; o[1] = (__bf16)v.y; o[2] = (__bf16)v.z; o[3] = (__bf16)v.w;
  *(bf16x4*)(out + i) = o;
}

// ---------------------------------------------------------------------------
// bf16 MFMA GEMM, NT: C[m,n] = act(sum_k A[m,k]*B[n,k]).
// m97 structure: 128x128 tile, 4 waves (each 64x64), BK=32, global_load_lds.
// M,N multiples of 128; K multiple of 32. ACT: 0=none, 1=sigmoid.
// ---------------------------------------------------------------------------
template <int ACT>
__global__ __launch_bounds__(256)
void gemm_bf16(const __bf16* __restrict__ A, const __bf16* __restrict__ Bm,
               float* __restrict__ Cm, int M, int N, int K)
{
  __shared__ __attribute__((aligned(16))) __bf16 As[128 * 32];
  __shared__ __attribute__((aligned(16))) __bf16 Bs[128 * 32];

  const int tid  = threadIdx.x;
  const int w    = tid >> 6;
  const int lane = tid & 63;
  const int m0 = blockIdx.y * 128, n0 = blockIdx.x * 128;
  const int wm = w >> 1, wn = w & 1;

  // staging: wave w handles LDS issues w*2 and w*2+1 for each matrix.
  // issue covers 16 rows x 32 k (1024 B); lane l -> row l>>2, k (l&3)*8.
  const int srow = lane >> 2;
  const int sk   = (lane & 3) * 8;
  const __bf16* aA0 = A  + (size_t)(m0 + w * 32 + srow) * K + sk;
  const __bf16* aA1 = aA0 + (size_t)16 * K;
  const __bf16* aB0 = Bm + (size_t)(n0 + w * 32 + srow) * K + sk;
  const __bf16* aB1 = aB0 + (size_t)16 * K;
  __bf16* lA0 = As + (w * 2 + 0) * 512;
  __bf16* lA1 = As + (w * 2 + 1) * 512;
  __bf16* lB0 = Bs + (w * 2 + 0) * 512;
  __bf16* lB1 = Bs + (w * 2 + 1) * 512;

  // fragment read addresses
  const int fr = lane & 15;
  const int fk = (lane >> 4) * 8;
  const __bf16* rA = As + (size_t)(wm * 64 + fr) * 32 + fk;
  const __bf16* rB = Bs + (size_t)(wn * 64 + fr) * 32 + fk;

  f32x4 acc[4][4] = {};

  for (int k0 = 0; k0 < K; k0 += 32) {
    __syncthreads();
    GLD16(aA0, lA0); GLD16(aA1, lA1);
    GLD16(aB0, lB0); GLD16(aB1, lB1);
    aA0 += 32; aA1 += 32; aB0 += 32; aB1 += 32;
    asm volatile("s_waitcnt vmcnt(0)" ::: "memory");
    __syncthreads();

    bf16x8 af[4], bfr[4];
#pragma unroll
    for (int i = 0; i < 4; ++i) af[i]  = *(const bf16x8*)(rA + i * 512);
#pragma unroll
    for (int j = 0; j < 4; ++j) bfr[j] = *(const bf16x8*)(rB + j * 512);
#pragma unroll
    for (int i = 0; i < 4; ++i)
#pragma unroll
      for (int j = 0; j < 4; ++j)
        acc[i][j] = __builtin_amdgcn_mfma_f32_16x16x32_bf16(af[i], bfr[j], acc[i][j], 0, 0, 0);
  }

  // epilogue: C/D layout col=lane&15, row=(lane>>4)*4+reg
  const int crow0 = (lane >> 4) * 4;
#pragma unroll
  for (int i = 0; i < 4; ++i) {
#pragma unroll
    for (int j = 0; j < 4; ++j) {
      const int n = n0 + wn * 64 + j * 16 + fr;
#pragma unroll
      for (int r = 0; r < 4; ++r) {
        const int m = m0 + wm * 64 + i * 16 + crow0 + r;
        float vv = acc[i][j][r];
        if (ACT == 1) vv = 1.f / (1.f + expf(-vv));
        Cm[(size_t)m * N + n] = vv;
      }
    }
  }
}

// ---------------------------------------------------------------------------
// causal dwconv(K=4) + silu + scale, elementwise over (B,T,C), 4 ch/thread.
// out[b,t,c] = silu(sum_j w[c][j] * u[b,t-3+j,c]) * scale
// ---------------------------------------------------------------------------
__global__ __launch_bounds__(256)
void conv_silu(const float* __restrict__ u, const float* __restrict__ wconv,
               float* __restrict__ out, float scale)
{
  const int idx = blockIdx.x * 256 + threadIdx.x;   // over B*T*C/4
  const int c4 = (idx & (CC / 4 - 1)) * 4;
  const int t  = (idx >> 9) & (TT - 1);
  const int b  = idx >> 20;
  const size_t base = ((size_t)(b * TT + t)) * CC + c4;

  const float4 z = make_float4(0.f, 0.f, 0.f, 0.f);
  const float4 u0 = *(const float4*)(u + base);
  const float4 u1 = (t >= 1) ? *(const float4*)(u + base - CC)     : z;
  const float4 u2 = (t >= 2) ? *(const float4*)(u + base - 2 * CC) : z;
  const float4 u3 = (t >= 3) ? *(const float4*)(u + base - 3 * CC) : z;

  float4 o;
  {
    const float4 wv = *(const float4*)(wconv + (size_t)(c4 + 0) * 4);
    const float vv = wv.x * u3.x + wv.y * u2.x + wv.z * u1.x + wv.w * u0.x;
    o.x = vv / (1.f + expf(-vv)) * scale;
  }
  {
    const float4 wv = *(const float4*)(wconv + (size_t)(c4 + 1) * 4);
    const float vv = wv.x * u3.y + wv.y * u2.y + wv.z * u1.y + wv.w * u0.y;
    o.y = vv / (1.f + expf(-vv)) * scale;
  }
  {
    const float4 wv = *(const float4*)(wconv + (size_t)(c4 + 2) * 4);
    const float vv = wv.x * u3.z + wv.y * u2.z + wv.z * u1.z + wv.w * u0.z;
    o.z = vv / (1.f + expf(-vv)) * scale;
  }
  {
    const float4 wv = *(const float4*)(wconv + (size_t)(c4 + 3) * 4);
    const float vv = wv.x * u3.w + wv.y * u2.w + wv.z * u1.w + wv.w * u0.w;
    o.w = vv / (1.f + expf(-vv)) * scale;
  }
  *(float4*)(out + base) = o;
}

// ---------------------------------------------------------------------------
// fp32 GEMM NT (used only for beta: N=16). ACT: 1 = sigmoid.
// ---------------------------------------------------------------------------
template <int ACT>
__global__ __launch_bounds__(256)
void gemm_nt(const float* __restrict__ A, const float* __restrict__ Bm,
             float* __restrict__ Cm, int M, int N, int Kd)
{
  const int m0 = blockIdx.y * 64;
  const int n0 = blockIdx.x * 64;
  const int tid = threadIdx.x;
  const int ty = tid >> 4, tx = tid & 15;

  __shared__ float As[16][64];
  __shared__ float Bs[16][64];

  float acc[4][4] = {};

  const int arow = tid >> 2;
  const int ak = (tid & 3) * 4;
  const float* aptr = A + (size_t)(m0 + arow) * Kd + ak;
  const int brow = n0 + arow;
  const bool bvalid = brow < N;
  const float* bptr = Bm + (size_t)(bvalid ? brow : 0) * Kd + ak;

  for (int k0 = 0; k0 < Kd; k0 += 16) {
    const float4 a4 = *(const float4*)(aptr + k0);
    float4 b4 = make_float4(0.f, 0.f, 0.f, 0.f);
    if (bvalid) b4 = *(const float4*)(bptr + k0);
    __syncthreads();
    As[ak + 0][arow] = a4.x; As[ak + 1][arow] = a4.y;
    As[ak + 2][arow] = a4.z; As[ak + 3][arow] = a4.w;
    Bs[ak + 0][arow] = b4.x; Bs[ak + 1][arow] = b4.y;
    Bs[ak + 2][arow] = b4.z; Bs[ak + 3][arow] = b4.w;
    __syncthreads();
#pragma unroll
    for (int kk = 0; kk < 16; ++kk) {
      float aa[4], bb[4];
      *(float4*)&aa[0] = *(const float4*)&As[kk][ty * 4];
      *(float4*)&bb[0] = *(const float4*)&Bs[kk][tx * 4];
#pragma unroll
      for (int i = 0; i < 4; ++i)
#pragma unroll
        for (int j = 0; j < 4; ++j)
          acc[i][j] = fmaf(aa[i], bb[j], acc[i][j]);
    }
  }

#pragma unroll
  for (int i = 0; i < 4; ++i) {
    const int m = m0 + ty * 4 + i;
#pragma unroll
    for (int j = 0; j < 4; ++j) {
      const int n = n0 + tx * 4 + j;
      if (n < N) {
        float v = acc[i][j];
        if (ACT == 1) v = 1.f / (1.f + expf(-v));
        Cm[(size_t)m * N + n] = v;
      }
    }
  }
}

// ---------------------------------------------------------------------------
// Phase A: per-chunk contribution  contrib[d][e] = sum_s b_s e^{Lend-Lc_s} k_s[d] v_s[e]
// ---------------------------------------------------------------------------
__global__ __launch_bounds__(256)
void phaseA(const float* __restrict__ kbuf, const float* __restrict__ vbuf,
            const float* __restrict__ beta, float* __restrict__ contrib,
            float* __restrict__ decay)
{
  const int c = blockIdx.x, h = blockIdx.y, b = blockIdx.z;
  const int tid = threadIdx.x;
  const int ty = tid >> 4, tx = tid & 15;

  __shared__ float lc[CHUNK], bsh[CHUNK], wgt[CHUNK];
  __shared__ float ks[16][128], vs[16][128];

  if (tid < CHUNK) {
    const float bv = beta[(size_t)(b * TT + c * CHUNK + tid) * HH + h];
    bsh[tid] = bv;
    lc[tid] = log1pf(-bv);
  }
  __syncthreads();
  for (int off = 1; off < CHUNK; off <<= 1) {
    float add = 0.f;
    if (tid < CHUNK && tid >= off) add = lc[tid - off];
    __syncthreads();
    if (tid < CHUNK) lc[tid] += add;
    __syncthreads();
  }
  const float lend = lc[CHUNK - 1];
  if (tid < CHUNK) wgt[tid] = bsh[tid] * expf(lend - lc[tid]);
  if (tid == 0) decay[(size_t)(b * HH + h) * NC + c] = expf(lend);
  __syncthreads();

  float acc[8][8] = {};
  const int srow = tid >> 4;
  const int d8 = (tid & 15) * 8;
  for (int s0 = 0; s0 < CHUNK; s0 += 16) {
    const size_t base = ((size_t)(b * TT + c * CHUNK + s0 + srow)) * CC + h * DD + d8;
    const float w = wgt[s0 + srow];
    const float4 ka0 = *(const float4*)(kbuf + base);
    const float4 ka1 = *(const float4*)(kbuf + base + 4);
    const float4 va0 = *(const float4*)(vbuf + base);
    const float4 va1 = *(const float4*)(vbuf + base + 4);
    __syncthreads();
    *(float4*)&ks[srow][d8]     = make_float4(ka0.x * w, ka0.y * w, ka0.z * w, ka0.w * w);
    *(float4*)&ks[srow][d8 + 4] = make_float4(ka1.x * w, ka1.y * w, ka1.z * w, ka1.w * w);
    *(float4*)&vs[srow][d8]     = va0;
    *(float4*)&vs[srow][d8 + 4] = va1;
    __syncthreads();
#pragma unroll
    for (int ss = 0; ss < 16; ++ss) {
      float ka[8], va[8];
      *(float4*)&ka[0] = *(const float4*)&ks[ss][ty * 8];
      *(float4*)&ka[4] = *(const float4*)&ks[ss][ty * 8 + 4];
      *(float4*)&va[0] = *(const float4*)&vs[ss][tx * 8];
      *(float4*)&va[4] = *(const float4*)&vs[ss][tx * 8 + 4];
#pragma unroll
      for (int i = 0; i < 8; ++i)
#pragma unroll
        for (int j = 0; j < 8; ++j)
          acc[i][j] = fmaf(ka[i], va[j], acc[i][j]);
    }
  }
  float* cp = contrib + ((size_t)((b * HH + h) * NC + c)) * DD * DD;
#pragma unroll
  for (int i = 0; i < 8; ++i)
#pragma unroll
    for (int j = 0; j < 8; ++j)
      cp[(size_t)(ty * 8 + i) * DD + tx * 8 + j] = acc[i][j];
}

// ---------------------------------------------------------------------------
// Phase B: inter-chunk state recurrence, elementwise-parallel.
// ---------------------------------------------------------------------------
__global__ __launch_bounds__(256)
void phaseB(const float* __restrict__ state0, const float* __restrict__ contrib,
            const float* __restrict__ decay, float* __restrict__ states,
            float* __restrict__ stateOut)
{
  const size_t gid = (size_t)blockIdx.x * 256 + threadIdx.x;
  const int bh = (int)(gid >> 14);
  const int de = (int)(gid & 16383);
  float s = state0[gid];
  const float* dc = decay + (size_t)bh * NC;
#pragma unroll
  for (int c = 0; c < NC; ++c) {
    const size_t off = ((size_t)bh * NC + c) * (DD * DD) + de;
    states[off] = s;
    s = fmaf(dc[c], s, contrib[off]);
  }
  stateOut[gid] = s;
}

// ---------------------------------------------------------------------------
// Phase C: per-chunk output.
// ---------------------------------------------------------------------------
__global__ __launch_bounds__(256)
void phaseC(const float* __restrict__ qbuf, const float* __restrict__ kbuf,
            const float* __restrict__ vbuf, const float* __restrict__ beta,
            const float* __restrict__ states, float* __restrict__ att)
{
  const int c = blockIdx.x, h = blockIdx.y, b = blockIdx.z;
  const int tid = threadIdx.x;
  const int ty = tid >> 4, tx = tid & 15;

  __shared__ float lc[CHUNK], bsh[CHUNK];
  __shared__ float sa[16][128], sb[16][128];
  __shared__ float Pm[CHUNK][CHUNK + 1];

  if (tid < CHUNK) {
    const float bv = beta[(size_t)(b * TT + c * CHUNK + tid) * HH + h];
    bsh[tid] = bv;
    lc[tid] = log1pf(-bv);
  }
  __syncthreads();
  for (int off = 1; off < CHUNK; off <<= 1) {
    float add = 0.f;
    if (tid < CHUNK && tid >= off) add = lc[tid - off];
    __syncthreads();
    if (tid < CHUNK) lc[tid] += add;
    __syncthreads();
  }
  __syncthreads();

  float acc[8][8] = {};
  const int strow = tid >> 1;
  const int sd8 = (tid & 1) * 8;
  for (int d0 = 0; d0 < DD; d0 += 16) {
    float qa[8], kk8[8];
    const size_t base = ((size_t)(b * TT + c * CHUNK + strow)) * CC + h * DD + d0 + sd8;
    *(float4*)&qa[0]  = *(const float4*)(qbuf + base);
    *(float4*)&qa[4]  = *(const float4*)(qbuf + base + 4);
    *(float4*)&kk8[0] = *(const float4*)(kbuf + base);
    *(float4*)&kk8[4] = *(const float4*)(kbuf + base + 4);
    __syncthreads();
#pragma unroll
    for (int l = 0; l < 8; ++l) { sa[sd8 + l][strow] = qa[l]; sb[sd8 + l][strow] = kk8[l]; }
    __syncthreads();
#pragma unroll
    for (int dd = 0; dd < 16; ++dd) {
      float a8[8], b8[8];
      *(float4*)&a8[0] = *(const float4*)&sa[dd][ty * 8];
      *(float4*)&a8[4] = *(const float4*)&sa[dd][ty * 8 + 4];
      *(float4*)&b8[0] = *(const float4*)&sb[dd][tx * 8];
      *(float4*)&b8[4] = *(const float4*)&sb[dd][tx * 8 + 4];
#pragma unroll
      for (int i = 0; i < 8; ++i)
#pragma unroll
        for (int j = 0; j < 8; ++j)
          acc[i][j] = fmaf(a8[i], b8[j], acc[i][j]);
    }
  }

#pragma unroll
  for (int i = 0; i < 8; ++i) {
    const int t = ty * 8 + i;
    const float lct = lc[t];
#pragma unroll
    for (int j = 0; j < 8; ++j) {
      const int s = tx * 8 + j;
      float p = 0.f;
      if (s <= t) p = acc[i][j] * bsh[s] * expf(lct - lc[s]);
      Pm[t][s] = p;
    }
  }

  float acc2[8][8] = {};
  const int vrow = tid >> 4;
  const int ve8 = (tid & 15) * 8;
  for (int s0 = 0; s0 < CHUNK; s0 += 16) {
    const size_t vbase = ((size_t)(b * TT + c * CHUNK + s0 + vrow)) * CC + h * DD + ve8;
    const float4 v0 = *(const float4*)(vbuf + vbase);
    const float4 v1 = *(const float4*)(vbuf + vbase + 4);
    __syncthreads();
    *(float4*)&sa[vrow][ve8]     = v0;
    *(float4*)&sa[vrow][ve8 + 4] = v1;
    __syncthreads();
#pragma unroll
    for (int ss = 0; ss < 16; ++ss) {
      float pv[8], vv[8];
#pragma unroll
      for (int i = 0; i < 8; ++i) pv[i] = Pm[ty * 8 + i][s0 + ss];
      *(float4*)&vv[0] = *(const float4*)&sa[ss][tx * 8];
      *(float4*)&vv[4] = *(const float4*)&sa[ss][tx * 8 + 4];
#pragma unroll
      for (int i = 0; i < 8; ++i)
#pragma unroll
        for (int j = 0; j < 8; ++j)
          acc2[i][j] = fmaf(pv[i], vv[j], acc2[i][j]);
    }
  }

  for (int d0 = 0; d0 < DD; d0 += 16) {
    float qa[8];
    const size_t qbase = ((size_t)(b * TT + c * CHUNK + strow)) * CC + h * DD + d0 + sd8;
    *(float4*)&qa[0] = *(const float4*)(qbuf + qbase);
    *(float4*)&qa[4] = *(const float4*)(qbuf + qbase + 4);
    const float sc = expf(lc[strow]);
    const size_t sbase = ((size_t)((b * HH + h) * NC + c)) * (DD * DD) + (size_t)(d0 + vrow) * DD + ve8;
    const float4 st0 = *(const float4*)(states + sbase);
    const float4 st1 = *(const float4*)(states + sbase + 4);
    __syncthreads();
#pragma unroll
    for (int l = 0; l < 8; ++l) sa[sd8 + l][strow] = qa[l] * sc;
    *(float4*)&sb[vrow][ve8]     = st0;
    *(float4*)&sb[vrow][ve8 + 4] = st1;
    __syncthreads();
#pragma unroll
    for (int dd = 0; dd < 16; ++dd) {
      float a8[8], b8[8];
      *(float4*)&a8[0] = *(const float4*)&sa[dd][ty * 8];
      *(float4*)&a8[4] = *(const float4*)&sa[dd][ty * 8 + 4];
      *(float4*)&b8[0] = *(const float4*)&sb[dd][tx * 8];
      *(float4*)&b8[4] = *(const float4*)&sb[dd][tx * 8 + 4];
#pragma unroll
      for (int i = 0; i < 8; ++i)
#pragma unroll
        for (int j = 0; j < 8; ++j)
          acc2[i][j] = fmaf(a8[i], b8[j], acc2[i][j]);
    }
  }

#pragma unroll
  for (int i = 0; i < 8; ++i) {
    const int t = ty * 8 + i;
    const size_t obase = ((size_t)(b * TT + c * CHUNK + t)) * CC + h * DD + tx * 8;
    *(float4*)(att + obase)     = make_float4(acc2[i][0], acc2[i][1], acc2[i][2], acc2[i][3]);
    *(float4*)(att + obase + 4) = make_float4(acc2[i][4], acc2[i][5], acc2[i][6], acc2[i][7]);
  }
}

// ---------------------------------------------------------------------------
// GroupNorm stats per (b,h) over (T,D).
// ---------------------------------------------------------------------------
__global__ __launch_bounds__(256)
void gn_stats(const float* __restrict__ att, float* __restrict__ stats)
{
  const int bh = blockIdx.x;
  const int b = bh >> 4, h = bh & 15;
  const int tid = threadIdx.x;
  float sum = 0.f, sq = 0.f;
  for (int idx = tid; idx < TT * DD / 4; idx += 256) {
    const int t = idx / (DD / 4);
    const int e4 = (idx % (DD / 4)) * 4;
    const float4 v = *(const float4*)(att + ((size_t)(b * TT + t)) * CC + h * DD + e4);
    sum += v.x + v.y + v.z + v.w;
    sq += v.x * v.x + v.y * v.y + v.z * v.z + v.w * v.w;
  }
  __shared__ float s1[256], s2[256];
  s1[tid] = sum; s2[tid] = sq;
  __syncthreads();
  for (int off = 128; off; off >>= 1) {
    if (tid < off) { s1[tid] += s1[tid + off]; s2[tid] += s2[tid + off]; }
    __syncthreads();
  }
  if (tid == 0) {
    const float n = (float)(TT * DD);
    const float mean = s1[0] / n;
    const float var = s2[0] / n - mean * mean;
    stats[bh * 2] = mean;
    stats[bh * 2 + 1] = rsqrtf(var + GN_EPS);
  }
}

// ---------------------------------------------------------------------------
// normalize + gate -> bf16 for the final MFMA GEMM.
// ---------------------------------------------------------------------------
__global__ __launch_bounds__(256)
void norm_gate(const float* __restrict__ att, const float* __restrict__ gate,
               const float* __restrict__ stats, __bf16* __restrict__ g)
{
  const size_t gid = ((size_t)blockIdx.x * 256 + threadIdx.x) * 4;
  if (gid >= (size_t)BB * TT * CC) return;
  const int cpos = (int)(gid % CC);
  const int b = (int)(gid / ((size_t)TT * CC));
  const int bh = b * HH + (cpos >> 7);
  const float mean = stats[bh * 2], rstd = stats[bh * 2 + 1];
  const float4 a = *(const float4*)(att + gid);
  const float4 gt = *(const float4*)(gate + gid);
  bf16x4 o;
  o[0] = (__bf16)((a.x - mean) * rstd * gt.x);
  o[1] = (__bf16)((a.y - mean) * rstd * gt.y);
  o[2] = (__bf16)((a.z - mean) * rstd * gt.z);
  o[3] = (__bf16)((a.w - mean) * rstd * gt.w);
  *(bf16x4*)(g + gid) = o;
}

// ---------------------------------------------------------------------------
extern "C" void kernel_launch(void* const* d_in, const int* in_sizes, int n_in,
                              void* d_out, int out_size, void* d_ws, size_t ws_size,
                              hipStream_t stream)
{
  const float* x      = (const float*)d_in[0];
  const float* st0    = (const float*)d_in[1];
  const float* Wq     = (const float*)d_in[2];
  const float* Wk     = (const float*)d_in[3];
  const float* Wv     = (const float*)d_in[4];
  const float* Wbeta  = (const float*)d_in[5];
  const float* Wgate  = (const float*)d_in[6];
  const float* Wo     = (const float*)d_in[7];
  const float* wqc    = (const float*)d_in[8];
  const float* wkc    = (const float*)d_in[9];
  const float* wvc    = (const float*)d_in[10];

  float* ws = (float*)d_ws;
  // fp32 buffers
  float* q      = ws;                       // 8388608
  float* k      = ws + 8388608;             // 8388608
  float* v      = ws + 16777216;            // 8388608
  float* betab  = ws + 25165824;            // 65536
  float* decay  = ws + 25231360;            // 512
  float* stats  = ws + 25231872;            // 64
  // bf16 buffers (element counts are bf16)
  __bf16* xbf = (__bf16*)(ws + 25231936);   // 8388608 bf16 (4194304 f)
  __bf16* Wob = (__bf16*)(ws + 29426240);   // 4194304 bf16 (2097152 f)
  __bf16* Wgb = (__bf16*)(ws + 31523392);   // 4194304 bf16
  __bf16* Wqb = (__bf16*)(ws + 33620544);   // 4194304 bf16
  __bf16* Wkb = (__bf16*)(ws + 35717696);   // 4194304 bf16
  __bf16* Wvb = (__bf16*)(ws + 37814848);   // 4194304 bf16
  // gate/states region: [Wqb .. Wqb + 8388608 floats) = Wqb,Wkb,Wvb + 2097152 fresh
  float* states  = ws + 33620544;           // 8388608 (alias Wqb..Wvb + extra; dead by then)
  float* gatebuf = ws + 33620544;           // 8388608 (after phaseC; Wgb NOT in range)
  // u / contrib / att all live in the d_out y-region (disjoint lifetimes)
  float* y_out  = (float*)d_out;            // 8388608
  float* st_out = (float*)d_out + (size_t)BB * TT * EE;
  float* u       = y_out;
  float* contrib = y_out;
  float* att     = y_out;
  __bf16* gbf = (__bf16*)q;                 // q dead after phaseC

  const dim3 blk(256);
  const dim3 gB(CC / 128, (BB * TT) / 128);   // 16 x 32
  const float qscale = 0.08838834764831845f;  // D^-0.5

  // f32 -> bf16 conversions
  f2b<<<dim3(8192), blk, 0, stream>>>(x, xbf, BB * TT * EE);
  f2b<<<dim3(4096), blk, 0, stream>>>(Wq, Wqb, CC * EE);
  f2b<<<dim3(4096), blk, 0, stream>>>(Wk, Wkb, CC * EE);
  f2b<<<dim3(4096), blk, 0, stream>>>(Wv, Wvb, CC * EE);
  f2b<<<dim3(4096), blk, 0, stream>>>(Wgate, Wgb, CC * EE);
  f2b<<<dim3(4096), blk, 0, stream>>>(Wo, Wob, EE * CC);

  // projections (bf16 MFMA) + conv/silu, sequenced through the shared u buffer
  gemm_bf16<0><<<gB, blk, 0, stream>>>(xbf, Wqb, u, BB * TT, CC, EE);
  conv_silu<<<dim3(8192), blk, 0, stream>>>(u, wqc, q, qscale);
  gemm_bf16<0><<<gB, blk, 0, stream>>>(xbf, Wkb, u, BB * TT, CC, EE);
  conv_silu<<<dim3(8192), blk, 0, stream>>>(u, wkc, k, 1.f);
  gemm_bf16<0><<<gB, blk, 0, stream>>>(xbf, Wvb, u, BB * TT, CC, EE);
  conv_silu<<<dim3(8192), blk, 0, stream>>>(u, wvc, v, 1.f);

  // beta = sigmoid(x @ Wbeta^T) (fp32, N=16)
  gemm_nt<1><<<dim3(1, (BB * TT) / 64), blk, 0, stream>>>(x, Wbeta, betab, BB * TT, HH, EE);

  // chunked delta scan
  phaseA<<<dim3(NC, HH, BB), blk, 0, stream>>>(k, v, betab, contrib, decay);
  phaseB<<<dim3((BB * HH * DD * DD) / 256), blk, 0, stream>>>(st0, contrib, decay, states, st_out);
  phaseC<<<dim3(NC, HH, BB), blk, 0, stream>>>(q, k, v, betab, states, att);

  // gate = sigmoid(xbf @ Wgb^T) -> gatebuf (overwrites states; dead)
  gemm_bf16<1><<<gB, blk, 0, stream>>>(xbf, Wgb, gatebuf, BB * TT, CC, EE);

  // groupnorm stats + normalize*gate -> bf16 (into dead q)
  gn_stats<<<dim3(BB * HH), blk, 0, stream>>>(att, stats);
  norm_gate<<<dim3((BB * TT * CC) / (256 * 4)), blk, 0, stream>>>(att, gatebuf, stats, gbf);

  // y = g @ Wo^T (bf16 MFMA, overwrites att region)
  gemm_bf16<0><<<dim3(EE / 128, (BB * TT) / 128), blk, 0, stream>>>(gbf, Wob, y_out, BB * TT, EE, CC);
}

// Round 3
// 716.003 us; speedup vs baseline: 4.3013x; 1.1437x over previous
//
#include <hip/hip_runtime.h>
#include <hip/hip_bf16.h>
#include <math.h>

#define BB 2
#define TT 2048
#define EE 2048
#define HH 16
#define DD 128
#define CC 2048
#define KCONV 4
#define CHUNK 128
#define NC 16          // TT / CHUNK
#define GN_EPS 1e-5f

typedef __bf16 bf16x8 __attribute__((ext_vector_type(8)));
typedef __bf16 bf16x4 __attribute__((ext_vector_type(4)));
typedef float  f32x4  __attribute__((ext_vector_type(4)));

#define GLD16(gp, lp)                                                          \
  __builtin_amdgcn_global_load_lds(                                            \
      (const __attribute__((address_space(1))) void*)(gp),                     \
      (__attribute__((address_space(3))) void*)(lp), 16, 0, 0)

// swizzled fragment load: row-major [128][128] bf16 tile, 16B-group XOR swizzle
__device__ __forceinline__ bf16x8 ldfrag(const __bf16* buf, int row, int kg)
{
  return *(const bf16x8*)(buf + row * 128 + ((kg ^ (row & 7)) << 3));
}

// ---------------------------------------------------------------------------
// f32 -> bf16 conversion, float4-vectorized.
// ---------------------------------------------------------------------------
__global__ __launch_bounds__(256)
void f2b(const float* __restrict__ in, __bf16* __restrict__ out, int n)
{
  const int i = (blockIdx.x * 256 + threadIdx.x) * 4;
  if (i >= n) return;
  const float4 v = *(const float4*)(in + i);
  bf16x4 o;
  o[0] = (__bf16)v.x; o[1] = (__bf16)v.y; o[2] = (__bf16)v.z; o[3] = (__bf16)v.w;
  *(bf16x4*)(out + i) = o;
}

// ---------------------------------------------------------------------------
// bf16 MFMA GEMM, NT (m97 structure) — unchanged from round 2 (verified).
// ---------------------------------------------------------------------------
template <int ACT>
__global__ __launch_bounds__(256)
void gemm_bf16(const __bf16* __restrict__ A, const __bf16* __restrict__ Bm,
               float* __restrict__ Cm, int M, int N, int K)
{
  __shared__ __attribute__((aligned(16))) __bf16 As[128 * 32];
  __shared__ __attribute__((aligned(16))) __bf16 Bs[128 * 32];

  const int tid  = threadIdx.x;
  const int w    = tid >> 6;
  const int lane = tid & 63;
  const int m0 = blockIdx.y * 128, n0 = blockIdx.x * 128;
  const int wm = w >> 1, wn = w & 1;

  const int srow = lane >> 2;
  const int sk   = (lane & 3) * 8;
  const __bf16* aA0 = A  + (size_t)(m0 + w * 32 + srow) * K + sk;
  const __bf16* aA1 = aA0 + (size_t)16 * K;
  const __bf16* aB0 = Bm + (size_t)(n0 + w * 32 + srow) * K + sk;
  const __bf16* aB1 = aB0 + (size_t)16 * K;
  __bf16* lA0 = As + (w * 2 + 0) * 512;
  __bf16* lA1 = As + (w * 2 + 1) * 512;
  __bf16* lB0 = Bs + (w * 2 + 0) * 512;
  __bf16* lB1 = Bs + (w * 2 + 1) * 512;

  const int fr = lane & 15;
  const int fk = (lane >> 4) * 8;
  const __bf16* rA = As + (size_t)(wm * 64 + fr) * 32 + fk;
  const __bf16* rB = Bs + (size_t)(wn * 64 + fr) * 32 + fk;

  f32x4 acc[4][4] = {};

  for (int k0 = 0; k0 < K; k0 += 32) {
    __syncthreads();
    GLD16(aA0, lA0); GLD16(aA1, lA1);
    GLD16(aB0, lB0); GLD16(aB1, lB1);
    aA0 += 32; aA1 += 32; aB0 += 32; aB1 += 32;
    asm volatile("s_waitcnt vmcnt(0)" ::: "memory");
    __syncthreads();

    bf16x8 af[4], bfr[4];
#pragma unroll
    for (int i = 0; i < 4; ++i) af[i]  = *(const bf16x8*)(rA + i * 512);
#pragma unroll
    for (int j = 0; j < 4; ++j) bfr[j] = *(const bf16x8*)(rB + j * 512);
#pragma unroll
    for (int i = 0; i < 4; ++i)
#pragma unroll
      for (int j = 0; j < 4; ++j)
        acc[i][j] = __builtin_amdgcn_mfma_f32_16x16x32_bf16(af[i], bfr[j], acc[i][j], 0, 0, 0);
  }

  const int crow0 = (lane >> 4) * 4;
#pragma unroll
  for (int i = 0; i < 4; ++i) {
#pragma unroll
    for (int j = 0; j < 4; ++j) {
      const int n = n0 + wn * 64 + j * 16 + fr;
#pragma unroll
      for (int r = 0; r < 4; ++r) {
        const int m = m0 + wm * 64 + i * 16 + crow0 + r;
        float vv = acc[i][j][r];
        if (ACT == 1) vv = 1.f / (1.f + expf(-vv));
        Cm[(size_t)m * N + n] = vv;
      }
    }
  }
}

// ---------------------------------------------------------------------------
// causal dwconv(K=4) + silu + scale -> bf16 output.
// ---------------------------------------------------------------------------
__global__ __launch_bounds__(256)
void conv_silu_b(const float* __restrict__ u, const float* __restrict__ wconv,
                 __bf16* __restrict__ out, float scale)
{
  const int idx = blockIdx.x * 256 + threadIdx.x;   // over B*T*C/4
  const int c4 = (idx & (CC / 4 - 1)) * 4;
  const int t  = (idx >> 9) & (TT - 1);
  const int b  = idx >> 20;
  const size_t base = ((size_t)(b * TT + t)) * CC + c4;

  const float4 z = make_float4(0.f, 0.f, 0.f, 0.f);
  const float4 u0 = *(const float4*)(u + base);
  const float4 u1 = (t >= 1) ? *(const float4*)(u + base - CC)     : z;
  const float4 u2 = (t >= 2) ? *(const float4*)(u + base - 2 * CC) : z;
  const float4 u3 = (t >= 3) ? *(const float4*)(u + base - 3 * CC) : z;

  bf16x4 o;
  {
    const float4 wv = *(const float4*)(wconv + (size_t)(c4 + 0) * 4);
    const float vv = wv.x * u3.x + wv.y * u2.x + wv.z * u1.x + wv.w * u0.x;
    o[0] = (__bf16)(vv / (1.f + expf(-vv)) * scale);
  }
  {
    const float4 wv = *(const float4*)(wconv + (size_t)(c4 + 1) * 4);
    const float vv = wv.x * u3.y + wv.y * u2.y + wv.z * u1.y + wv.w * u0.y;
    o[1] = (__bf16)(vv / (1.f + expf(-vv)) * scale);
  }
  {
    const float4 wv = *(const float4*)(wconv + (size_t)(c4 + 2) * 4);
    const float vv = wv.x * u3.z + wv.y * u2.z + wv.z * u1.z + wv.w * u0.z;
    o[2] = (__bf16)(vv / (1.f + expf(-vv)) * scale);
  }
  {
    const float4 wv = *(const float4*)(wconv + (size_t)(c4 + 3) * 4);
    const float vv = wv.x * u3.w + wv.y * u2.w + wv.z * u1.w + wv.w * u0.w;
    o[3] = (__bf16)(vv / (1.f + expf(-vv)) * scale);
  }
  *(bf16x4*)(out + base) = o;
}

// ---------------------------------------------------------------------------
// bf16 transpose (B,T,C[h,d]) -> (B,H,D,T), 64x64 tiles through LDS.
// grid (TT/64, DD/64, BB*HH), 256 threads.
// ---------------------------------------------------------------------------
__global__ __launch_bounds__(256)
void tr_bf16(const __bf16* __restrict__ src, __bf16* __restrict__ dst)
{
  const int t0 = blockIdx.x * 64, d0 = blockIdx.y * 64;
  const int bh = blockIdx.z, b = bh >> 4, h = bh & 15;
  const int tid = threadIdx.x;
  __shared__ __attribute__((aligned(16))) __bf16 tile[64][72];

#pragma unroll
  for (int it = 0; it < 2; ++it) {
    const int idx = tid + it * 256;       // 512 = 64 rows x 8 groups
    const int tl = idx >> 3, g = idx & 7;
    const bf16x8 v = *(const bf16x8*)(src + ((size_t)(b * TT + t0 + tl)) * CC + h * DD + d0 + g * 8);
    *(bf16x8*)&tile[tl][g * 8] = v;
  }
  __syncthreads();
#pragma unroll
  for (int it = 0; it < 2; ++it) {
    const int idx = tid + it * 256;
    const int dl = idx >> 3, g = idx & 7;
    bf16x8 o;
#pragma unroll
    for (int jj = 0; jj < 8; ++jj) o[jj] = tile[g * 8 + jj][dl];
    *(bf16x8*)(dst + ((size_t)(bh * DD + d0 + dl)) * TT + t0 + g * 8) = o;
  }
}

// ---------------------------------------------------------------------------
// fp32 128x128 transpose per bh. grid (2,2,BB*HH), 256 threads.
// ---------------------------------------------------------------------------
__global__ __launch_bounds__(256)
void tr_f32(const float* __restrict__ in, float* __restrict__ out)
{
  const int r0 = blockIdx.x * 64, c0 = blockIdx.y * 64;
  const int bh = blockIdx.z;
  const int tid = threadIdx.x;
  __shared__ float tile[64][65];

#pragma unroll
  for (int it = 0; it < 4; ++it) {
    const int idx = tid + it * 256;       // 1024 = 64 rows x 16 float4
    const int rl = idx >> 4, g = idx & 15;
    const float4 v = *(const float4*)(in + (size_t)bh * 16384 + (r0 + rl) * 128 + c0 + g * 4);
    tile[rl][g * 4 + 0] = v.x; tile[rl][g * 4 + 1] = v.y;
    tile[rl][g * 4 + 2] = v.z; tile[rl][g * 4 + 3] = v.w;
  }
  __syncthreads();
#pragma unroll
  for (int it = 0; it < 4; ++it) {
    const int idx = tid + it * 256;
    const int cl = idx >> 4, g = idx & 15;
    float4 o;
    o.x = tile[g * 4 + 0][cl]; o.y = tile[g * 4 + 1][cl];
    o.z = tile[g * 4 + 2][cl]; o.w = tile[g * 4 + 3][cl];
    *(float4*)(out + (size_t)bh * 16384 + (c0 + cl) * 128 + r0 + g * 4) = o;
  }
}

// ---------------------------------------------------------------------------
// fp32 GEMM NT (beta only, N=16). ACT 1 = sigmoid.
// ---------------------------------------------------------------------------
template <int ACT>
__global__ __launch_bounds__(256)
void gemm_nt(const float* __restrict__ A, const float* __restrict__ Bm,
             float* __restrict__ Cm, int M, int N, int Kd)
{
  const int m0 = blockIdx.y * 64;
  const int n0 = blockIdx.x * 64;
  const int tid = threadIdx.x;
  const int ty = tid >> 4, tx = tid & 15;

  __shared__ float As[16][64];
  __shared__ float Bs[16][64];

  float acc[4][4] = {};

  const int arow = tid >> 2;
  const int ak = (tid & 3) * 4;
  const float* aptr = A + (size_t)(m0 + arow) * Kd + ak;
  const int brow = n0 + arow;
  const bool bvalid = brow < N;
  const float* bptr = Bm + (size_t)(bvalid ? brow : 0) * Kd + ak;

  for (int k0 = 0; k0 < Kd; k0 += 16) {
    const float4 a4 = *(const float4*)(aptr + k0);
    float4 b4 = make_float4(0.f, 0.f, 0.f, 0.f);
    if (bvalid) b4 = *(const float4*)(bptr + k0);
    __syncthreads();
    As[ak + 0][arow] = a4.x; As[ak + 1][arow] = a4.y;
    As[ak + 2][arow] = a4.z; As[ak + 3][arow] = a4.w;
    Bs[ak + 0][arow] = b4.x; Bs[ak + 1][arow] = b4.y;
    Bs[ak + 2][arow] = b4.z; Bs[ak + 3][arow] = b4.w;
    __syncthreads();
#pragma unroll
    for (int kk = 0; kk < 16; ++kk) {
      float aa[4], bb[4];
      *(float4*)&aa[0] = *(const float4*)&As[kk][ty * 4];
      *(float4*)&bb[0] = *(const float4*)&Bs[kk][tx * 4];
#pragma unroll
      for (int i = 0; i < 4; ++i)
#pragma unroll
        for (int j = 0; j < 4; ++j)
          acc[i][j] = fmaf(aa[i], bb[j], acc[i][j]);
    }
  }

#pragma unroll
  for (int i = 0; i < 4; ++i) {
    const int m = m0 + ty * 4 + i;
#pragma unroll
    for (int j = 0; j < 4; ++j) {
      const int n = n0 + tx * 4 + j;
      if (n < N) {
        float v = acc[i][j];
        if (ACT == 1) v = 1.f / (1.f + expf(-v));
        Cm[(size_t)m * N + n] = v;
      }
    }
  }
}

// ---------------------------------------------------------------------------
// Phase A (MFMA): contribT[e][d] = sum_s (w_s k_s[d]) v_s[e];  decay out.
// Operands: vT, kT (B,H,D,T bf16). grid (NC, HH, BB), 256 thr.
// ---------------------------------------------------------------------------
__global__ __launch_bounds__(256)
void phaseA_mfma(const __bf16* __restrict__ kT, const __bf16* __restrict__ vT,
                 const float* __restrict__ beta, float* __restrict__ contribT,
                 float* __restrict__ decay)
{
  const int c = blockIdx.x, h = blockIdx.y, b = blockIdx.z;
  const int bh = b * HH + h;
  const int tid = threadIdx.x;
  const int w = tid >> 6, lane = tid & 63;
  const int wm = w >> 1, wn = w & 1;

  __shared__ __attribute__((aligned(16))) __bf16 bufVT[128 * 128];
  __shared__ __attribute__((aligned(16))) __bf16 bufKW[128 * 128];
  __shared__ float lc[CHUNK], bsh[CHUNK], wgt[CHUNK];

  // stage V^T (GLD16, pre-swizzled source)
  {
    const __bf16* vbase = vT + ((size_t)bh * DD) * TT + c * CHUNK;
#pragma unroll
    for (int jj = 0; jj < 8; ++jj) {
      const int row = w * 32 + jj * 4 + (lane >> 4);
      const int g = lane & 15;
      GLD16(vbase + (size_t)row * TT + ((g ^ (row & 7)) << 3),
            bufVT + (w * 32 + jj * 4) * 128);
    }
  }

  // beta scan
  if (tid < CHUNK) {
    const float bv = beta[(size_t)(b * TT + c * CHUNK + tid) * HH + h];
    bsh[tid] = bv;
    lc[tid] = log1pf(-bv);
  }
  __syncthreads();
  for (int off = 1; off < CHUNK; off <<= 1) {
    float add = 0.f;
    if (tid < CHUNK && tid >= off) add = lc[tid - off];
    __syncthreads();
    if (tid < CHUNK) lc[tid] += add;
    __syncthreads();
  }
  const float lend = lc[CHUNK - 1];
  if (tid < CHUNK) wgt[tid] = bsh[tid] * expf(lend - lc[tid]);
  if (tid == 0) decay[(size_t)bh * NC + c] = expf(lend);
  __syncthreads();

  // stage K^T with per-column weight (register path, swizzled ds_write)
  {
    const __bf16* kbase = kT + ((size_t)bh * DD) * TT + c * CHUNK;
#pragma unroll
    for (int it = 0; it < 8; ++it) {
      const int idx = tid + it * 256;
      const int d = idx >> 4, g = idx & 15;
      const bf16x8 kv = *(const bf16x8*)(kbase + (size_t)d * TT + g * 8);
      bf16x8 o;
#pragma unroll
      for (int jj = 0; jj < 8; ++jj)
        o[jj] = (__bf16)((float)kv[jj] * wgt[g * 8 + jj]);
      *(bf16x8*)(bufKW + d * 128 + ((g ^ (d & 7)) << 3)) = o;
    }
  }
  asm volatile("s_waitcnt vmcnt(0)" ::: "memory");
  __syncthreads();

  // MFMA: C[m=e][n=d] = sum_s VT[e,s] * KW[d,s]
  f32x4 acc[4][4] = {};
#pragma unroll
  for (int ks = 0; ks < 4; ++ks) {
    bf16x8 a[4], bq[4];
    const int kg = ks * 4 + (lane >> 4);
#pragma unroll
    for (int f = 0; f < 4; ++f) a[f]  = ldfrag(bufVT, wm * 64 + f * 16 + (lane & 15), kg);
#pragma unroll
    for (int f = 0; f < 4; ++f) bq[f] = ldfrag(bufKW, wn * 64 + f * 16 + (lane & 15), kg);
#pragma unroll
    for (int i = 0; i < 4; ++i)
#pragma unroll
      for (int j = 0; j < 4; ++j)
        acc[i][j] = __builtin_amdgcn_mfma_f32_16x16x32_bf16(a[i], bq[j], acc[i][j], 0, 0, 0);
  }

  float* cp = contribT + ((size_t)(bh * NC + c) << 14);
  const int crow = (lane >> 4) * 4;
#pragma unroll
  for (int i = 0; i < 4; ++i)
#pragma unroll
    for (int j = 0; j < 4; ++j) {
      const int dd = wn * 64 + j * 16 + (lane & 15);
#pragma unroll
      for (int r = 0; r < 4; ++r) {
        const int e = wm * 64 + i * 16 + crow + r;
        cp[(size_t)e * 128 + dd] = acc[i][j][r];
      }
    }
}

// ---------------------------------------------------------------------------
// Phase B (transposed space): statesT bf16 per chunk + stateOutT fp32.
// ---------------------------------------------------------------------------
__global__ __launch_bounds__(256)
void phaseB_T(const float* __restrict__ state0T, const float* __restrict__ contribT,
              const float* __restrict__ decay, __bf16* __restrict__ statesT,
              float* __restrict__ stateOutT)
{
  const size_t gid = (size_t)blockIdx.x * 256 + threadIdx.x;
  const int bh = (int)(gid >> 14);
  const int ed = (int)(gid & 16383);
  float s = state0T[gid];
  const float* dc = decay + (size_t)bh * NC;
#pragma unroll
  for (int c = 0; c < NC; ++c) {
    const size_t off = ((size_t)(bh * NC + c) << 14) + ed;
    statesT[off] = (__bf16)s;
    s = fmaf(dc[c], s, contribT[off]);
  }
  stateOutT[gid] = s;
}

// ---------------------------------------------------------------------------
// Phase C (MFMA): att[t][e] = sum_s P[t][s] v[s][e] + e^{lc_t} sum_d q[t][d] S0[d][e]
// P[t][s] = (q_t.k_s) * b_s * e^{lc_t - lc_s} for s<=t.
// grid (NC, HH, BB), 256 thr. LDS: bufQ (Q then P), bufB (K, S0T, VT).
// ---------------------------------------------------------------------------
__global__ __launch_bounds__(256)
void phaseC_mfma(const __bf16* __restrict__ qb, const __bf16* __restrict__ kb,
                 const __bf16* __restrict__ vT, const float* __restrict__ beta,
                 const __bf16* __restrict__ statesT, float* __restrict__ att)
{
  const int c = blockIdx.x, h = blockIdx.y, b = blockIdx.z;
  const int bh = b * HH + h;
  const int tid = threadIdx.x;
  const int w = tid >> 6, lane = tid & 63;
  const int wm = w >> 1, wn = w & 1;

  __shared__ __attribute__((aligned(16))) __bf16 bufQ[128 * 128];
  __shared__ __attribute__((aligned(16))) __bf16 bufB[128 * 128];
  __shared__ float lc[CHUNK], bsh[CHUNK];

  // stage Q and K ([t][d] rows from (B,T,C) layout)
  {
    const __bf16* qbase = qb + ((size_t)(b * TT + c * CHUNK)) * CC + h * DD;
    const __bf16* kbase = kb + ((size_t)(b * TT + c * CHUNK)) * CC + h * DD;
#pragma unroll
    for (int jj = 0; jj < 8; ++jj) {
      const int row = w * 32 + jj * 4 + (lane >> 4);
      const int g = lane & 15;
      GLD16(qbase + (size_t)row * CC + ((g ^ (row & 7)) << 3),
            bufQ + (w * 32 + jj * 4) * 128);
      GLD16(kbase + (size_t)row * CC + ((g ^ (row & 7)) << 3),
            bufB + (w * 32 + jj * 4) * 128);
    }
  }

  // beta scan
  if (tid < CHUNK) {
    const float bv = beta[(size_t)(b * TT + c * CHUNK + tid) * HH + h];
    bsh[tid] = bv;
    lc[tid] = log1pf(-bv);
  }
  __syncthreads();
  for (int off = 1; off < CHUNK; off <<= 1) {
    float add = 0.f;
    if (tid < CHUNK && tid >= off) add = lc[tid - off];
    __syncthreads();
    if (tid < CHUNK) lc[tid] += add;
    __syncthreads();
  }

  asm volatile("s_waitcnt vmcnt(0)" ::: "memory");
  __syncthreads();

  // phase 1: S = Q K^T  (m=t, n=s)
  f32x4 accS[4][4] = {};
#pragma unroll
  for (int ks = 0; ks < 4; ++ks) {
    bf16x8 a[4], bq[4];
    const int kg = ks * 4 + (lane >> 4);
#pragma unroll
    for (int f = 0; f < 4; ++f) a[f]  = ldfrag(bufQ, wm * 64 + f * 16 + (lane & 15), kg);
#pragma unroll
    for (int f = 0; f < 4; ++f) bq[f] = ldfrag(bufB, wn * 64 + f * 16 + (lane & 15), kg);
#pragma unroll
    for (int i = 0; i < 4; ++i)
#pragma unroll
      for (int j = 0; j < 4; ++j)
        accS[i][j] = __builtin_amdgcn_mfma_f32_16x16x32_bf16(a[i], bq[j], accS[i][j], 0, 0, 0);
  }

  __syncthreads();   // all K reads done -> reuse bufB for S0T
  {
    const __bf16* sbase = statesT + ((size_t)(bh * NC + c) << 14);
#pragma unroll
    for (int jj = 0; jj < 8; ++jj) {
      const int row = w * 32 + jj * 4 + (lane >> 4);
      const int g = lane & 15;
      GLD16(sbase + (size_t)row * 128 + ((g ^ (row & 7)) << 3),
            bufB + (w * 32 + jj * 4) * 128);
    }
  }
  asm volatile("s_waitcnt vmcnt(0)" ::: "memory");
  __syncthreads();

  // phase 3: accO = Q S0T (m=t, n=e), then scale rows by e^{lc_t}
  f32x4 accO[4][4] = {};
#pragma unroll
  for (int ks = 0; ks < 4; ++ks) {
    bf16x8 a[4], bq[4];
    const int kg = ks * 4 + (lane >> 4);
#pragma unroll
    for (int f = 0; f < 4; ++f) a[f]  = ldfrag(bufQ, wm * 64 + f * 16 + (lane & 15), kg);
#pragma unroll
    for (int f = 0; f < 4; ++f) bq[f] = ldfrag(bufB, wn * 64 + f * 16 + (lane & 15), kg);
#pragma unroll
    for (int i = 0; i < 4; ++i)
#pragma unroll
      for (int j = 0; j < 4; ++j)
        accO[i][j] = __builtin_amdgcn_mfma_f32_16x16x32_bf16(a[i], bq[j], accO[i][j], 0, 0, 0);
  }
  const int crow = (lane >> 4) * 4;
#pragma unroll
  for (int i = 0; i < 4; ++i)
#pragma unroll
    for (int r = 0; r < 4; ++r) {
      const float el = expf(lc[wm * 64 + i * 16 + crow + r]);
#pragma unroll
      for (int j = 0; j < 4; ++j) accO[i][j][r] *= el;
    }

  __syncthreads();   // all Q / S0T reads done -> reuse bufQ for P, bufB for VT
  // stage V^T
  {
    const __bf16* vbase = vT + ((size_t)bh * DD) * TT + c * CHUNK;
#pragma unroll
    for (int jj = 0; jj < 8; ++jj) {
      const int row = w * 32 + jj * 4 + (lane >> 4);
      const int g = lane & 15;
      GLD16(vbase + (size_t)row * TT + ((g ^ (row & 7)) << 3),
            bufB + (w * 32 + jj * 4) * 128);
    }
  }
  // transform S -> P and write bf16 into bufQ (swizzled)
  {
    float lcs[4], bss[4];
#pragma unroll
    for (int j = 0; j < 4; ++j) {
      const int s = wn * 64 + j * 16 + (lane & 15);
      lcs[j] = lc[s]; bss[j] = bsh[s];
    }
#pragma unroll
    for (int i = 0; i < 4; ++i)
#pragma unroll
      for (int r = 0; r < 4; ++r) {
        const int t = wm * 64 + i * 16 + crow + r;
        const float lct = lc[t];
#pragma unroll
        for (int j = 0; j < 4; ++j) {
          const int s = wn * 64 + j * 16 + (lane & 15);
          float p = 0.f;
          if (s <= t) p = accS[i][j][r] * bss[j] * expf(lct - lcs[j]);
          bufQ[t * 128 + (((s >> 3) ^ (t & 7)) << 3) + (s & 7)] = (__bf16)p;
        }
      }
  }
  asm volatile("s_waitcnt vmcnt(0)" ::: "memory");
  __syncthreads();

  // phase 2: accO += P V^T  (m=t, n=e, k=s)
#pragma unroll
  for (int ks = 0; ks < 4; ++ks) {
    bf16x8 a[4], bq[4];
    const int kg = ks * 4 + (lane >> 4);
#pragma unroll
    for (int f = 0; f < 4; ++f) a[f]  = ldfrag(bufQ, wm * 64 + f * 16 + (lane & 15), kg);
#pragma unroll
    for (int f = 0; f < 4; ++f) bq[f] = ldfrag(bufB, wn * 64 + f * 16 + (lane & 15), kg);
#pragma unroll
    for (int i = 0; i < 4; ++i)
#pragma unroll
      for (int j = 0; j < 4; ++j)
        accO[i][j] = __builtin_amdgcn_mfma_f32_16x16x32_bf16(a[i], bq[j], accO[i][j], 0, 0, 0);
  }

  // epilogue: att (B,T,H,D) fp32
  float* obase = att + ((size_t)(b * TT + c * CHUNK)) * CC + h * DD;
#pragma unroll
  for (int i = 0; i < 4; ++i)
#pragma unroll
    for (int j = 0; j < 4; ++j) {
      const int e = wn * 64 + j * 16 + (lane & 15);
#pragma unroll
      for (int r = 0; r < 4; ++r) {
        const int t = wm * 64 + i * 16 + crow + r;
        obase[(size_t)t * CC + e] = accO[i][j][r];
      }
    }
}

// ---------------------------------------------------------------------------
// GroupNorm stats per (b,h) over (T,D).
// ---------------------------------------------------------------------------
__global__ __launch_bounds__(256)
void gn_stats(const float* __restrict__ att, float* __restrict__ stats)
{
  const int bh = blockIdx.x;
  const int b = bh >> 4, h = bh & 15;
  const int tid = threadIdx.x;
  float sum = 0.f, sq = 0.f;
  for (int idx = tid; idx < TT * DD / 4; idx += 256) {
    const int t = idx / (DD / 4);
    const int e4 = (idx % (DD / 4)) * 4;
    const float4 v = *(const float4*)(att + ((size_t)(b * TT + t)) * CC + h * DD + e4);
    sum += v.x + v.y + v.z + v.w;
    sq += v.x * v.x + v.y * v.y + v.z * v.z + v.w * v.w;
  }
  __shared__ float s1[256], s2[256];
  s1[tid] = sum; s2[tid] = sq;
  __syncthreads();
  for (int off = 128; off; off >>= 1) {
    if (tid < off) { s1[tid] += s1[tid + off]; s2[tid] += s2[tid + off]; }
    __syncthreads();
  }
  if (tid == 0) {
    const float n = (float)(TT * DD);
    const float mean = s1[0] / n;
    const float var = s2[0] / n - mean * mean;
    stats[bh * 2] = mean;
    stats[bh * 2 + 1] = rsqrtf(var + GN_EPS);
  }
}

// ---------------------------------------------------------------------------
// normalize + gate -> bf16.
// ---------------------------------------------------------------------------
__global__ __launch_bounds__(256)
void norm_gate(const float* __restrict__ att, const float* __restrict__ gate,
               const float* __restrict__ stats, __bf16* __restrict__ g)
{
  const size_t gid = ((size_t)blockIdx.x * 256 + threadIdx.x) * 4;
  if (gid >= (size_t)BB * TT * CC) return;
  const int cpos = (int)(gid % CC);
  const int b = (int)(gid / ((size_t)TT * CC));
  const int bh = b * HH + (cpos >> 7);
  const float mean = stats[bh * 2], rstd = stats[bh * 2 + 1];
  const float4 a = *(const float4*)(att + gid);
  const float4 gt = *(const float4*)(gate + gid);
  bf16x4 o;
  o[0] = (__bf16)((a.x - mean) * rstd * gt.x);
  o[1] = (__bf16)((a.y - mean) * rstd * gt.y);
  o[2] = (__bf16)((a.z - mean) * rstd * gt.z);
  o[3] = (__bf16)((a.w - mean) * rstd * gt.w);
  *(bf16x4*)(g + gid) = o;
}

// ---------------------------------------------------------------------------
extern "C" void kernel_launch(void* const* d_in, const int* in_sizes, int n_in,
                              void* d_out, int out_size, void* d_ws, size_t ws_size,
                              hipStream_t stream)
{
  const float* x      = (const float*)d_in[0];
  const float* st0    = (const float*)d_in[1];
  const float* Wq     = (const float*)d_in[2];
  const float* Wk     = (const float*)d_in[3];
  const float* Wv     = (const float*)d_in[4];
  const float* Wbeta  = (const float*)d_in[5];
  const float* Wgate  = (const float*)d_in[6];
  const float* Wo     = (const float*)d_in[7];
  const float* wqc    = (const float*)d_in[8];
  const float* wkc    = (const float*)d_in[9];
  const float* wvc    = (const float*)d_in[10];

  float* ws = (float*)d_ws;
  // layout (float offsets); total 38,863,424 f = 155.5 MB
  __bf16* qbf  = (__bf16*)(ws + 0);          // 8388608 bf16
  __bf16* kbf  = (__bf16*)(ws + 4194304);    // 8388608 bf16
  __bf16* vbf  = (__bf16*)(ws + 8388608);    // 8388608 bf16 -> statesT after transpose
  __bf16* kT   = (__bf16*)(ws + 12582912);   // 8388608 bf16 -> gbf after phaseA
  __bf16* vT   = (__bf16*)(ws + 16777216);   // 8388608 bf16
  __bf16* xbf  = (__bf16*)(ws + 20971520);   // 8388608 bf16
  __bf16* Wgb  = (__bf16*)(ws + 25165824);   // 4194304 bf16
  __bf16* Wob  = (__bf16*)(ws + 27262976);   // 4194304 bf16
  __bf16* Wqb  = (__bf16*)(ws + 29360128);   // 4194304 bf16 ┐
  __bf16* Wkb  = (__bf16*)(ws + 31457280);   // 4194304 bf16 │ contribT/gatebuf span
  __bf16* Wvb  = (__bf16*)(ws + 33554432);   // 4194304 bf16 ┘
  float* contribT = ws + 29360128;           // 8388608 f (overwrites Wqb..Wvb+extra)
  float* gatebuf  = ws + 29360128;           // 8388608 f (after phaseB)
  __bf16* statesT = (__bf16*)(ws + 8388608); // 8388608 bf16 (overwrites vbf)
  __bf16* gbf     = (__bf16*)(ws + 12582912);// 8388608 bf16 (overwrites kT)
  float* betab    = ws + 37748736;           // 65536
  float* decay    = ws + 37814272;           // 512
  float* stats    = ws + 37814784;           // 64
  float* state0T  = ws + 37814848;           // 524288
  float* stateOutT= ws + 38339136;           // 524288

  float* y_out  = (float*)d_out;             // (B,T,E); also u / att scratch
  float* st_out = (float*)d_out + (size_t)BB * TT * EE;
  float* u   = y_out;
  float* att = y_out;

  const dim3 blk(256);
  const dim3 gB(CC / 128, (BB * TT) / 128);   // 16 x 32
  const dim3 gTr(TT / 64, DD / 64, BB * HH);  // bf16 transpose
  const dim3 gTrS(2, 2, BB * HH);             // state transpose
  const dim3 gScan(NC, HH, BB);
  const float qscale = 0.08838834764831845f;  // D^-0.5

  // f32 -> bf16 conversions
  f2b<<<dim3(8192), blk, 0, stream>>>(x, xbf, BB * TT * EE);
  f2b<<<dim3(4096), blk, 0, stream>>>(Wq, Wqb, CC * EE);
  f2b<<<dim3(4096), blk, 0, stream>>>(Wk, Wkb, CC * EE);
  f2b<<<dim3(4096), blk, 0, stream>>>(Wv, Wvb, CC * EE);
  f2b<<<dim3(4096), blk, 0, stream>>>(Wgate, Wgb, CC * EE);
  f2b<<<dim3(4096), blk, 0, stream>>>(Wo, Wob, EE * CC);

  // projections + conv/silu (bf16 outputs)
  gemm_bf16<0><<<gB, blk, 0, stream>>>(xbf, Wqb, u, BB * TT, CC, EE);
  conv_silu_b<<<dim3(8192), blk, 0, stream>>>(u, wqc, qbf, qscale);
  gemm_bf16<0><<<gB, blk, 0, stream>>>(xbf, Wkb, u, BB * TT, CC, EE);
  conv_silu_b<<<dim3(8192), blk, 0, stream>>>(u, wkc, kbf, 1.f);
  gemm_bf16<0><<<gB, blk, 0, stream>>>(xbf, Wvb, u, BB * TT, CC, EE);
  conv_silu_b<<<dim3(8192), blk, 0, stream>>>(u, wvc, vbf, 1.f);

  // k,v transposes -> (B,H,D,T)
  tr_bf16<<<gTr, blk, 0, stream>>>(kbf, kT);
  tr_bf16<<<gTr, blk, 0, stream>>>(vbf, vT);

  // beta (fp32)
  gemm_nt<1><<<dim3(1, (BB * TT) / 64), blk, 0, stream>>>(x, Wbeta, betab, BB * TT, HH, EE);

  // state0 transpose -> [bh][e][d]
  tr_f32<<<gTrS, blk, 0, stream>>>(st0, state0T);

  // chunked delta scan (MFMA)
  phaseA_mfma<<<gScan, blk, 0, stream>>>(kT, vT, betab, contribT, decay);
  phaseB_T<<<dim3((BB * HH * DD * DD) / 256), blk, 0, stream>>>(state0T, contribT, decay, statesT, stateOutT);
  tr_f32<<<gTrS, blk, 0, stream>>>(stateOutT, st_out);
  phaseC_mfma<<<gScan, blk, 0, stream>>>(qbf, kbf, vT, betab, statesT, att);

  // gate = sigmoid(xbf @ Wgb^T)
  gemm_bf16<1><<<gB, blk, 0, stream>>>(xbf, Wgb, gatebuf, BB * TT, CC, EE);

  // groupnorm + gate -> bf16
  gn_stats<<<dim3(BB * HH), blk, 0, stream>>>(att, stats);
  norm_gate<<<dim3((BB * TT * CC) / (256 * 4)), blk, 0, stream>>>(att, gatebuf, stats, gbf);

  // y = g @ Wo^T
  gemm_bf16<0><<<dim3(EE / 128, (BB * TT) / 128), blk, 0, stream>>>(gbf, Wob, y_out, BB * TT, EE, CC);
}

// Round 4
// 579.341 us; speedup vs baseline: 5.3159x; 1.2359x over previous
//
#include <hip/hip_runtime.h>
#include <hip/hip_bf16.h>
#include <math.h>

#define BB 2
#define TT 2048
#define EE 2048
#define HH 16
#define DD 128
#define CC 2048
#define KCONV 4
#define CHUNK 128
#define NC 16          // TT / CHUNK
#define GN_EPS 1e-5f

typedef __bf16 bf16x8 __attribute__((ext_vector_type(8)));
typedef __bf16 bf16x4 __attribute__((ext_vector_type(4)));
typedef float  f32x4  __attribute__((ext_vector_type(4)));

#define GLD16(gp, lp)                                                          \
  __builtin_amdgcn_global_load_lds(                                            \
      (const __attribute__((address_space(1))) void*)(gp),                     \
      (__attribute__((address_space(3))) void*)(lp), 16, 0, 0)

// swizzled fragment load: row-major [128][128] bf16 tile, 16B-group XOR swizzle
__device__ __forceinline__ bf16x8 ldfrag(const __bf16* buf, int row, int kg)
{
  return *(const bf16x8*)(buf + row * 128 + ((kg ^ (row & 7)) << 3));
}

// ---------------------------------------------------------------------------
// f32 -> bf16 conversion, float4-vectorized.
// ---------------------------------------------------------------------------
__global__ __launch_bounds__(256)
void f2b(const float* __restrict__ in, __bf16* __restrict__ out, int n)
{
  const int i = (blockIdx.x * 256 + threadIdx.x) * 4;
  if (i >= n) return;
  const float4 v = *(const float4*)(in + i);
  bf16x4 o;
  o[0] = (__bf16)v.x; o[1] = (__bf16)v.y; o[2] = (__bf16)v.z; o[3] = (__bf16)v.w;
  *(bf16x4*)(out + i) = o;
}

// ---------------------------------------------------------------------------
// beta = sigmoid(x @ Wbeta^T), x fp32 (B*T, E), Wbeta (16, E).
// grid 1024 x 256thr: one wave per row; Wbeta staged in LDS K-tiles of 1024.
// ---------------------------------------------------------------------------
__global__ __launch_bounds__(256)
void beta_ker(const float* __restrict__ x, const float* __restrict__ Wb,
              float* __restrict__ betab)
{
  __shared__ float wsb[16 * 1024];   // 64 KB
  const int tid = threadIdx.x;
  const int w = tid >> 6, lane = tid & 63;
  const int row = blockIdx.x * 4 + w;           // < B*T = 4096
  const float* xrow = x + (size_t)row * EE;

  float acc[16] = {};
#pragma unroll
  for (int kt = 0; kt < 2; ++kt) {
    __syncthreads();
#pragma unroll
    for (int it = 0; it < 16; ++it) {           // stage 16x1024 floats
      const int i = tid + it * 256;             // < 4096 float4s
      const int h = i >> 8, kq = i & 255;
      *(float4*)&wsb[h * 1024 + kq * 4] =
          *(const float4*)(Wb + (size_t)h * EE + kt * 1024 + kq * 4);
    }
    __syncthreads();
#pragma unroll
    for (int j = 0; j < 4; ++j) {
      const int kof = lane * 4 + j * 256;       // conflict-free 16B stride
      const float4 xv = *(const float4*)(xrow + kt * 1024 + kof);
#pragma unroll
      for (int h = 0; h < 16; ++h) {
        const float4 wv = *(const float4*)&wsb[h * 1024 + kof];
        acc[h] += xv.x * wv.x + xv.y * wv.y + xv.z * wv.z + xv.w * wv.w;
      }
    }
  }
#pragma unroll
  for (int h = 0; h < 16; ++h) {
#pragma unroll
    for (int off = 32; off; off >>= 1)
      acc[h] += __shfl_xor(acc[h], off, 64);
  }
#pragma unroll
  for (int h = 0; h < 16; ++h)
    if (lane == h)
      betab[(size_t)row * HH + h] = 1.f / (1.f + expf(-acc[h]));
}

// ---------------------------------------------------------------------------
// bf16 MFMA GEMM, NT (m97 structure). OT = output type (float or __bf16).
// ---------------------------------------------------------------------------
template <int ACT, typename OT>
__global__ __launch_bounds__(256)
void gemm_bf16(const __bf16* __restrict__ A, const __bf16* __restrict__ Bm,
               OT* __restrict__ Cm, int M, int N, int K)
{
  __shared__ __attribute__((aligned(16))) __bf16 As[128 * 32];
  __shared__ __attribute__((aligned(16))) __bf16 Bs[128 * 32];

  const int tid  = threadIdx.x;
  const int w    = tid >> 6;
  const int lane = tid & 63;
  const int m0 = blockIdx.y * 128, n0 = blockIdx.x * 128;
  const int wm = w >> 1, wn = w & 1;

  const int srow = lane >> 2;
  const int sk   = (lane & 3) * 8;
  const __bf16* aA0 = A  + (size_t)(m0 + w * 32 + srow) * K + sk;
  const __bf16* aA1 = aA0 + (size_t)16 * K;
  const __bf16* aB0 = Bm + (size_t)(n0 + w * 32 + srow) * K + sk;
  const __bf16* aB1 = aB0 + (size_t)16 * K;
  __bf16* lA0 = As + (w * 2 + 0) * 512;
  __bf16* lA1 = As + (w * 2 + 1) * 512;
  __bf16* lB0 = Bs + (w * 2 + 0) * 512;
  __bf16* lB1 = Bs + (w * 2 + 1) * 512;

  const int fr = lane & 15;
  const int fk = (lane >> 4) * 8;
  const __bf16* rA = As + (size_t)(wm * 64 + fr) * 32 + fk;
  const __bf16* rB = Bs + (size_t)(wn * 64 + fr) * 32 + fk;

  f32x4 acc[4][4] = {};

  for (int k0 = 0; k0 < K; k0 += 32) {
    __syncthreads();
    GLD16(aA0, lA0); GLD16(aA1, lA1);
    GLD16(aB0, lB0); GLD16(aB1, lB1);
    aA0 += 32; aA1 += 32; aB0 += 32; aB1 += 32;
    asm volatile("s_waitcnt vmcnt(0)" ::: "memory");
    __syncthreads();

    bf16x8 af[4], bfr[4];
#pragma unroll
    for (int i = 0; i < 4; ++i) af[i]  = *(const bf16x8*)(rA + i * 512);
#pragma unroll
    for (int j = 0; j < 4; ++j) bfr[j] = *(const bf16x8*)(rB + j * 512);
#pragma unroll
    for (int i = 0; i < 4; ++i)
#pragma unroll
      for (int j = 0; j < 4; ++j)
        acc[i][j] = __builtin_amdgcn_mfma_f32_16x16x32_bf16(af[i], bfr[j], acc[i][j], 0, 0, 0);
  }

  const int crow0 = (lane >> 4) * 4;
#pragma unroll
  for (int i = 0; i < 4; ++i) {
#pragma unroll
    for (int j = 0; j < 4; ++j) {
      const int n = n0 + wn * 64 + j * 16 + fr;
#pragma unroll
      for (int r = 0; r < 4; ++r) {
        const int m = m0 + wm * 64 + i * 16 + crow0 + r;
        float vv = acc[i][j][r];
        if (ACT == 1) vv = 1.f / (1.f + expf(-vv));
        Cm[(size_t)m * N + n] = (OT)vv;
      }
    }
  }
}

// ---------------------------------------------------------------------------
// causal dwconv(K=4) + silu + scale, bf16 in -> bf16 out, 8 ch/thread.
// ---------------------------------------------------------------------------
__global__ __launch_bounds__(256)
void conv_silu_b8(const __bf16* __restrict__ u, const float* __restrict__ wconv,
                  __bf16* __restrict__ out, float scale)
{
  const int idx = blockIdx.x * 256 + threadIdx.x;   // over B*T*C/8
  const int c8 = (idx & (CC / 8 - 1)) * 8;
  const int t  = (idx >> 8) & (TT - 1);
  const int b  = idx >> 19;
  const size_t base = ((size_t)(b * TT + t)) * CC + c8;

  const bf16x8 z = {};
  const bf16x8 u0 = *(const bf16x8*)(u + base);
  const bf16x8 u1 = (t >= 1) ? *(const bf16x8*)(u + base - CC)     : z;
  const bf16x8 u2 = (t >= 2) ? *(const bf16x8*)(u + base - 2 * CC) : z;
  const bf16x8 u3 = (t >= 3) ? *(const bf16x8*)(u + base - 3 * CC) : z;

  bf16x8 o;
#pragma unroll
  for (int jj = 0; jj < 8; ++jj) {
    const float4 wv = *(const float4*)(wconv + (size_t)(c8 + jj) * 4);
    const float vv = wv.x * (float)u3[jj] + wv.y * (float)u2[jj]
                   + wv.z * (float)u1[jj] + wv.w * (float)u0[jj];
    o[jj] = (__bf16)(vv / (1.f + expf(-vv)) * scale);
  }
  *(bf16x8*)(out + base) = o;
}

// ---------------------------------------------------------------------------
// bf16 transpose (B,T,C[h,d]) -> (B,H,D,T), 64x64 tiles through LDS.
// ---------------------------------------------------------------------------
__global__ __launch_bounds__(256)
void tr_bf16(const __bf16* __restrict__ src, __bf16* __restrict__ dst)
{
  const int t0 = blockIdx.x * 64, d0 = blockIdx.y * 64;
  const int bh = blockIdx.z, b = bh >> 4, h = bh & 15;
  const int tid = threadIdx.x;
  __shared__ __attribute__((aligned(16))) __bf16 tile[64][72];

#pragma unroll
  for (int it = 0; it < 2; ++it) {
    const int idx = tid + it * 256;       // 512 = 64 rows x 8 groups
    const int tl = idx >> 3, g = idx & 7;
    const bf16x8 v = *(const bf16x8*)(src + ((size_t)(b * TT + t0 + tl)) * CC + h * DD + d0 + g * 8);
    *(bf16x8*)&tile[tl][g * 8] = v;
  }
  __syncthreads();
#pragma unroll
  for (int it = 0; it < 2; ++it) {
    const int idx = tid + it * 256;
    const int dl = idx >> 3, g = idx & 7;
    bf16x8 o;
#pragma unroll
    for (int jj = 0; jj < 8; ++jj) o[jj] = tile[g * 8 + jj][dl];
    *(bf16x8*)(dst + ((size_t)(bh * DD + d0 + dl)) * TT + t0 + g * 8) = o;
  }
}

// ---------------------------------------------------------------------------
// fp32 128x128 transpose per bh. grid (2,2,BB*HH).
// ---------------------------------------------------------------------------
__global__ __launch_bounds__(256)
void tr_f32(const float* __restrict__ in, float* __restrict__ out)
{
  const int r0 = blockIdx.x * 64, c0 = blockIdx.y * 64;
  const int bh = blockIdx.z;
  const int tid = threadIdx.x;
  __shared__ float tile[64][65];

#pragma unroll
  for (int it = 0; it < 4; ++it) {
    const int idx = tid + it * 256;
    const int rl = idx >> 4, g = idx & 15;
    const float4 v = *(const float4*)(in + (size_t)bh * 16384 + (r0 + rl) * 128 + c0 + g * 4);
    tile[rl][g * 4 + 0] = v.x; tile[rl][g * 4 + 1] = v.y;
    tile[rl][g * 4 + 2] = v.z; tile[rl][g * 4 + 3] = v.w;
  }
  __syncthreads();
#pragma unroll
  for (int it = 0; it < 4; ++it) {
    const int idx = tid + it * 256;
    const int cl = idx >> 4, g = idx & 15;
    float4 o;
    o.x = tile[g * 4 + 0][cl]; o.y = tile[g * 4 + 1][cl];
    o.z = tile[g * 4 + 2][cl]; o.w = tile[g * 4 + 3][cl];
    *(float4*)(out + (size_t)bh * 16384 + (c0 + cl) * 128 + r0 + g * 4) = o;
  }
}

// ---------------------------------------------------------------------------
// Phase A (MFMA): contribT[e][d] = sum_s (w_s k_s[d]) v_s[e];  decay out.
// ---------------------------------------------------------------------------
__global__ __launch_bounds__(256)
void phaseA_mfma(const __bf16* __restrict__ kT, const __bf16* __restrict__ vT,
                 const float* __restrict__ beta, float* __restrict__ contribT,
                 float* __restrict__ decay)
{
  const int c = blockIdx.x, h = blockIdx.y, b = blockIdx.z;
  const int bh = b * HH + h;
  const int tid = threadIdx.x;
  const int w = tid >> 6, lane = tid & 63;
  const int wm = w >> 1, wn = w & 1;

  __shared__ __attribute__((aligned(16))) __bf16 bufVT[128 * 128];
  __shared__ __attribute__((aligned(16))) __bf16 bufKW[128 * 128];
  __shared__ float lc[CHUNK], bsh[CHUNK], wgt[CHUNK];

  {
    const __bf16* vbase = vT + ((size_t)bh * DD) * TT + c * CHUNK;
#pragma unroll
    for (int jj = 0; jj < 8; ++jj) {
      const int row = w * 32 + jj * 4 + (lane >> 4);
      const int g = lane & 15;
      GLD16(vbase + (size_t)row * TT + ((g ^ (row & 7)) << 3),
            bufVT + (w * 32 + jj * 4) * 128);
    }
  }

  if (tid < CHUNK) {
    const float bv = beta[(size_t)(b * TT + c * CHUNK + tid) * HH + h];
    bsh[tid] = bv;
    lc[tid] = log1pf(-bv);
  }
  __syncthreads();
  for (int off = 1; off < CHUNK; off <<= 1) {
    float add = 0.f;
    if (tid < CHUNK && tid >= off) add = lc[tid - off];
    __syncthreads();
    if (tid < CHUNK) lc[tid] += add;
    __syncthreads();
  }
  const float lend = lc[CHUNK - 1];
  if (tid < CHUNK) wgt[tid] = bsh[tid] * expf(lend - lc[tid]);
  if (tid == 0) decay[(size_t)bh * NC + c] = expf(lend);
  __syncthreads();

  {
    const __bf16* kbase = kT + ((size_t)bh * DD) * TT + c * CHUNK;
#pragma unroll
    for (int it = 0; it < 8; ++it) {
      const int idx = tid + it * 256;
      const int d = idx >> 4, g = idx & 15;
      const bf16x8 kv = *(const bf16x8*)(kbase + (size_t)d * TT + g * 8);
      bf16x8 o;
#pragma unroll
      for (int jj = 0; jj < 8; ++jj)
        o[jj] = (__bf16)((float)kv[jj] * wgt[g * 8 + jj]);
      *(bf16x8*)(bufKW + d * 128 + ((g ^ (d & 7)) << 3)) = o;
    }
  }
  asm volatile("s_waitcnt vmcnt(0)" ::: "memory");
  __syncthreads();

  f32x4 acc[4][4] = {};
#pragma unroll
  for (int ks = 0; ks < 4; ++ks) {
    bf16x8 a[4], bq[4];
    const int kg = ks * 4 + (lane >> 4);
#pragma unroll
    for (int f = 0; f < 4; ++f) a[f]  = ldfrag(bufVT, wm * 64 + f * 16 + (lane & 15), kg);
#pragma unroll
    for (int f = 0; f < 4; ++f) bq[f] = ldfrag(bufKW, wn * 64 + f * 16 + (lane & 15), kg);
#pragma unroll
    for (int i = 0; i < 4; ++i)
#pragma unroll
      for (int j = 0; j < 4; ++j)
        acc[i][j] = __builtin_amdgcn_mfma_f32_16x16x32_bf16(a[i], bq[j], acc[i][j], 0, 0, 0);
  }

  float* cp = contribT + ((size_t)(bh * NC + c) << 14);
  const int crow = (lane >> 4) * 4;
#pragma unroll
  for (int i = 0; i < 4; ++i)
#pragma unroll
    for (int j = 0; j < 4; ++j) {
      const int dd = wn * 64 + j * 16 + (lane & 15);
#pragma unroll
      for (int r = 0; r < 4; ++r) {
        const int e = wm * 64 + i * 16 + crow + r;
        cp[(size_t)e * 128 + dd] = acc[i][j][r];
      }
    }
}

// ---------------------------------------------------------------------------
// Phase B (transposed space).
// ---------------------------------------------------------------------------
__global__ __launch_bounds__(256)
void phaseB_T(const float* __restrict__ state0T, const float* __restrict__ contribT,
              const float* __restrict__ decay, __bf16* __restrict__ statesT,
              float* __restrict__ stateOutT)
{
  const size_t gid = (size_t)blockIdx.x * 256 + threadIdx.x;
  const int bh = (int)(gid >> 14);
  float s = state0T[gid];
  const float* dc = decay + (size_t)bh * NC;
  const int ed = (int)(gid & 16383);
#pragma unroll
  for (int c = 0; c < NC; ++c) {
    const size_t off = ((size_t)(bh * NC + c) << 14) + ed;
    statesT[off] = (__bf16)s;
    s = fmaf(dc[c], s, contribT[off]);
  }
  stateOutT[gid] = s;
}

// ---------------------------------------------------------------------------
// Phase C (MFMA).
// ---------------------------------------------------------------------------
__global__ __launch_bounds__(256)
void phaseC_mfma(const __bf16* __restrict__ qb, const __bf16* __restrict__ kb,
                 const __bf16* __restrict__ vT, const float* __restrict__ beta,
                 const __bf16* __restrict__ statesT, float* __restrict__ att)
{
  const int c = blockIdx.x, h = blockIdx.y, b = blockIdx.z;
  const int bh = b * HH + h;
  const int tid = threadIdx.x;
  const int w = tid >> 6, lane = tid & 63;
  const int wm = w >> 1, wn = w & 1;

  __shared__ __attribute__((aligned(16))) __bf16 bufQ[128 * 128];
  __shared__ __attribute__((aligned(16))) __bf16 bufB[128 * 128];
  __shared__ float lc[CHUNK], bsh[CHUNK];

  {
    const __bf16* qbase = qb + ((size_t)(b * TT + c * CHUNK)) * CC + h * DD;
    const __bf16* kbase = kb + ((size_t)(b * TT + c * CHUNK)) * CC + h * DD;
#pragma unroll
    for (int jj = 0; jj < 8; ++jj) {
      const int row = w * 32 + jj * 4 + (lane >> 4);
      const int g = lane & 15;
      GLD16(qbase + (size_t)row * CC + ((g ^ (row & 7)) << 3),
            bufQ + (w * 32 + jj * 4) * 128);
      GLD16(kbase + (size_t)row * CC + ((g ^ (row & 7)) << 3),
            bufB + (w * 32 + jj * 4) * 128);
    }
  }

  if (tid < CHUNK) {
    const float bv = beta[(size_t)(b * TT + c * CHUNK + tid) * HH + h];
    bsh[tid] = bv;
    lc[tid] = log1pf(-bv);
  }
  __syncthreads();
  for (int off = 1; off < CHUNK; off <<= 1) {
    float add = 0.f;
    if (tid < CHUNK && tid >= off) add = lc[tid - off];
    __syncthreads();
    if (tid < CHUNK) lc[tid] += add;
    __syncthreads();
  }

  asm volatile("s_waitcnt vmcnt(0)" ::: "memory");
  __syncthreads();

  // S = Q K^T
  f32x4 accS[4][4] = {};
#pragma unroll
  for (int ks = 0; ks < 4; ++ks) {
    bf16x8 a[4], bq[4];
    const int kg = ks * 4 + (lane >> 4);
#pragma unroll
    for (int f = 0; f < 4; ++f) a[f]  = ldfrag(bufQ, wm * 64 + f * 16 + (lane & 15), kg);
#pragma unroll
    for (int f = 0; f < 4; ++f) bq[f] = ldfrag(bufB, wn * 64 + f * 16 + (lane & 15), kg);
#pragma unroll
    for (int i = 0; i < 4; ++i)
#pragma unroll
      for (int j = 0; j < 4; ++j)
        accS[i][j] = __builtin_amdgcn_mfma_f32_16x16x32_bf16(a[i], bq[j], accS[i][j], 0, 0, 0);
  }

  __syncthreads();
  {
    const __bf16* sbase = statesT + ((size_t)(bh * NC + c) << 14);
#pragma unroll
    for (int jj = 0; jj < 8; ++jj) {
      const int row = w * 32 + jj * 4 + (lane >> 4);
      const int g = lane & 15;
      GLD16(sbase + (size_t)row * 128 + ((g ^ (row & 7)) << 3),
            bufB + (w * 32 + jj * 4) * 128);
    }
  }
  asm volatile("s_waitcnt vmcnt(0)" ::: "memory");
  __syncthreads();

  // accO = Q S0T, scaled by e^{lc_t}
  f32x4 accO[4][4] = {};
#pragma unroll
  for (int ks = 0; ks < 4; ++ks) {
    bf16x8 a[4], bq[4];
    const int kg = ks * 4 + (lane >> 4);
#pragma unroll
    for (int f = 0; f < 4; ++f) a[f]  = ldfrag(bufQ, wm * 64 + f * 16 + (lane & 15), kg);
#pragma unroll
    for (int f = 0; f < 4; ++f) bq[f] = ldfrag(bufB, wn * 64 + f * 16 + (lane & 15), kg);
#pragma unroll
    for (int i = 0; i < 4; ++i)
#pragma unroll
      for (int j = 0; j < 4; ++j)
        accO[i][j] = __builtin_amdgcn_mfma_f32_16x16x32_bf16(a[i], bq[j], accO[i][j], 0, 0, 0);
  }
  const int crow = (lane >> 4) * 4;
#pragma unroll
  for (int i = 0; i < 4; ++i)
#pragma unroll
    for (int r = 0; r < 4; ++r) {
      const float el = expf(lc[wm * 64 + i * 16 + crow + r]);
#pragma unroll
      for (int j = 0; j < 4; ++j) accO[i][j][r] *= el;
    }

  __syncthreads();
  {
    const __bf16* vbase = vT + ((size_t)bh * DD) * TT + c * CHUNK;
#pragma unroll
    for (int jj = 0; jj < 8; ++jj) {
      const int row = w * 32 + jj * 4 + (lane >> 4);
      const int g = lane & 15;
      GLD16(vbase + (size_t)row * TT + ((g ^ (row & 7)) << 3),
            bufB + (w * 32 + jj * 4) * 128);
    }
  }
  {
    float lcs[4], bss[4];
#pragma unroll
    for (int j = 0; j < 4; ++j) {
      const int s = wn * 64 + j * 16 + (lane & 15);
      lcs[j] = lc[s]; bss[j] = bsh[s];
    }
#pragma unroll
    for (int i = 0; i < 4; ++i)
#pragma unroll
      for (int r = 0; r < 4; ++r) {
        const int t = wm * 64 + i * 16 + crow + r;
        const float lct = lc[t];
#pragma unroll
        for (int j = 0; j < 4; ++j) {
          const int s = wn * 64 + j * 16 + (lane & 15);
          float p = 0.f;
          if (s <= t) p = accS[i][j][r] * bss[j] * expf(lct - lcs[j]);
          bufQ[t * 128 + (((s >> 3) ^ (t & 7)) << 3) + (s & 7)] = (__bf16)p;
        }
      }
  }
  asm volatile("s_waitcnt vmcnt(0)" ::: "memory");
  __syncthreads();

  // accO += P V^T
#pragma unroll
  for (int ks = 0; ks < 4; ++ks) {
    bf16x8 a[4], bq[4];
    const int kg = ks * 4 + (lane >> 4);
#pragma unroll
    for (int f = 0; f < 4; ++f) a[f]  = ldfrag(bufQ, wm * 64 + f * 16 + (lane & 15), kg);
#pragma unroll
    for (int f = 0; f < 4; ++f) bq[f] = ldfrag(bufB, wn * 64 + f * 16 + (lane & 15), kg);
#pragma unroll
    for (int i = 0; i < 4; ++i)
#pragma unroll
      for (int j = 0; j < 4; ++j)
        accO[i][j] = __builtin_amdgcn_mfma_f32_16x16x32_bf16(a[i], bq[j], accO[i][j], 0, 0, 0);
  }

  float* obase = att + ((size_t)(b * TT + c * CHUNK)) * CC + h * DD;
#pragma unroll
  for (int i = 0; i < 4; ++i)
#pragma unroll
    for (int j = 0; j < 4; ++j) {
      const int e = wn * 64 + j * 16 + (lane & 15);
#pragma unroll
      for (int r = 0; r < 4; ++r) {
        const int t = wm * 64 + i * 16 + crow + r;
        obase[(size_t)t * CC + e] = accO[i][j][r];
      }
    }
}

// ---------------------------------------------------------------------------
// GroupNorm stats per (b,h) over (T,D).
// ---------------------------------------------------------------------------
__global__ __launch_bounds__(256)
void gn_stats(const float* __restrict__ att, float* __restrict__ stats)
{
  const int bh = blockIdx.x;
  const int b = bh >> 4, h = bh & 15;
  const int tid = threadIdx.x;
  float sum = 0.f, sq = 0.f;
  for (int idx = tid; idx < TT * DD / 4; idx += 256) {
    const int t = idx / (DD / 4);
    const int e4 = (idx % (DD / 4)) * 4;
    const float4 v = *(const float4*)(att + ((size_t)(b * TT + t)) * CC + h * DD + e4);
    sum += v.x + v.y + v.z + v.w;
    sq += v.x * v.x + v.y * v.y + v.z * v.z + v.w * v.w;
  }
  __shared__ float s1[256], s2[256];
  s1[tid] = sum; s2[tid] = sq;
  __syncthreads();
  for (int off = 128; off; off >>= 1) {
    if (tid < off) { s1[tid] += s1[tid + off]; s2[tid] += s2[tid + off]; }
    __syncthreads();
  }
  if (tid == 0) {
    const float n = (float)(TT * DD);
    const float mean = s1[0] / n;
    const float var = s2[0] / n - mean * mean;
    stats[bh * 2] = mean;
    stats[bh * 2 + 1] = rsqrtf(var + GN_EPS);
  }
}

// ---------------------------------------------------------------------------
// normalize + gate (bf16 gate) -> bf16.
// ---------------------------------------------------------------------------
__global__ __launch_bounds__(256)
void norm_gate(const float* __restrict__ att, const __bf16* __restrict__ gate,
               const float* __restrict__ stats, __bf16* __restrict__ g)
{
  const size_t gid = ((size_t)blockIdx.x * 256 + threadIdx.x) * 4;
  if (gid >= (size_t)BB * TT * CC) return;
  const int cpos = (int)(gid % CC);
  const int b = (int)(gid / ((size_t)TT * CC));
  const int bh = b * HH + (cpos >> 7);
  const float mean = stats[bh * 2], rstd = stats[bh * 2 + 1];
  const float4 a = *(const float4*)(att + gid);
  const bf16x4 gt = *(const bf16x4*)(gate + gid);
  bf16x4 o;
  o[0] = (__bf16)((a.x - mean) * rstd * (float)gt[0]);
  o[1] = (__bf16)((a.y - mean) * rstd * (float)gt[1]);
  o[2] = (__bf16)((a.z - mean) * rstd * (float)gt[2]);
  o[3] = (__bf16)((a.w - mean) * rstd * (float)gt[3]);
  *(bf16x4*)(g + gid) = o;
}

// ---------------------------------------------------------------------------
extern "C" void kernel_launch(void* const* d_in, const int* in_sizes, int n_in,
                              void* d_out, int out_size, void* d_ws, size_t ws_size,
                              hipStream_t stream)
{
  const float* x      = (const float*)d_in[0];
  const float* st0    = (const float*)d_in[1];
  const float* Wq     = (const float*)d_in[2];
  const float* Wk     = (const float*)d_in[3];
  const float* Wv     = (const float*)d_in[4];
  const float* Wbeta  = (const float*)d_in[5];
  const float* Wgate  = (const float*)d_in[6];
  const float* Wo     = (const float*)d_in[7];
  const float* wqc    = (const float*)d_in[8];
  const float* wkc    = (const float*)d_in[9];
  const float* wvc    = (const float*)d_in[10];

  float* ws = (float*)d_ws;
  __bf16* qbf  = (__bf16*)(ws + 0);          // 8388608 bf16
  __bf16* kbf  = (__bf16*)(ws + 4194304);    // 8388608 bf16
  __bf16* vbf  = (__bf16*)(ws + 8388608);    // 8388608 bf16 -> statesT later
  __bf16* kT   = (__bf16*)(ws + 12582912);   // 8388608 bf16 -> gbf later
  __bf16* vT   = (__bf16*)(ws + 16777216);   // 8388608 bf16
  __bf16* xbf  = (__bf16*)(ws + 20971520);   // 8388608 bf16
  __bf16* Wgb  = (__bf16*)(ws + 25165824);   // 4194304 bf16
  __bf16* Wob  = (__bf16*)(ws + 27262976);   // 4194304 bf16
  __bf16* Wqb  = (__bf16*)(ws + 29360128);   // 4194304 bf16 ┐
  __bf16* Wkb  = (__bf16*)(ws + 31457280);   // 4194304 bf16 │ contribT/gate span
  __bf16* Wvb  = (__bf16*)(ws + 33554432);   // 4194304 bf16 ┘
  float* contribT = ws + 29360128;           // 8388608 f
  __bf16* gatebuf = (__bf16*)(ws + 29360128);// 8388608 bf16 (after phaseC)
  __bf16* statesT = (__bf16*)(ws + 8388608); // 8388608 bf16
  __bf16* gbf     = (__bf16*)(ws + 12582912);// 8388608 bf16
  float* betab    = ws + 37748736;           // 65536
  float* decay    = ws + 37814272;           // 512
  float* stats    = ws + 37814784;           // 64
  float* state0T  = ws + 37814848;           // 524288
  float* stateOutT= ws + 38339136;           // 524288

  float* y_out  = (float*)d_out;
  float* st_out = (float*)d_out + (size_t)BB * TT * EE;
  __bf16* u  = (__bf16*)d_out;               // bf16 pre-activation scratch
  float* att = y_out;

  const dim3 blk(256);
  const dim3 gB(CC / 128, (BB * TT) / 128);
  const dim3 gTr(TT / 64, DD / 64, BB * HH);
  const dim3 gTrS(2, 2, BB * HH);
  const dim3 gScan(NC, HH, BB);
  const float qscale = 0.08838834764831845f;

  // conversions
  f2b<<<dim3(8192), blk, 0, stream>>>(x, xbf, BB * TT * EE);
  f2b<<<dim3(4096), blk, 0, stream>>>(Wq, Wqb, CC * EE);
  f2b<<<dim3(4096), blk, 0, stream>>>(Wk, Wkb, CC * EE);
  f2b<<<dim3(4096), blk, 0, stream>>>(Wv, Wvb, CC * EE);
  f2b<<<dim3(4096), blk, 0, stream>>>(Wgate, Wgb, CC * EE);
  f2b<<<dim3(4096), blk, 0, stream>>>(Wo, Wob, EE * CC);

  // beta (fp32, dedicated kernel)
  beta_ker<<<dim3((BB * TT) / 4), blk, 0, stream>>>(x, Wbeta, betab);

  // projections + conv/silu (all bf16)
  gemm_bf16<0, __bf16><<<gB, blk, 0, stream>>>(xbf, Wqb, u, BB * TT, CC, EE);
  conv_silu_b8<<<dim3(4096), blk, 0, stream>>>(u, wqc, qbf, qscale);
  gemm_bf16<0, __bf16><<<gB, blk, 0, stream>>>(xbf, Wkb, u, BB * TT, CC, EE);
  conv_silu_b8<<<dim3(4096), blk, 0, stream>>>(u, wkc, kbf, 1.f);
  gemm_bf16<0, __bf16><<<gB, blk, 0, stream>>>(xbf, Wvb, u, BB * TT, CC, EE);
  conv_silu_b8<<<dim3(4096), blk, 0, stream>>>(u, wvc, vbf, 1.f);

  // k,v transposes -> (B,H,D,T)
  tr_bf16<<<gTr, blk, 0, stream>>>(kbf, kT);
  tr_bf16<<<gTr, blk, 0, stream>>>(vbf, vT);

  // state0 transpose -> [bh][e][d]
  tr_f32<<<gTrS, blk, 0, stream>>>(st0, state0T);

  // chunked delta scan (MFMA)
  phaseA_mfma<<<gScan, blk, 0, stream>>>(kT, vT, betab, contribT, decay);
  phaseB_T<<<dim3((BB * HH * DD * DD) / 256), blk, 0, stream>>>(state0T, contribT, decay, statesT, stateOutT);
  tr_f32<<<gTrS, blk, 0, stream>>>(stateOutT, st_out);
  phaseC_mfma<<<gScan, blk, 0, stream>>>(qbf, kbf, vT, betab, statesT, att);

  // gate = sigmoid(xbf @ Wgb^T) -> bf16
  gemm_bf16<1, __bf16><<<gB, blk, 0, stream>>>(xbf, Wgb, gatebuf, BB * TT, CC, EE);

  // groupnorm + gate -> bf16
  gn_stats<<<dim3(BB * HH), blk, 0, stream>>>(att, stats);
  norm_gate<<<dim3((BB * TT * CC) / (256 * 4)), blk, 0, stream>>>(att, gatebuf, stats, gbf);

  // y = g @ Wo^T
  gemm_bf16<0, float><<<dim3(EE / 128, (BB * TT) / 128), blk, 0, stream>>>(gbf, Wob, y_out, BB * TT, EE, CC);
}

// Round 5
// 459.583 us; speedup vs baseline: 6.7011x; 1.2606x over previous
//
#include <hip/hip_runtime.h>
#include <hip/hip_bf16.h>
#include <math.h>

#define BB 2
#define TT 2048
#define EE 2048
#define HH 16
#define DD 128
#define CC 2048
#define KCONV 4
#define CHUNK 128
#define NC 16          // TT / CHUNK
#define GN_EPS 1e-5f

typedef __bf16 bf16x8 __attribute__((ext_vector_type(8)));
typedef __bf16 bf16x4 __attribute__((ext_vector_type(4)));
typedef float  f32x4  __attribute__((ext_vector_type(4)));

#define GLD16(gp, lp)                                                          \
  __builtin_amdgcn_global_load_lds(                                            \
      (const __attribute__((address_space(1))) void*)(gp),                     \
      (__attribute__((address_space(3))) void*)(lp), 16, 0, 0)

// swizzled fragment load: row-major [128][128] bf16 tile, 16B-group XOR swizzle
__device__ __forceinline__ bf16x8 ldfrag(const __bf16* buf, int row, int kg)
{
  return *(const bf16x8*)(buf + row * 128 + ((kg ^ (row & 7)) << 3));
}

// ---------------------------------------------------------------------------
// f32 -> bf16 conversion, float4-vectorized.
// ---------------------------------------------------------------------------
__global__ __launch_bounds__(256)
void f2b(const float* __restrict__ in, __bf16* __restrict__ out, int n)
{
  const int i = (blockIdx.x * 256 + threadIdx.x) * 4;
  if (i >= n) return;
  const float4 v = *(const float4*)(in + i);
  bf16x4 o;
  o[0] = (__bf16)v.x; o[1] = (__bf16)v.y; o[2] = (__bf16)v.z; o[3] = (__bf16)v.w;
  *(bf16x4*)(out + i) = o;
}

// ---------------------------------------------------------------------------
// beta = sigmoid(x @ Wbeta^T), x fp32 (B*T, E), Wbeta (16, E).
// ---------------------------------------------------------------------------
__global__ __launch_bounds__(256)
void beta_ker(const float* __restrict__ x, const float* __restrict__ Wb,
              float* __restrict__ betab)
{
  __shared__ float wsb[16 * 1024];   // 64 KB
  const int tid = threadIdx.x;
  const int w = tid >> 6, lane = tid & 63;
  const int row = blockIdx.x * 4 + w;           // < B*T = 4096
  const float* xrow = x + (size_t)row * EE;

  float acc[16] = {};
#pragma unroll
  for (int kt = 0; kt < 2; ++kt) {
    __syncthreads();
#pragma unroll
    for (int it = 0; it < 16; ++it) {
      const int i = tid + it * 256;
      const int h = i >> 8, kq = i & 255;
      *(float4*)&wsb[h * 1024 + kq * 4] =
          *(const float4*)(Wb + (size_t)h * EE + kt * 1024 + kq * 4);
    }
    __syncthreads();
#pragma unroll
    for (int j = 0; j < 4; ++j) {
      const int kof = lane * 4 + j * 256;
      const float4 xv = *(const float4*)(xrow + kt * 1024 + kof);
#pragma unroll
      for (int h = 0; h < 16; ++h) {
        const float4 wv = *(const float4*)&wsb[h * 1024 + kof];
        acc[h] += xv.x * wv.x + xv.y * wv.y + xv.z * wv.z + xv.w * wv.w;
      }
    }
  }
#pragma unroll
  for (int h = 0; h < 16; ++h) {
#pragma unroll
    for (int off = 32; off; off >>= 1)
      acc[h] += __shfl_xor(acc[h], off, 64);
  }
#pragma unroll
  for (int h = 0; h < 16; ++h)
    if (lane == h)
      betab[(size_t)row * HH + h] = 1.f / (1.f + expf(-acc[h]));
}

// ---------------------------------------------------------------------------
// bf16 MFMA GEMM, NT (m97 structure). OT = output type (float or __bf16).
// ---------------------------------------------------------------------------
template <int ACT, typename OT>
__global__ __launch_bounds__(256)
void gemm_bf16(const __bf16* __restrict__ A, const __bf16* __restrict__ Bm,
               OT* __restrict__ Cm, int M, int N, int K)
{
  __shared__ __attribute__((aligned(16))) __bf16 As[128 * 32];
  __shared__ __attribute__((aligned(16))) __bf16 Bs[128 * 32];

  const int tid  = threadIdx.x;
  const int w    = tid >> 6;
  const int lane = tid & 63;
  const int m0 = blockIdx.y * 128, n0 = blockIdx.x * 128;
  const int wm = w >> 1, wn = w & 1;

  const int srow = lane >> 2;
  const int sk   = (lane & 3) * 8;
  const __bf16* aA0 = A  + (size_t)(m0 + w * 32 + srow) * K + sk;
  const __bf16* aA1 = aA0 + (size_t)16 * K;
  const __bf16* aB0 = Bm + (size_t)(n0 + w * 32 + srow) * K + sk;
  const __bf16* aB1 = aB0 + (size_t)16 * K;
  __bf16* lA0 = As + (w * 2 + 0) * 512;
  __bf16* lA1 = As + (w * 2 + 1) * 512;
  __bf16* lB0 = Bs + (w * 2 + 0) * 512;
  __bf16* lB1 = Bs + (w * 2 + 1) * 512;

  const int fr = lane & 15;
  const int fk = (lane >> 4) * 8;
  const __bf16* rA = As + (size_t)(wm * 64 + fr) * 32 + fk;
  const __bf16* rB = Bs + (size_t)(wn * 64 + fr) * 32 + fk;

  f32x4 acc[4][4] = {};

  for (int k0 = 0; k0 < K; k0 += 32) {
    __syncthreads();
    GLD16(aA0, lA0); GLD16(aA1, lA1);
    GLD16(aB0, lB0); GLD16(aB1, lB1);
    aA0 += 32; aA1 += 32; aB0 += 32; aB1 += 32;
    asm volatile("s_waitcnt vmcnt(0)" ::: "memory");
    __syncthreads();

    bf16x8 af[4], bfr[4];
#pragma unroll
    for (int i = 0; i < 4; ++i) af[i]  = *(const bf16x8*)(rA + i * 512);
#pragma unroll
    for (int j = 0; j < 4; ++j) bfr[j] = *(const bf16x8*)(rB + j * 512);
#pragma unroll
    for (int i = 0; i < 4; ++i)
#pragma unroll
      for (int j = 0; j < 4; ++j)
        acc[i][j] = __builtin_amdgcn_mfma_f32_16x16x32_bf16(af[i], bfr[j], acc[i][j], 0, 0, 0);
  }

  const int crow0 = (lane >> 4) * 4;
#pragma unroll
  for (int i = 0; i < 4; ++i) {
#pragma unroll
    for (int j = 0; j < 4; ++j) {
      const int n = n0 + wn * 64 + j * 16 + fr;
#pragma unroll
      for (int r = 0; r < 4; ++r) {
        const int m = m0 + wm * 64 + i * 16 + crow0 + r;
        float vv = acc[i][j][r];
        if (ACT == 1) vv = 1.f / (1.f + expf(-vv));
        Cm[(size_t)m * N + n] = (OT)vv;
      }
    }
  }
}

// ---------------------------------------------------------------------------
// merged QKV GEMM: A (M,K) bf16 x Wcat (6144,K) bf16 -> three (M,2048) bf16
// pre-activation buffers. Tiles never straddle projections (2048 % 128 == 0).
// ---------------------------------------------------------------------------
__global__ __launch_bounds__(256)
void gemm_qkv(const __bf16* __restrict__ A, const __bf16* __restrict__ Bm,
              __bf16* __restrict__ u0, __bf16* __restrict__ u1,
              __bf16* __restrict__ u2, int M, int K)
{
  __shared__ __attribute__((aligned(16))) __bf16 As[128 * 32];
  __shared__ __attribute__((aligned(16))) __bf16 Bs[128 * 32];

  const int tid  = threadIdx.x;
  const int w    = tid >> 6;
  const int lane = tid & 63;
  const int m0 = blockIdx.y * 128, n0 = blockIdx.x * 128;
  const int wm = w >> 1, wn = w & 1;

  const int srow = lane >> 2;
  const int sk   = (lane & 3) * 8;
  const __bf16* aA0 = A  + (size_t)(m0 + w * 32 + srow) * K + sk;
  const __bf16* aA1 = aA0 + (size_t)16 * K;
  const __bf16* aB0 = Bm + (size_t)(n0 + w * 32 + srow) * K + sk;
  const __bf16* aB1 = aB0 + (size_t)16 * K;
  __bf16* lA0 = As + (w * 2 + 0) * 512;
  __bf16* lA1 = As + (w * 2 + 1) * 512;
  __bf16* lB0 = Bs + (w * 2 + 0) * 512;
  __bf16* lB1 = Bs + (w * 2 + 1) * 512;

  const int fr = lane & 15;
  const int fk = (lane >> 4) * 8;
  const __bf16* rA = As + (size_t)(wm * 64 + fr) * 32 + fk;
  const __bf16* rB = Bs + (size_t)(wn * 64 + fr) * 32 + fk;

  f32x4 acc[4][4] = {};

  for (int k0 = 0; k0 < K; k0 += 32) {
    __syncthreads();
    GLD16(aA0, lA0); GLD16(aA1, lA1);
    GLD16(aB0, lB0); GLD16(aB1, lB1);
    aA0 += 32; aA1 += 32; aB0 += 32; aB1 += 32;
    asm volatile("s_waitcnt vmcnt(0)" ::: "memory");
    __syncthreads();

    bf16x8 af[4], bfr[4];
#pragma unroll
    for (int i = 0; i < 4; ++i) af[i]  = *(const bf16x8*)(rA + i * 512);
#pragma unroll
    for (int j = 0; j < 4; ++j) bfr[j] = *(const bf16x8*)(rB + j * 512);
#pragma unroll
    for (int i = 0; i < 4; ++i)
#pragma unroll
      for (int j = 0; j < 4; ++j)
        acc[i][j] = __builtin_amdgcn_mfma_f32_16x16x32_bf16(af[i], bfr[j], acc[i][j], 0, 0, 0);
  }

  __bf16* outp = (n0 < 2048) ? u0 : (n0 < 4096) ? u1 : u2;
  const int nb = n0 & 2047;
  const int crow0 = (lane >> 4) * 4;
#pragma unroll
  for (int i = 0; i < 4; ++i) {
#pragma unroll
    for (int j = 0; j < 4; ++j) {
      const int n = nb + wn * 64 + j * 16 + fr;
#pragma unroll
      for (int r = 0; r < 4; ++r) {
        const int m = m0 + wm * 64 + i * 16 + crow0 + r;
        outp[(size_t)m * 2048 + n] = (__bf16)acc[i][j][r];
      }
    }
  }
}

// ---------------------------------------------------------------------------
// causal dwconv(K=4) + silu + scale, bf16 in -> bf16 out, 8 ch/thread.
// ---------------------------------------------------------------------------
__global__ __launch_bounds__(256)
void conv_silu_b8(const __bf16* __restrict__ u, const float* __restrict__ wconv,
                  __bf16* __restrict__ out, float scale)
{
  const int idx = blockIdx.x * 256 + threadIdx.x;   // over B*T*C/8
  const int c8 = (idx & (CC / 8 - 1)) * 8;
  const int t  = (idx >> 8) & (TT - 1);
  const int b  = idx >> 19;
  const size_t base = ((size_t)(b * TT + t)) * CC + c8;

  const bf16x8 z = {};
  const bf16x8 u0 = *(const bf16x8*)(u + base);
  const bf16x8 u1 = (t >= 1) ? *(const bf16x8*)(u + base - CC)     : z;
  const bf16x8 u2 = (t >= 2) ? *(const bf16x8*)(u + base - 2 * CC) : z;
  const bf16x8 u3 = (t >= 3) ? *(const bf16x8*)(u + base - 3 * CC) : z;

  bf16x8 o;
#pragma unroll
  for (int jj = 0; jj < 8; ++jj) {
    const float4 wv = *(const float4*)(wconv + (size_t)(c8 + jj) * 4);
    const float vv = wv.x * (float)u3[jj] + wv.y * (float)u2[jj]
                   + wv.z * (float)u1[jj] + wv.w * (float)u0[jj];
    o[jj] = (__bf16)(vv / (1.f + expf(-vv)) * scale);
  }
  *(bf16x8*)(out + base) = o;
}

// ---------------------------------------------------------------------------
// bf16 transpose (B,T,C[h,d]) -> (B,H,D,T), 64x64 tiles through LDS.
// ---------------------------------------------------------------------------
__global__ __launch_bounds__(256)
void tr_bf16(const __bf16* __restrict__ src, __bf16* __restrict__ dst)
{
  const int t0 = blockIdx.x * 64, d0 = blockIdx.y * 64;
  const int bh = blockIdx.z, b = bh >> 4, h = bh & 15;
  const int tid = threadIdx.x;
  __shared__ __attribute__((aligned(16))) __bf16 tile[64][72];

#pragma unroll
  for (int it = 0; it < 2; ++it) {
    const int idx = tid + it * 256;
    const int tl = idx >> 3, g = idx & 7;
    const bf16x8 v = *(const bf16x8*)(src + ((size_t)(b * TT + t0 + tl)) * CC + h * DD + d0 + g * 8);
    *(bf16x8*)&tile[tl][g * 8] = v;
  }
  __syncthreads();
#pragma unroll
  for (int it = 0; it < 2; ++it) {
    const int idx = tid + it * 256;
    const int dl = idx >> 3, g = idx & 7;
    bf16x8 o;
#pragma unroll
    for (int jj = 0; jj < 8; ++jj) o[jj] = tile[g * 8 + jj][dl];
    *(bf16x8*)(dst + ((size_t)(bh * DD + d0 + dl)) * TT + t0 + g * 8) = o;
  }
}

// ---------------------------------------------------------------------------
// fp32 128x128 transpose per bh. grid (2,2,BB*HH).
// ---------------------------------------------------------------------------
__global__ __launch_bounds__(256)
void tr_f32(const float* __restrict__ in, float* __restrict__ out)
{
  const int r0 = blockIdx.x * 64, c0 = blockIdx.y * 64;
  const int bh = blockIdx.z;
  const int tid = threadIdx.x;
  __shared__ float tile[64][65];

#pragma unroll
  for (int it = 0; it < 4; ++it) {
    const int idx = tid + it * 256;
    const int rl = idx >> 4, g = idx & 15;
    const float4 v = *(const float4*)(in + (size_t)bh * 16384 + (r0 + rl) * 128 + c0 + g * 4);
    tile[rl][g * 4 + 0] = v.x; tile[rl][g * 4 + 1] = v.y;
    tile[rl][g * 4 + 2] = v.z; tile[rl][g * 4 + 3] = v.w;
  }
  __syncthreads();
#pragma unroll
  for (int it = 0; it < 4; ++it) {
    const int idx = tid + it * 256;
    const int cl = idx >> 4, g = idx & 15;
    float4 o;
    o.x = tile[g * 4 + 0][cl]; o.y = tile[g * 4 + 1][cl];
    o.z = tile[g * 4 + 2][cl]; o.w = tile[g * 4 + 3][cl];
    *(float4*)(out + (size_t)bh * 16384 + (c0 + cl) * 128 + r0 + g * 4) = o;
  }
}

// ---------------------------------------------------------------------------
// Phase A (MFMA): contribT[e][d] = sum_s (w_s k_s[d]) v_s[e];  decay out.
// ---------------------------------------------------------------------------
__global__ __launch_bounds__(256)
void phaseA_mfma(const __bf16* __restrict__ kT, const __bf16* __restrict__ vT,
                 const float* __restrict__ beta, float* __restrict__ contribT,
                 float* __restrict__ decay)
{
  const int c = blockIdx.x, h = blockIdx.y, b = blockIdx.z;
  const int bh = b * HH + h;
  const int tid = threadIdx.x;
  const int w = tid >> 6, lane = tid & 63;
  const int wm = w >> 1, wn = w & 1;

  __shared__ __attribute__((aligned(16))) __bf16 bufVT[128 * 128];
  __shared__ __attribute__((aligned(16))) __bf16 bufKW[128 * 128];
  __shared__ float lc[CHUNK], bsh[CHUNK], wgt[CHUNK];

  {
    const __bf16* vbase = vT + ((size_t)bh * DD) * TT + c * CHUNK;
#pragma unroll
    for (int jj = 0; jj < 8; ++jj) {
      const int row = w * 32 + jj * 4 + (lane >> 4);
      const int g = lane & 15;
      GLD16(vbase + (size_t)row * TT + ((g ^ (row & 7)) << 3),
            bufVT + (w * 32 + jj * 4) * 128);
    }
  }

  if (tid < CHUNK) {
    const float bv = beta[(size_t)(b * TT + c * CHUNK + tid) * HH + h];
    bsh[tid] = bv;
    lc[tid] = log1pf(-bv);
  }
  __syncthreads();
  for (int off = 1; off < CHUNK; off <<= 1) {
    float add = 0.f;
    if (tid < CHUNK && tid >= off) add = lc[tid - off];
    __syncthreads();
    if (tid < CHUNK) lc[tid] += add;
    __syncthreads();
  }
  const float lend = lc[CHUNK - 1];
  if (tid < CHUNK) wgt[tid] = bsh[tid] * expf(lend - lc[tid]);
  if (tid == 0) decay[(size_t)bh * NC + c] = expf(lend);
  __syncthreads();

  {
    const __bf16* kbase = kT + ((size_t)bh * DD) * TT + c * CHUNK;
#pragma unroll
    for (int it = 0; it < 8; ++it) {
      const int idx = tid + it * 256;
      const int d = idx >> 4, g = idx & 15;
      const bf16x8 kv = *(const bf16x8*)(kbase + (size_t)d * TT + g * 8);
      bf16x8 o;
#pragma unroll
      for (int jj = 0; jj < 8; ++jj)
        o[jj] = (__bf16)((float)kv[jj] * wgt[g * 8 + jj]);
      *(bf16x8*)(bufKW + d * 128 + ((g ^ (d & 7)) << 3)) = o;
    }
  }
  asm volatile("s_waitcnt vmcnt(0)" ::: "memory");
  __syncthreads();

  f32x4 acc[4][4] = {};
#pragma unroll
  for (int ks = 0; ks < 4; ++ks) {
    bf16x8 a[4], bq[4];
    const int kg = ks * 4 + (lane >> 4);
#pragma unroll
    for (int f = 0; f < 4; ++f) a[f]  = ldfrag(bufVT, wm * 64 + f * 16 + (lane & 15), kg);
#pragma unroll
    for (int f = 0; f < 4; ++f) bq[f] = ldfrag(bufKW, wn * 64 + f * 16 + (lane & 15), kg);
#pragma unroll
    for (int i = 0; i < 4; ++i)
#pragma unroll
      for (int j = 0; j < 4; ++j)
        acc[i][j] = __builtin_amdgcn_mfma_f32_16x16x32_bf16(a[i], bq[j], acc[i][j], 0, 0, 0);
  }

  float* cp = contribT + ((size_t)(bh * NC + c) << 14);
  const int crow = (lane >> 4) * 4;
#pragma unroll
  for (int i = 0; i < 4; ++i)
#pragma unroll
    for (int j = 0; j < 4; ++j) {
      const int dd = wn * 64 + j * 16 + (lane & 15);
#pragma unroll
      for (int r = 0; r < 4; ++r) {
        const int e = wm * 64 + i * 16 + crow + r;
        cp[(size_t)e * 128 + dd] = acc[i][j][r];
      }
    }
}

// ---------------------------------------------------------------------------
// Phase B (transposed space).
// ---------------------------------------------------------------------------
__global__ __launch_bounds__(256)
void phaseB_T(const float* __restrict__ state0T, const float* __restrict__ contribT,
              const float* __restrict__ decay, __bf16* __restrict__ statesT,
              float* __restrict__ stateOutT)
{
  const size_t gid = (size_t)blockIdx.x * 256 + threadIdx.x;
  const int bh = (int)(gid >> 14);
  float s = state0T[gid];
  const float* dc = decay + (size_t)bh * NC;
  const int ed = (int)(gid & 16383);
#pragma unroll
  for (int c = 0; c < NC; ++c) {
    const size_t off = ((size_t)(bh * NC + c) << 14) + ed;
    statesT[off] = (__bf16)s;
    s = fmaf(dc[c], s, contribT[off]);
  }
  stateOutT[gid] = s;
}

// ---------------------------------------------------------------------------
// Phase C (MFMA) + fused GroupNorm partial stats.
// ---------------------------------------------------------------------------
__global__ __launch_bounds__(256)
void phaseC_mfma(const __bf16* __restrict__ qb, const __bf16* __restrict__ kb,
                 const __bf16* __restrict__ vT, const float* __restrict__ beta,
                 const __bf16* __restrict__ statesT, float* __restrict__ att,
                 float* __restrict__ partials)
{
  const int c = blockIdx.x, h = blockIdx.y, b = blockIdx.z;
  const int bh = b * HH + h;
  const int tid = threadIdx.x;
  const int w = tid >> 6, lane = tid & 63;
  const int wm = w >> 1, wn = w & 1;

  __shared__ __attribute__((aligned(16))) __bf16 bufQ[128 * 128];
  __shared__ __attribute__((aligned(16))) __bf16 bufB[128 * 128];
  __shared__ float lc[CHUNK], bsh[CHUNK];
  __shared__ float s1[256], s2[256];

  {
    const __bf16* qbase = qb + ((size_t)(b * TT + c * CHUNK)) * CC + h * DD;
    const __bf16* kbase = kb + ((size_t)(b * TT + c * CHUNK)) * CC + h * DD;
#pragma unroll
    for (int jj = 0; jj < 8; ++jj) {
      const int row = w * 32 + jj * 4 + (lane >> 4);
      const int g = lane & 15;
      GLD16(qbase + (size_t)row * CC + ((g ^ (row & 7)) << 3),
            bufQ + (w * 32 + jj * 4) * 128);
      GLD16(kbase + (size_t)row * CC + ((g ^ (row & 7)) << 3),
            bufB + (w * 32 + jj * 4) * 128);
    }
  }

  if (tid < CHUNK) {
    const float bv = beta[(size_t)(b * TT + c * CHUNK + tid) * HH + h];
    bsh[tid] = bv;
    lc[tid] = log1pf(-bv);
  }
  __syncthreads();
  for (int off = 1; off < CHUNK; off <<= 1) {
    float add = 0.f;
    if (tid < CHUNK && tid >= off) add = lc[tid - off];
    __syncthreads();
    if (tid < CHUNK) lc[tid] += add;
    __syncthreads();
  }

  asm volatile("s_waitcnt vmcnt(0)" ::: "memory");
  __syncthreads();

  // S = Q K^T
  f32x4 accS[4][4] = {};
#pragma unroll
  for (int ks = 0; ks < 4; ++ks) {
    bf16x8 a[4], bq[4];
    const int kg = ks * 4 + (lane >> 4);
#pragma unroll
    for (int f = 0; f < 4; ++f) a[f]  = ldfrag(bufQ, wm * 64 + f * 16 + (lane & 15), kg);
#pragma unroll
    for (int f = 0; f < 4; ++f) bq[f] = ldfrag(bufB, wn * 64 + f * 16 + (lane & 15), kg);
#pragma unroll
    for (int i = 0; i < 4; ++i)
#pragma unroll
      for (int j = 0; j < 4; ++j)
        accS[i][j] = __builtin_amdgcn_mfma_f32_16x16x32_bf16(a[i], bq[j], accS[i][j], 0, 0, 0);
  }

  __syncthreads();
  {
    const __bf16* sbase = statesT + ((size_t)(bh * NC + c) << 14);
#pragma unroll
    for (int jj = 0; jj < 8; ++jj) {
      const int row = w * 32 + jj * 4 + (lane >> 4);
      const int g = lane & 15;
      GLD16(sbase + (size_t)row * 128 + ((g ^ (row & 7)) << 3),
            bufB + (w * 32 + jj * 4) * 128);
    }
  }
  asm volatile("s_waitcnt vmcnt(0)" ::: "memory");
  __syncthreads();

  // accO = Q S0T, scaled by e^{lc_t}
  f32x4 accO[4][4] = {};
#pragma unroll
  for (int ks = 0; ks < 4; ++ks) {
    bf16x8 a[4], bq[4];
    const int kg = ks * 4 + (lane >> 4);
#pragma unroll
    for (int f = 0; f < 4; ++f) a[f]  = ldfrag(bufQ, wm * 64 + f * 16 + (lane & 15), kg);
#pragma unroll
    for (int f = 0; f < 4; ++f) bq[f] = ldfrag(bufB, wn * 64 + f * 16 + (lane & 15), kg);
#pragma unroll
    for (int i = 0; i < 4; ++i)
#pragma unroll
      for (int j = 0; j < 4; ++j)
        accO[i][j] = __builtin_amdgcn_mfma_f32_16x16x32_bf16(a[i], bq[j], accO[i][j], 0, 0, 0);
  }
  const int crow = (lane >> 4) * 4;
#pragma unroll
  for (int i = 0; i < 4; ++i)
#pragma unroll
    for (int r = 0; r < 4; ++r) {
      const float el = expf(lc[wm * 64 + i * 16 + crow + r]);
#pragma unroll
      for (int j = 0; j < 4; ++j) accO[i][j][r] *= el;
    }

  __syncthreads();
  {
    const __bf16* vbase = vT + ((size_t)bh * DD) * TT + c * CHUNK;
#pragma unroll
    for (int jj = 0; jj < 8; ++jj) {
      const int row = w * 32 + jj * 4 + (lane >> 4);
      const int g = lane & 15;
      GLD16(vbase + (size_t)row * TT + ((g ^ (row & 7)) << 3),
            bufB + (w * 32 + jj * 4) * 128);
    }
  }
  {
    float lcs[4], bss[4];
#pragma unroll
    for (int j = 0; j < 4; ++j) {
      const int s = wn * 64 + j * 16 + (lane & 15);
      lcs[j] = lc[s]; bss[j] = bsh[s];
    }
#pragma unroll
    for (int i = 0; i < 4; ++i)
#pragma unroll
      for (int r = 0; r < 4; ++r) {
        const int t = wm * 64 + i * 16 + crow + r;
        const float lct = lc[t];
#pragma unroll
        for (int j = 0; j < 4; ++j) {
          const int s = wn * 64 + j * 16 + (lane & 15);
          float p = 0.f;
          if (s <= t) p = accS[i][j][r] * bss[j] * expf(lct - lcs[j]);
          bufQ[t * 128 + (((s >> 3) ^ (t & 7)) << 3) + (s & 7)] = (__bf16)p;
        }
      }
  }
  asm volatile("s_waitcnt vmcnt(0)" ::: "memory");
  __syncthreads();

  // accO += P V^T
#pragma unroll
  for (int ks = 0; ks < 4; ++ks) {
    bf16x8 a[4], bq[4];
    const int kg = ks * 4 + (lane >> 4);
#pragma unroll
    for (int f = 0; f < 4; ++f) a[f]  = ldfrag(bufQ, wm * 64 + f * 16 + (lane & 15), kg);
#pragma unroll
    for (int f = 0; f < 4; ++f) bq[f] = ldfrag(bufB, wn * 64 + f * 16 + (lane & 15), kg);
#pragma unroll
    for (int i = 0; i < 4; ++i)
#pragma unroll
      for (int j = 0; j < 4; ++j)
        accO[i][j] = __builtin_amdgcn_mfma_f32_16x16x32_bf16(a[i], bq[j], accO[i][j], 0, 0, 0);
  }

  // epilogue: store att + accumulate GN partial stats
  float lsum = 0.f, lsq = 0.f;
  float* obase = att + ((size_t)(b * TT + c * CHUNK)) * CC + h * DD;
#pragma unroll
  for (int i = 0; i < 4; ++i)
#pragma unroll
    for (int j = 0; j < 4; ++j) {
      const int e = wn * 64 + j * 16 + (lane & 15);
#pragma unroll
      for (int r = 0; r < 4; ++r) {
        const int t = wm * 64 + i * 16 + crow + r;
        const float vv = accO[i][j][r];
        obase[(size_t)t * CC + e] = vv;
        lsum += vv;
        lsq  += vv * vv;
      }
    }
  s1[tid] = lsum; s2[tid] = lsq;
  __syncthreads();
  for (int off = 128; off; off >>= 1) {
    if (tid < off) { s1[tid] += s1[tid + off]; s2[tid] += s2[tid + off]; }
    __syncthreads();
  }
  if (tid == 0) {
    partials[(size_t)(bh * NC + c) * 2]     = s1[0];
    partials[(size_t)(bh * NC + c) * 2 + 1] = s2[0];
  }
}

// ---------------------------------------------------------------------------
// combine GN partials -> stats. grid (BB*HH), 64 threads.
// ---------------------------------------------------------------------------
__global__ __launch_bounds__(64)
void gn_combine(const float* __restrict__ partials, float* __restrict__ stats)
{
  const int bh = blockIdx.x;
  const int lane = threadIdx.x;
  float s = 0.f, q = 0.f;
  if (lane < NC) {
    s = partials[(size_t)(bh * NC + lane) * 2];
    q = partials[(size_t)(bh * NC + lane) * 2 + 1];
  }
#pragma unroll
  for (int off = 8; off; off >>= 1) {
    s += __shfl_xor(s, off, 64);
    q += __shfl_xor(q, off, 64);
  }
  if (lane == 0) {
    const float n = (float)(TT * DD);
    const float mean = s / n;
    const float var = q / n - mean * mean;
    stats[bh * 2] = mean;
    stats[bh * 2 + 1] = rsqrtf(var + GN_EPS);
  }
}

// ---------------------------------------------------------------------------
// normalize + gate (bf16 gate) -> bf16.
// ---------------------------------------------------------------------------
__global__ __launch_bounds__(256)
void norm_gate(const float* __restrict__ att, const __bf16* __restrict__ gate,
               const float* __restrict__ stats, __bf16* __restrict__ g)
{
  const size_t gid = ((size_t)blockIdx.x * 256 + threadIdx.x) * 4;
  if (gid >= (size_t)BB * TT * CC) return;
  const int cpos = (int)(gid % CC);
  const int b = (int)(gid / ((size_t)TT * CC));
  const int bh = b * HH + (cpos >> 7);
  const float mean = stats[bh * 2], rstd = stats[bh * 2 + 1];
  const float4 a = *(const float4*)(att + gid);
  const bf16x4 gt = *(const bf16x4*)(gate + gid);
  bf16x4 o;
  o[0] = (__bf16)((a.x - mean) * rstd * (float)gt[0]);
  o[1] = (__bf16)((a.y - mean) * rstd * (float)gt[1]);
  o[2] = (__bf16)((a.z - mean) * rstd * (float)gt[2]);
  o[3] = (__bf16)((a.w - mean) * rstd * (float)gt[3]);
  *(bf16x4*)(g + gid) = o;
}

// ---------------------------------------------------------------------------
extern "C" void kernel_launch(void* const* d_in, const int* in_sizes, int n_in,
                              void* d_out, int out_size, void* d_ws, size_t ws_size,
                              hipStream_t stream)
{
  const float* x      = (const float*)d_in[0];
  const float* st0    = (const float*)d_in[1];
  const float* Wq     = (const float*)d_in[2];
  const float* Wk     = (const float*)d_in[3];
  const float* Wv     = (const float*)d_in[4];
  const float* Wbeta  = (const float*)d_in[5];
  const float* Wgate  = (const float*)d_in[6];
  const float* Wo     = (const float*)d_in[7];
  const float* wqc    = (const float*)d_in[8];
  const float* wkc    = (const float*)d_in[9];
  const float* wvc    = (const float*)d_in[10];

  float* ws = (float*)d_ws;
  __bf16* qbf  = (__bf16*)(ws + 0);           // 8.4M bf16
  __bf16* kbf  = (__bf16*)(ws + 4194304);     // 8.4M bf16
  __bf16* vbf  = (__bf16*)(ws + 8388608);     // -> statesT later
  __bf16* u_v  = (__bf16*)(ws + 12582912);    // pre-act v; -> kT -> gbf
  __bf16* kT   = (__bf16*)(ws + 12582912);
  __bf16* gbf  = (__bf16*)(ws + 12582912);
  __bf16* vT   = (__bf16*)(ws + 16777216);
  __bf16* xbf  = (__bf16*)(ws + 20971520);
  __bf16* Wcat = (__bf16*)(ws + 25165824);    // 12.6M bf16 (6144x2048); dead after qkv GEMM
  float* contribT = ws + 25165824;            // 8.4M f (overlay Wcat span)
  __bf16* gatebuf = (__bf16*)(ws + 25165824); // 8.4M bf16 (after phaseB)
  __bf16* statesT = (__bf16*)(ws + 8388608);
  __bf16* Wgb  = (__bf16*)(ws + 33554432);    // 4.2M bf16
  __bf16* Wob  = (__bf16*)(ws + 35651584);    // 4.2M bf16
  float* betab    = ws + 37748736;            // 65536
  float* decay    = ws + 37814272;            // 512
  float* stats    = ws + 37814784;            // 64
  float* partials = ws + 37814848;            // 1024
  float* state0T  = ws + 37815872;            // 524288
  float* stateOutT= ws + 38340160;            // 524288 -> end 38864448 f

  float* y_out  = (float*)d_out;
  float* st_out = (float*)d_out + (size_t)BB * TT * EE;
  __bf16* u_q = (__bf16*)d_out;               // floats [0, 4.2M)
  __bf16* u_k = (__bf16*)d_out + 8388608;     // floats [4.2M, 8.4M)
  float* att = y_out;

  const dim3 blk(256);
  const dim3 gQKV(3 * CC / 128, (BB * TT) / 128);  // 48 x 32
  const dim3 gB(CC / 128, (BB * TT) / 128);        // 16 x 32
  const dim3 gTr(TT / 64, DD / 64, BB * HH);
  const dim3 gTrS(2, 2, BB * HH);
  const dim3 gScan(NC, HH, BB);
  const float qscale = 0.08838834764831845f;

  // conversions
  f2b<<<dim3(8192), blk, 0, stream>>>(x, xbf, BB * TT * EE);
  f2b<<<dim3(4096), blk, 0, stream>>>(Wq, Wcat, CC * EE);
  f2b<<<dim3(4096), blk, 0, stream>>>(Wk, Wcat + (size_t)CC * EE, CC * EE);
  f2b<<<dim3(4096), blk, 0, stream>>>(Wv, Wcat + (size_t)2 * CC * EE, CC * EE);
  f2b<<<dim3(4096), blk, 0, stream>>>(Wgate, Wgb, CC * EE);
  f2b<<<dim3(4096), blk, 0, stream>>>(Wo, Wob, EE * CC);

  // beta (fp32)
  beta_ker<<<dim3((BB * TT) / 4), blk, 0, stream>>>(x, Wbeta, betab);

  // merged QKV projection, then conv/silu per projection
  gemm_qkv<<<gQKV, blk, 0, stream>>>(xbf, Wcat, u_q, u_k, u_v, BB * TT, EE);
  conv_silu_b8<<<dim3(4096), blk, 0, stream>>>(u_q, wqc, qbf, qscale);
  conv_silu_b8<<<dim3(4096), blk, 0, stream>>>(u_k, wkc, kbf, 1.f);
  conv_silu_b8<<<dim3(4096), blk, 0, stream>>>(u_v, wvc, vbf, 1.f);

  // k,v transposes -> (B,H,D,T)
  tr_bf16<<<gTr, blk, 0, stream>>>(kbf, kT);
  tr_bf16<<<gTr, blk, 0, stream>>>(vbf, vT);

  // state0 transpose -> [bh][e][d]
  tr_f32<<<gTrS, blk, 0, stream>>>(st0, state0T);

  // chunked delta scan (MFMA)
  phaseA_mfma<<<gScan, blk, 0, stream>>>(kT, vT, betab, contribT, decay);
  phaseB_T<<<dim3((BB * HH * DD * DD) / 256), blk, 0, stream>>>(state0T, contribT, decay, statesT, stateOutT);
  tr_f32<<<gTrS, blk, 0, stream>>>(stateOutT, st_out);
  phaseC_mfma<<<gScan, blk, 0, stream>>>(qbf, kbf, vT, betab, statesT, att, partials);

  // gate = sigmoid(xbf @ Wgb^T) -> bf16
  gemm_bf16<1, __bf16><<<gB, blk, 0, stream>>>(xbf, Wgb, gatebuf, BB * TT, CC, EE);

  // groupnorm combine + normalize*gate -> bf16
  gn_combine<<<dim3(BB * HH), dim3(64), 0, stream>>>(partials, stats);
  norm_gate<<<dim3((BB * TT * CC) / (256 * 4)), blk, 0, stream>>>(att, gatebuf, stats, gbf);

  // y = g @ Wo^T
  gemm_bf16<0, float><<<dim3(EE / 128, (BB * TT) / 128), blk, 0, stream>>>(gbf, Wob, y_out, BB * TT, EE, CC);
}

// Round 6
// 438.776 us; speedup vs baseline: 7.0189x; 1.0474x over previous
//
#include <hip/hip_runtime.h>
#include <hip/hip_bf16.h>
#include <math.h>

#define BB 2
#define TT 2048
#define EE 2048
#define HH 16
#define DD 128
#define CC 2048
#define KCONV 4
#define CHUNK 128
#define NC 16          // TT / CHUNK
#define GN_EPS 1e-5f

typedef __bf16 bf16x8 __attribute__((ext_vector_type(8)));
typedef __bf16 bf16x4 __attribute__((ext_vector_type(4)));
typedef float  f32x4  __attribute__((ext_vector_type(4)));

#define GLD16(gp, lp)                                                          \
  __builtin_amdgcn_global_load_lds(                                            \
      (const __attribute__((address_space(1))) void*)(gp),                     \
      (__attribute__((address_space(3))) void*)(lp), 16, 0, 0)

// swizzled fragment load: row-major [128][128] bf16 tile, 16B-group XOR swizzle
__device__ __forceinline__ bf16x8 ldfrag(const __bf16* buf, int row, int kg)
{
  return *(const bf16x8*)(buf + row * 128 + ((kg ^ (row & 7)) << 3));
}

// ---------------------------------------------------------------------------
// f32 -> bf16 conversion, float4-vectorized.
// ---------------------------------------------------------------------------
__global__ __launch_bounds__(256)
void f2b(const float* __restrict__ in, __bf16* __restrict__ out, int n)
{
  const int i = (blockIdx.x * 256 + threadIdx.x) * 4;
  if (i >= n) return;
  const float4 v = *(const float4*)(in + i);
  bf16x4 o;
  o[0] = (__bf16)v.x; o[1] = (__bf16)v.y; o[2] = (__bf16)v.z; o[3] = (__bf16)v.w;
  *(bf16x4*)(out + i) = o;
}

// ---------------------------------------------------------------------------
// beta = sigmoid(x @ Wbeta^T), x fp32 (B*T, E), Wbeta (16, E).
// ---------------------------------------------------------------------------
__global__ __launch_bounds__(256)
void beta_ker(const float* __restrict__ x, const float* __restrict__ Wb,
              float* __restrict__ betab)
{
  __shared__ float wsb[16 * 1024];   // 64 KB
  const int tid = threadIdx.x;
  const int w = tid >> 6, lane = tid & 63;
  const int row = blockIdx.x * 4 + w;           // < B*T = 4096
  const float* xrow = x + (size_t)row * EE;

  float acc[16] = {};
#pragma unroll
  for (int kt = 0; kt < 2; ++kt) {
    __syncthreads();
#pragma unroll
    for (int it = 0; it < 16; ++it) {
      const int i = tid + it * 256;
      const int h = i >> 8, kq = i & 255;
      *(float4*)&wsb[h * 1024 + kq * 4] =
          *(const float4*)(Wb + (size_t)h * EE + kt * 1024 + kq * 4);
    }
    __syncthreads();
#pragma unroll
    for (int j = 0; j < 4; ++j) {
      const int kof = lane * 4 + j * 256;
      const float4 xv = *(const float4*)(xrow + kt * 1024 + kof);
#pragma unroll
      for (int h = 0; h < 16; ++h) {
        const float4 wv = *(const float4*)&wsb[h * 1024 + kof];
        acc[h] += xv.x * wv.x + xv.y * wv.y + xv.z * wv.z + xv.w * wv.w;
      }
    }
  }
#pragma unroll
  for (int h = 0; h < 16; ++h) {
#pragma unroll
    for (int off = 32; off; off >>= 1)
      acc[h] += __shfl_xor(acc[h], off, 64);
  }
#pragma unroll
  for (int h = 0; h < 16; ++h)
    if (lane == h)
      betab[(size_t)row * HH + h] = 1.f / (1.f + expf(-acc[h]));
}

// ---------------------------------------------------------------------------
// 256x256 deep-pipelined bf16 GEMM (QKV+gate merged), K=2048, BK=64.
// 8 waves (2Mx4N), per-wave C = 128x64. LDS 128 KiB (2 K-tile dbuf, swizzled).
// Schedule per K-tile t (4 phases q0..q3, one half-tile staged per phase):
//   q0: stage A0(t+1); q1: stage A1(t+1); q2: stage B0(t+2); q3: stage B1(t+2)
//   vmcnt(4) at q3 only (counted; retires exactly tile t+1's 4 halves).
// Output cols routed: [0,2048)q [2048,4096)k [4096,6144)v [6144,8192)gate(sigmoid)
// ---------------------------------------------------------------------------
__global__ __launch_bounds__(512)
void gemm_big(const __bf16* __restrict__ A, const __bf16* __restrict__ Bm,
              __bf16* __restrict__ o0, __bf16* __restrict__ o1,
              __bf16* __restrict__ o2, __bf16* __restrict__ o3)
{
  __shared__ __attribute__((aligned(16))) __bf16 ldsA[2][256][64];
  __shared__ __attribute__((aligned(16))) __bf16 ldsB[2][256][64];

  const int tid = threadIdx.x;
  const int w = tid >> 6, l = tid & 63;
  const int wm = w >> 2, wn = w & 3;          // 2 x 4 wave grid
  const int m0 = blockIdx.y * 256, n0 = blockIdx.x * 256;
  const int NT = EE / 64;                     // 32 K-tiles

  // staging: per stage-call each thread issues 2 GLD16 (one half-tile total).
  const int sr0 = w * 8 + (l >> 3);           // dest row (issue 0), 0..63
  const int skg = l & 7;                      // dest 16B chunk in 128B row
  // fragment read ids
  const int fr = l & 15;
  const int fkg = l >> 4;                     // 0..3

#define STAGE(MAT, PTR, RB, tile, half) do {                                   \
    const int b_ = (tile) & 1;                                                 \
    const int r0_ = sr0;                                                       \
    const int r1_ = 64 + sr0;                                                  \
    GLD16((PTR) + (size_t)((RB) + (half) * 128 + r0_) * 2048 + (tile) * 64     \
              + ((skg ^ (r0_ & 7)) << 3),                                      \
          &MAT[b_][(half) * 128 + w * 8][0]);                                  \
    GLD16((PTR) + (size_t)((RB) + (half) * 128 + r1_) * 2048 + (tile) * 64     \
              + ((skg ^ (r1_ & 7)) << 3),                                      \
          &MAT[b_][(half) * 128 + 64 + w * 8][0]);                             \
  } while (0)

#define LDA_FRAG(dst, buf, q, mf, ks) do {                                     \
    const int row_ = wm * 128 + (q) * 32 + (mf) * 16 + fr;                     \
    const int kg_ = (ks) * 4 + fkg;                                            \
    dst = *(const bf16x8*)&ldsA[buf][row_][((kg_ ^ (row_ & 7)) << 3)];         \
  } while (0)
#define LDB_FRAG(dst, buf, nf, ks) do {                                        \
    const int row_ = wn * 64 + (nf) * 16 + fr;                                 \
    const int kg_ = (ks) * 4 + fkg;                                            \
    dst = *(const bf16x8*)&ldsB[buf][row_][((kg_ ^ (row_ & 7)) << 3)];         \
  } while (0)

  f32x4 acc[8][4] = {};

  // prologue: tile 0 (A0,A1,B0,B1) + B halves of tile 1 -> 12 loads in flight
  STAGE(ldsA, A, m0, 0, 0);  STAGE(ldsA, A, m0, 0, 1);
  STAGE(ldsB, Bm, n0, 0, 0); STAGE(ldsB, Bm, n0, 0, 1);
  STAGE(ldsB, Bm, n0, 1, 0); STAGE(ldsB, Bm, n0, 1, 1);
  asm volatile("s_waitcnt vmcnt(4)" ::: "memory");   // tile 0 fully resident
  __syncthreads();

  for (int t = 0; t < NT; ++t) {
    const int buf = t & 1;
    bf16x8 bfr[4][2];

    // ---- phase q0: all B frags + A quadrant 0
    {
#pragma unroll
      for (int nf = 0; nf < 4; ++nf)
#pragma unroll
        for (int ks = 0; ks < 2; ++ks) LDB_FRAG(bfr[nf][ks], buf, nf, ks);
      bf16x8 af[2][2];
#pragma unroll
      for (int mf = 0; mf < 2; ++mf)
#pragma unroll
        for (int ks = 0; ks < 2; ++ks) LDA_FRAG(af[mf][ks], buf, 0, mf, ks);
      if (t + 1 < NT) STAGE(ldsA, A, m0, t + 1, 0);
      __builtin_amdgcn_s_barrier();
      __builtin_amdgcn_s_setprio(1);
#pragma unroll
      for (int mf = 0; mf < 2; ++mf)
#pragma unroll
        for (int nf = 0; nf < 4; ++nf)
#pragma unroll
          for (int ks = 0; ks < 2; ++ks)
            acc[mf][nf] = __builtin_amdgcn_mfma_f32_16x16x32_bf16(
                af[mf][ks], bfr[nf][ks], acc[mf][nf], 0, 0, 0);
      __builtin_amdgcn_s_setprio(0);
      __builtin_amdgcn_s_barrier();
    }

    // ---- phases q1..q3: A quadrants 1..3 (B frags reused from registers)
#pragma unroll
    for (int q = 1; q < 4; ++q) {
      bf16x8 af[2][2];
#pragma unroll
      for (int mf = 0; mf < 2; ++mf)
#pragma unroll
        for (int ks = 0; ks < 2; ++ks) LDA_FRAG(af[mf][ks], buf, q, mf, ks);
      if (q == 1) {
        if (t + 1 < NT) STAGE(ldsA, A, m0, t + 1, 1);
      } else if (q == 2) {
        if (t + 2 < NT) STAGE(ldsB, Bm, n0, t + 2, 0);
      } else {
        if (t + 2 < NT) STAGE(ldsB, Bm, n0, t + 2, 1);
        if (t == NT - 2) asm volatile("s_waitcnt vmcnt(0)" ::: "memory");
        else             asm volatile("s_waitcnt vmcnt(4)" ::: "memory");
      }
      __builtin_amdgcn_s_barrier();
      __builtin_amdgcn_s_setprio(1);
#pragma unroll
      for (int mf = 0; mf < 2; ++mf)
#pragma unroll
        for (int nf = 0; nf < 4; ++nf)
#pragma unroll
          for (int ks = 0; ks < 2; ++ks)
            acc[2 * q + mf][nf] = __builtin_amdgcn_mfma_f32_16x16x32_bf16(
                af[mf][ks], bfr[nf][ks], acc[2 * q + mf][nf], 0, 0, 0);
      __builtin_amdgcn_s_setprio(0);
      __builtin_amdgcn_s_barrier();
    }
  }

  // epilogue: route by projection; sigmoid for gate
  const int proj = n0 >> 11;
  const int nb = n0 & 2047;
  __bf16* outp = proj == 0 ? o0 : proj == 1 ? o1 : proj == 2 ? o2 : o3;
  const int crow = (l >> 4) * 4;
#pragma unroll
  for (int mf2 = 0; mf2 < 8; ++mf2) {
#pragma unroll
    for (int nf = 0; nf < 4; ++nf) {
      const int n = nb + wn * 64 + nf * 16 + fr;
#pragma unroll
      for (int r = 0; r < 4; ++r) {
        const int m = m0 + wm * 128 + mf2 * 16 + crow + r;
        float vv = acc[mf2][nf][r];
        if (proj == 3) vv = 1.f / (1.f + expf(-vv));
        outp[(size_t)m * 2048 + n] = (__bf16)vv;
      }
    }
  }
#undef STAGE
#undef LDA_FRAG
#undef LDB_FRAG
}

// ---------------------------------------------------------------------------
// bf16 MFMA GEMM, NT (m97 structure) — used for the Wo GEMM.
// ---------------------------------------------------------------------------
template <int ACT, typename OT>
__global__ __launch_bounds__(256)
void gemm_bf16(const __bf16* __restrict__ A, const __bf16* __restrict__ Bm,
               OT* __restrict__ Cm, int M, int N, int K)
{
  __shared__ __attribute__((aligned(16))) __bf16 As[128 * 32];
  __shared__ __attribute__((aligned(16))) __bf16 Bs[128 * 32];

  const int tid  = threadIdx.x;
  const int w    = tid >> 6;
  const int lane = tid & 63;
  const int m0 = blockIdx.y * 128, n0 = blockIdx.x * 128;
  const int wm = w >> 1, wn = w & 1;

  const int srow = lane >> 2;
  const int sk   = (lane & 3) * 8;
  const __bf16* aA0 = A  + (size_t)(m0 + w * 32 + srow) * K + sk;
  const __bf16* aA1 = aA0 + (size_t)16 * K;
  const __bf16* aB0 = Bm + (size_t)(n0 + w * 32 + srow) * K + sk;
  const __bf16* aB1 = aB0 + (size_t)16 * K;
  __bf16* lA0 = As + (w * 2 + 0) * 512;
  __bf16* lA1 = As + (w * 2 + 1) * 512;
  __bf16* lB0 = Bs + (w * 2 + 0) * 512;
  __bf16* lB1 = Bs + (w * 2 + 1) * 512;

  const int fr = lane & 15;
  const int fk = (lane >> 4) * 8;
  const __bf16* rA = As + (size_t)(wm * 64 + fr) * 32 + fk;
  const __bf16* rB = Bs + (size_t)(wn * 64 + fr) * 32 + fk;

  f32x4 acc[4][4] = {};

  for (int k0 = 0; k0 < K; k0 += 32) {
    __syncthreads();
    GLD16(aA0, lA0); GLD16(aA1, lA1);
    GLD16(aB0, lB0); GLD16(aB1, lB1);
    aA0 += 32; aA1 += 32; aB0 += 32; aB1 += 32;
    asm volatile("s_waitcnt vmcnt(0)" ::: "memory");
    __syncthreads();

    bf16x8 af[4], bfr[4];
#pragma unroll
    for (int i = 0; i < 4; ++i) af[i]  = *(const bf16x8*)(rA + i * 512);
#pragma unroll
    for (int j = 0; j < 4; ++j) bfr[j] = *(const bf16x8*)(rB + j * 512);
#pragma unroll
    for (int i = 0; i < 4; ++i)
#pragma unroll
      for (int j = 0; j < 4; ++j)
        acc[i][j] = __builtin_amdgcn_mfma_f32_16x16x32_bf16(af[i], bfr[j], acc[i][j], 0, 0, 0);
  }

  const int crow0 = (lane >> 4) * 4;
#pragma unroll
  for (int i = 0; i < 4; ++i) {
#pragma unroll
    for (int j = 0; j < 4; ++j) {
      const int n = n0 + wn * 64 + j * 16 + fr;
#pragma unroll
      for (int r = 0; r < 4; ++r) {
        const int m = m0 + wm * 64 + i * 16 + crow0 + r;
        float vv = acc[i][j][r];
        if (ACT == 1) vv = 1.f / (1.f + expf(-vv));
        Cm[(size_t)m * N + n] = (OT)vv;
      }
    }
  }
}

// ---------------------------------------------------------------------------
// causal dwconv(K=4) + silu + scale, bf16 in -> bf16 out, 8 ch/thread.
// ---------------------------------------------------------------------------
__global__ __launch_bounds__(256)
void conv_silu_b8(const __bf16* __restrict__ u, const float* __restrict__ wconv,
                  __bf16* __restrict__ out, float scale)
{
  const int idx = blockIdx.x * 256 + threadIdx.x;   // over B*T*C/8
  const int c8 = (idx & (CC / 8 - 1)) * 8;
  const int t  = (idx >> 8) & (TT - 1);
  const int b  = idx >> 19;
  const size_t base = ((size_t)(b * TT + t)) * CC + c8;

  const bf16x8 z = {};
  const bf16x8 u0 = *(const bf16x8*)(u + base);
  const bf16x8 u1 = (t >= 1) ? *(const bf16x8*)(u + base - CC)     : z;
  const bf16x8 u2 = (t >= 2) ? *(const bf16x8*)(u + base - 2 * CC) : z;
  const bf16x8 u3 = (t >= 3) ? *(const bf16x8*)(u + base - 3 * CC) : z;

  bf16x8 o;
#pragma unroll
  for (int jj = 0; jj < 8; ++jj) {
    const float4 wv = *(const float4*)(wconv + (size_t)(c8 + jj) * 4);
    const float vv = wv.x * (float)u3[jj] + wv.y * (float)u2[jj]
                   + wv.z * (float)u1[jj] + wv.w * (float)u0[jj];
    o[jj] = (__bf16)(vv / (1.f + expf(-vv)) * scale);
  }
  *(bf16x8*)(out + base) = o;
}

// ---------------------------------------------------------------------------
// bf16 transpose (B,T,C[h,d]) -> (B,H,D,T), 64x64 tiles through LDS.
// ---------------------------------------------------------------------------
__global__ __launch_bounds__(256)
void tr_bf16(const __bf16* __restrict__ src, __bf16* __restrict__ dst)
{
  const int t0 = blockIdx.x * 64, d0 = blockIdx.y * 64;
  const int bh = blockIdx.z, b = bh >> 4, h = bh & 15;
  const int tid = threadIdx.x;
  __shared__ __attribute__((aligned(16))) __bf16 tile[64][72];

#pragma unroll
  for (int it = 0; it < 2; ++it) {
    const int idx = tid + it * 256;
    const int tl = idx >> 3, g = idx & 7;
    const bf16x8 v = *(const bf16x8*)(src + ((size_t)(b * TT + t0 + tl)) * CC + h * DD + d0 + g * 8);
    *(bf16x8*)&tile[tl][g * 8] = v;
  }
  __syncthreads();
#pragma unroll
  for (int it = 0; it < 2; ++it) {
    const int idx = tid + it * 256;
    const int dl = idx >> 3, g = idx & 7;
    bf16x8 o;
#pragma unroll
    for (int jj = 0; jj < 8; ++jj) o[jj] = tile[g * 8 + jj][dl];
    *(bf16x8*)(dst + ((size_t)(bh * DD + d0 + dl)) * TT + t0 + g * 8) = o;
  }
}

// ---------------------------------------------------------------------------
// fp32 128x128 transpose per bh. grid (2,2,BB*HH).
// ---------------------------------------------------------------------------
__global__ __launch_bounds__(256)
void tr_f32(const float* __restrict__ in, float* __restrict__ out)
{
  const int r0 = blockIdx.x * 64, c0 = blockIdx.y * 64;
  const int bh = blockIdx.z;
  const int tid = threadIdx.x;
  __shared__ float tile[64][65];

#pragma unroll
  for (int it = 0; it < 4; ++it) {
    const int idx = tid + it * 256;
    const int rl = idx >> 4, g = idx & 15;
    const float4 v = *(const float4*)(in + (size_t)bh * 16384 + (r0 + rl) * 128 + c0 + g * 4);
    tile[rl][g * 4 + 0] = v.x; tile[rl][g * 4 + 1] = v.y;
    tile[rl][g * 4 + 2] = v.z; tile[rl][g * 4 + 3] = v.w;
  }
  __syncthreads();
#pragma unroll
  for (int it = 0; it < 4; ++it) {
    const int idx = tid + it * 256;
    const int cl = idx >> 4, g = idx & 15;
    float4 o;
    o.x = tile[g * 4 + 0][cl]; o.y = tile[g * 4 + 1][cl];
    o.z = tile[g * 4 + 2][cl]; o.w = tile[g * 4 + 3][cl];
    *(float4*)(out + (size_t)bh * 16384 + (c0 + cl) * 128 + r0 + g * 4) = o;
  }
}

// ---------------------------------------------------------------------------
// Phase A (MFMA): contribT[e][d] = sum_s (w_s k_s[d]) v_s[e];  decay out.
// ---------------------------------------------------------------------------
__global__ __launch_bounds__(256)
void phaseA_mfma(const __bf16* __restrict__ kT, const __bf16* __restrict__ vT,
                 const float* __restrict__ beta, float* __restrict__ contribT,
                 float* __restrict__ decay)
{
  const int c = blockIdx.x, h = blockIdx.y, b = blockIdx.z;
  const int bh = b * HH + h;
  const int tid = threadIdx.x;
  const int w = tid >> 6, lane = tid & 63;
  const int wm = w >> 1, wn = w & 1;

  __shared__ __attribute__((aligned(16))) __bf16 bufVT[128 * 128];
  __shared__ __attribute__((aligned(16))) __bf16 bufKW[128 * 128];
  __shared__ float lc[CHUNK], bsh[CHUNK], wgt[CHUNK];

  {
    const __bf16* vbase = vT + ((size_t)bh * DD) * TT + c * CHUNK;
#pragma unroll
    for (int jj = 0; jj < 8; ++jj) {
      const int row = w * 32 + jj * 4 + (lane >> 4);
      const int g = lane & 15;
      GLD16(vbase + (size_t)row * TT + ((g ^ (row & 7)) << 3),
            bufVT + (w * 32 + jj * 4) * 128);
    }
  }

  if (tid < CHUNK) {
    const float bv = beta[(size_t)(b * TT + c * CHUNK + tid) * HH + h];
    bsh[tid] = bv;
    lc[tid] = log1pf(-bv);
  }
  __syncthreads();
  for (int off = 1; off < CHUNK; off <<= 1) {
    float add = 0.f;
    if (tid < CHUNK && tid >= off) add = lc[tid - off];
    __syncthreads();
    if (tid < CHUNK) lc[tid] += add;
    __syncthreads();
  }
  const float lend = lc[CHUNK - 1];
  if (tid < CHUNK) wgt[tid] = bsh[tid] * expf(lend - lc[tid]);
  if (tid == 0) decay[(size_t)bh * NC + c] = expf(lend);
  __syncthreads();

  {
    const __bf16* kbase = kT + ((size_t)bh * DD) * TT + c * CHUNK;
#pragma unroll
    for (int it = 0; it < 8; ++it) {
      const int idx = tid + it * 256;
      const int d = idx >> 4, g = idx & 15;
      const bf16x8 kv = *(const bf16x8*)(kbase + (size_t)d * TT + g * 8);
      bf16x8 o;
#pragma unroll
      for (int jj = 0; jj < 8; ++jj)
        o[jj] = (__bf16)((float)kv[jj] * wgt[g * 8 + jj]);
      *(bf16x8*)(bufKW + d * 128 + ((g ^ (d & 7)) << 3)) = o;
    }
  }
  asm volatile("s_waitcnt vmcnt(0)" ::: "memory");
  __syncthreads();

  f32x4 acc[4][4] = {};
#pragma unroll
  for (int ks = 0; ks < 4; ++ks) {
    bf16x8 a[4], bq[4];
    const int kg = ks * 4 + (lane >> 4);
#pragma unroll
    for (int f = 0; f < 4; ++f) a[f]  = ldfrag(bufVT, wm * 64 + f * 16 + (lane & 15), kg);
#pragma unroll
    for (int f = 0; f < 4; ++f) bq[f] = ldfrag(bufKW, wn * 64 + f * 16 + (lane & 15), kg);
#pragma unroll
    for (int i = 0; i < 4; ++i)
#pragma unroll
      for (int j = 0; j < 4; ++j)
        acc[i][j] = __builtin_amdgcn_mfma_f32_16x16x32_bf16(a[i], bq[j], acc[i][j], 0, 0, 0);
  }

  float* cp = contribT + ((size_t)(bh * NC + c) << 14);
  const int crow = (lane >> 4) * 4;
#pragma unroll
  for (int i = 0; i < 4; ++i)
#pragma unroll
    for (int j = 0; j < 4; ++j) {
      const int dd = wn * 64 + j * 16 + (lane & 15);
#pragma unroll
      for (int r = 0; r < 4; ++r) {
        const int e = wm * 64 + i * 16 + crow + r;
        cp[(size_t)e * 128 + dd] = acc[i][j][r];
      }
    }
}

// ---------------------------------------------------------------------------
// Phase B (transposed space).
// ---------------------------------------------------------------------------
__global__ __launch_bounds__(256)
void phaseB_T(const float* __restrict__ state0T, const float* __restrict__ contribT,
              const float* __restrict__ decay, __bf16* __restrict__ statesT,
              float* __restrict__ stateOutT)
{
  const size_t gid = (size_t)blockIdx.x * 256 + threadIdx.x;
  const int bh = (int)(gid >> 14);
  float s = state0T[gid];
  const float* dc = decay + (size_t)bh * NC;
  const int ed = (int)(gid & 16383);
#pragma unroll
  for (int c = 0; c < NC; ++c) {
    const size_t off = ((size_t)(bh * NC + c) << 14) + ed;
    statesT[off] = (__bf16)s;
    s = fmaf(dc[c], s, contribT[off]);
  }
  stateOutT[gid] = s;
}

// ---------------------------------------------------------------------------
// Phase C (MFMA) + fused GroupNorm partial stats.
// ---------------------------------------------------------------------------
__global__ __launch_bounds__(256)
void phaseC_mfma(const __bf16* __restrict__ qb, const __bf16* __restrict__ kb,
                 const __bf16* __restrict__ vT, const float* __restrict__ beta,
                 const __bf16* __restrict__ statesT, float* __restrict__ att,
                 float* __restrict__ partials)
{
  const int c = blockIdx.x, h = blockIdx.y, b = blockIdx.z;
  const int bh = b * HH + h;
  const int tid = threadIdx.x;
  const int w = tid >> 6, lane = tid & 63;
  const int wm = w >> 1, wn = w & 1;

  __shared__ __attribute__((aligned(16))) __bf16 bufQ[128 * 128];
  __shared__ __attribute__((aligned(16))) __bf16 bufB[128 * 128];
  __shared__ float lc[CHUNK], bsh[CHUNK];
  __shared__ float s1[256], s2[256];

  {
    const __bf16* qbase = qb + ((size_t)(b * TT + c * CHUNK)) * CC + h * DD;
    const __bf16* kbase = kb + ((size_t)(b * TT + c * CHUNK)) * CC + h * DD;
#pragma unroll
    for (int jj = 0; jj < 8; ++jj) {
      const int row = w * 32 + jj * 4 + (lane >> 4);
      const int g = lane & 15;
      GLD16(qbase + (size_t)row * CC + ((g ^ (row & 7)) << 3),
            bufQ + (w * 32 + jj * 4) * 128);
      GLD16(kbase + (size_t)row * CC + ((g ^ (row & 7)) << 3),
            bufB + (w * 32 + jj * 4) * 128);
    }
  }

  if (tid < CHUNK) {
    const float bv = beta[(size_t)(b * TT + c * CHUNK + tid) * HH + h];
    bsh[tid] = bv;
    lc[tid] = log1pf(-bv);
  }
  __syncthreads();
  for (int off = 1; off < CHUNK; off <<= 1) {
    float add = 0.f;
    if (tid < CHUNK && tid >= off) add = lc[tid - off];
    __syncthreads();
    if (tid < CHUNK) lc[tid] += add;
    __syncthreads();
  }

  asm volatile("s_waitcnt vmcnt(0)" ::: "memory");
  __syncthreads();

  // S = Q K^T
  f32x4 accS[4][4] = {};
#pragma unroll
  for (int ks = 0; ks < 4; ++ks) {
    bf16x8 a[4], bq[4];
    const int kg = ks * 4 + (lane >> 4);
#pragma unroll
    for (int f = 0; f < 4; ++f) a[f]  = ldfrag(bufQ, wm * 64 + f * 16 + (lane & 15), kg);
#pragma unroll
    for (int f = 0; f < 4; ++f) bq[f] = ldfrag(bufB, wn * 64 + f * 16 + (lane & 15), kg);
#pragma unroll
    for (int i = 0; i < 4; ++i)
#pragma unroll
      for (int j = 0; j < 4; ++j)
        accS[i][j] = __builtin_amdgcn_mfma_f32_16x16x32_bf16(a[i], bq[j], accS[i][j], 0, 0, 0);
  }

  __syncthreads();
  {
    const __bf16* sbase = statesT + ((size_t)(bh * NC + c) << 14);
#pragma unroll
    for (int jj = 0; jj < 8; ++jj) {
      const int row = w * 32 + jj * 4 + (lane >> 4);
      const int g = lane & 15;
      GLD16(sbase + (size_t)row * 128 + ((g ^ (row & 7)) << 3),
            bufB + (w * 32 + jj * 4) * 128);
    }
  }
  asm volatile("s_waitcnt vmcnt(0)" ::: "memory");
  __syncthreads();

  // accO = Q S0T, scaled by e^{lc_t}
  f32x4 accO[4][4] = {};
#pragma unroll
  for (int ks = 0; ks < 4; ++ks) {
    bf16x8 a[4], bq[4];
    const int kg = ks * 4 + (lane >> 4);
#pragma unroll
    for (int f = 0; f < 4; ++f) a[f]  = ldfrag(bufQ, wm * 64 + f * 16 + (lane & 15), kg);
#pragma unroll
    for (int f = 0; f < 4; ++f) bq[f] = ldfrag(bufB, wn * 64 + f * 16 + (lane & 15), kg);
#pragma unroll
    for (int i = 0; i < 4; ++i)
#pragma unroll
      for (int j = 0; j < 4; ++j)
        accO[i][j] = __builtin_amdgcn_mfma_f32_16x16x32_bf16(a[i], bq[j], accO[i][j], 0, 0, 0);
  }
  const int crow = (lane >> 4) * 4;
#pragma unroll
  for (int i = 0; i < 4; ++i)
#pragma unroll
    for (int r = 0; r < 4; ++r) {
      const float el = expf(lc[wm * 64 + i * 16 + crow + r]);
#pragma unroll
      for (int j = 0; j < 4; ++j) accO[i][j][r] *= el;
    }

  __syncthreads();
  {
    const __bf16* vbase = vT + ((size_t)bh * DD) * TT + c * CHUNK;
#pragma unroll
    for (int jj = 0; jj < 8; ++jj) {
      const int row = w * 32 + jj * 4 + (lane >> 4);
      const int g = lane & 15;
      GLD16(vbase + (size_t)row * TT + ((g ^ (row & 7)) << 3),
            bufB + (w * 32 + jj * 4) * 128);
    }
  }
  {
    float lcs[4], bss[4];
#pragma unroll
    for (int j = 0; j < 4; ++j) {
      const int s = wn * 64 + j * 16 + (lane & 15);
      lcs[j] = lc[s]; bss[j] = bsh[s];
    }
#pragma unroll
    for (int i = 0; i < 4; ++i)
#pragma unroll
      for (int r = 0; r < 4; ++r) {
        const int t = wm * 64 + i * 16 + crow + r;
        const float lct = lc[t];
#pragma unroll
        for (int j = 0; j < 4; ++j) {
          const int s = wn * 64 + j * 16 + (lane & 15);
          float p = 0.f;
          if (s <= t) p = accS[i][j][r] * bss[j] * expf(lct - lcs[j]);
          bufQ[t * 128 + (((s >> 3) ^ (t & 7)) << 3) + (s & 7)] = (__bf16)p;
        }
      }
  }
  asm volatile("s_waitcnt vmcnt(0)" ::: "memory");
  __syncthreads();

  // accO += P V^T
#pragma unroll
  for (int ks = 0; ks < 4; ++ks) {
    bf16x8 a[4], bq[4];
    const int kg = ks * 4 + (lane >> 4);
#pragma unroll
    for (int f = 0; f < 4; ++f) a[f]  = ldfrag(bufQ, wm * 64 + f * 16 + (lane & 15), kg);
#pragma unroll
    for (int f = 0; f < 4; ++f) bq[f] = ldfrag(bufB, wn * 64 + f * 16 + (lane & 15), kg);
#pragma unroll
    for (int i = 0; i < 4; ++i)
#pragma unroll
      for (int j = 0; j < 4; ++j)
        accO[i][j] = __builtin_amdgcn_mfma_f32_16x16x32_bf16(a[i], bq[j], accO[i][j], 0, 0, 0);
  }

  // epilogue: store att + accumulate GN partial stats
  float lsum = 0.f, lsq = 0.f;
  float* obase = att + ((size_t)(b * TT + c * CHUNK)) * CC + h * DD;
#pragma unroll
  for (int i = 0; i < 4; ++i)
#pragma unroll
    for (int j = 0; j < 4; ++j) {
      const int e = wn * 64 + j * 16 + (lane & 15);
#pragma unroll
      for (int r = 0; r < 4; ++r) {
        const int t = wm * 64 + i * 16 + crow + r;
        const float vv = accO[i][j][r];
        obase[(size_t)t * CC + e] = vv;
        lsum += vv;
        lsq  += vv * vv;
      }
    }
  s1[tid] = lsum; s2[tid] = lsq;
  __syncthreads();
  for (int off = 128; off; off >>= 1) {
    if (tid < off) { s1[tid] += s1[tid + off]; s2[tid] += s2[tid + off]; }
    __syncthreads();
  }
  if (tid == 0) {
    partials[(size_t)(bh * NC + c) * 2]     = s1[0];
    partials[(size_t)(bh * NC + c) * 2 + 1] = s2[0];
  }
}

// ---------------------------------------------------------------------------
// combine GN partials -> stats. grid (BB*HH), 64 threads.
// ---------------------------------------------------------------------------
__global__ __launch_bounds__(64)
void gn_combine(const float* __restrict__ partials, float* __restrict__ stats)
{
  const int bh = blockIdx.x;
  const int lane = threadIdx.x;
  float s = 0.f, q = 0.f;
  if (lane < NC) {
    s = partials[(size_t)(bh * NC + lane) * 2];
    q = partials[(size_t)(bh * NC + lane) * 2 + 1];
  }
#pragma unroll
  for (int off = 8; off; off >>= 1) {
    s += __shfl_xor(s, off, 64);
    q += __shfl_xor(q, off, 64);
  }
  if (lane == 0) {
    const float n = (float)(TT * DD);
    const float mean = s / n;
    const float var = q / n - mean * mean;
    stats[bh * 2] = mean;
    stats[bh * 2 + 1] = rsqrtf(var + GN_EPS);
  }
}

// ---------------------------------------------------------------------------
// normalize + gate (bf16 gate) -> bf16.
// ---------------------------------------------------------------------------
__global__ __launch_bounds__(256)
void norm_gate(const float* __restrict__ att, const __bf16* __restrict__ gate,
               const float* __restrict__ stats, __bf16* __restrict__ g)
{
  const size_t gid = ((size_t)blockIdx.x * 256 + threadIdx.x) * 4;
  if (gid >= (size_t)BB * TT * CC) return;
  const int cpos = (int)(gid % CC);
  const int b = (int)(gid / ((size_t)TT * CC));
  const int bh = b * HH + (cpos >> 7);
  const float mean = stats[bh * 2], rstd = stats[bh * 2 + 1];
  const float4 a = *(const float4*)(att + gid);
  const bf16x4 gt = *(const bf16x4*)(gate + gid);
  bf16x4 o;
  o[0] = (__bf16)((a.x - mean) * rstd * (float)gt[0]);
  o[1] = (__bf16)((a.y - mean) * rstd * (float)gt[1]);
  o[2] = (__bf16)((a.z - mean) * rstd * (float)gt[2]);
  o[3] = (__bf16)((a.w - mean) * rstd * (float)gt[3]);
  *(bf16x4*)(g + gid) = o;
}

// ---------------------------------------------------------------------------
extern "C" void kernel_launch(void* const* d_in, const int* in_sizes, int n_in,
                              void* d_out, int out_size, void* d_ws, size_t ws_size,
                              hipStream_t stream)
{
  const float* x      = (const float*)d_in[0];
  const float* st0    = (const float*)d_in[1];
  const float* Wq     = (const float*)d_in[2];
  const float* Wk     = (const float*)d_in[3];
  const float* Wv     = (const float*)d_in[4];
  const float* Wbeta  = (const float*)d_in[5];
  const float* Wgate  = (const float*)d_in[6];
  const float* Wo     = (const float*)d_in[7];
  const float* wqc    = (const float*)d_in[8];
  const float* wkc    = (const float*)d_in[9];
  const float* wvc    = (const float*)d_in[10];

  float* ws = (float*)d_ws;
  __bf16* qbf  = (__bf16*)(ws + 0);           // 8.4M bf16
  __bf16* kbf  = (__bf16*)(ws + 4194304);     // 8.4M bf16
  __bf16* vbf  = (__bf16*)(ws + 8388608);     // -> statesT later
  __bf16* u_v  = (__bf16*)(ws + 12582912);    // pre-act v; -> kT -> gbf
  __bf16* kT   = (__bf16*)(ws + 12582912);
  __bf16* gbf  = (__bf16*)(ws + 12582912);
  __bf16* vT   = (__bf16*)(ws + 16777216);
  __bf16* xbf  = (__bf16*)(ws + 20971520);    // dead after gemm_big
  float* contribT = ws + 20971520;            // 8.4M f, overlays xbf + Wcat[0:4.2M]
  __bf16* Wcat = (__bf16*)(ws + 25165824);    // 16.8M bf16 (8192x2048), dead after gemm_big
  __bf16* gatebuf = (__bf16*)(ws + 33554432); // 8.4M bf16, alive GEMM -> norm_gate
  __bf16* statesT = (__bf16*)(ws + 8388608);
  float* betab    = ws + 37748736;            // 65536
  float* decay    = ws + 37814272;            // 512
  float* stats    = ws + 37814784;            // 64
  float* partials = ws + 37814848;            // 1024
  float* state0T  = ws + 37815872;            // 524288
  float* stateOutT= ws + 38340160;            // 524288
  __bf16* Wob  = (__bf16*)(ws + 38864448);    // 4.2M bf16 -> end 40961536 f

  float* y_out  = (float*)d_out;
  float* st_out = (float*)d_out + (size_t)BB * TT * EE;
  __bf16* u_q = (__bf16*)d_out;               // floats [0, 4.2M)
  __bf16* u_k = (__bf16*)d_out + 8388608;     // floats [4.2M, 8.4M)
  float* att = y_out;

  const dim3 blk(256);
  const dim3 gBig(8192 / 256, (BB * TT) / 256);    // 32 x 16 = 512 blocks
  const dim3 gB(CC / 128, (BB * TT) / 128);        // Wo GEMM
  const dim3 gTr(TT / 64, DD / 64, BB * HH);
  const dim3 gTrS(2, 2, BB * HH);
  const dim3 gScan(NC, HH, BB);
  const float qscale = 0.08838834764831845f;

  // conversions (Wq,Wk,Wv,Wgate concatenated into Wcat)
  f2b<<<dim3(8192), blk, 0, stream>>>(x, xbf, BB * TT * EE);
  f2b<<<dim3(4096), blk, 0, stream>>>(Wq, Wcat, CC * EE);
  f2b<<<dim3(4096), blk, 0, stream>>>(Wk, Wcat + (size_t)CC * EE, CC * EE);
  f2b<<<dim3(4096), blk, 0, stream>>>(Wv, Wcat + (size_t)2 * CC * EE, CC * EE);
  f2b<<<dim3(4096), blk, 0, stream>>>(Wgate, Wcat + (size_t)3 * CC * EE, CC * EE);
  f2b<<<dim3(4096), blk, 0, stream>>>(Wo, Wob, EE * CC);

  // beta (fp32)
  beta_ker<<<dim3((BB * TT) / 4), blk, 0, stream>>>(x, Wbeta, betab);

  // merged QKV+gate projection (256^2 pipelined), then conv/silu per projection
  gemm_big<<<gBig, dim3(512), 0, stream>>>(xbf, Wcat, u_q, u_k, u_v, gatebuf);
  conv_silu_b8<<<dim3(4096), blk, 0, stream>>>(u_q, wqc, qbf, qscale);
  conv_silu_b8<<<dim3(4096), blk, 0, stream>>>(u_k, wkc, kbf, 1.f);
  conv_silu_b8<<<dim3(4096), blk, 0, stream>>>(u_v, wvc, vbf, 1.f);

  // k,v transposes -> (B,H,D,T)
  tr_bf16<<<gTr, blk, 0, stream>>>(kbf, kT);
  tr_bf16<<<gTr, blk, 0, stream>>>(vbf, vT);

  // state0 transpose -> [bh][e][d]
  tr_f32<<<gTrS, blk, 0, stream>>>(st0, state0T);

  // chunked delta scan (MFMA)
  phaseA_mfma<<<gScan, blk, 0, stream>>>(kT, vT, betab, contribT, decay);
  phaseB_T<<<dim3((BB * HH * DD * DD) / 256), blk, 0, stream>>>(state0T, contribT, decay, statesT, stateOutT);
  tr_f32<<<gTrS, blk, 0, stream>>>(stateOutT, st_out);
  phaseC_mfma<<<gScan, blk, 0, stream>>>(qbf, kbf, vT, betab, statesT, att, partials);

  // groupnorm combine + normalize*gate -> bf16
  gn_combine<<<dim3(BB * HH), dim3(64), 0, stream>>>(partials, stats);
  norm_gate<<<dim3((BB * TT * CC) / (256 * 4)), blk, 0, stream>>>(att, gatebuf, stats, gbf);

  // y = g @ Wo^T
  gemm_bf16<0, float><<<gB, blk, 0, stream>>>(gbf, Wob, y_out, BB * TT, EE, CC);
}

// Round 7
// 383.471 us; speedup vs baseline: 8.0312x; 1.1442x over previous
//
#include <hip/hip_runtime.h>
#include <hip/hip_bf16.h>
#include <math.h>

#define BB 2
#define TT 2048
#define EE 2048
#define HH 16
#define DD 128
#define CC 2048
#define KCONV 4
#define CHUNK 128
#define NC 16          // TT / CHUNK
#define GN_EPS 1e-5f

typedef __bf16 bf16x8 __attribute__((ext_vector_type(8)));
typedef __bf16 bf16x4 __attribute__((ext_vector_type(4)));
typedef float  f32x4  __attribute__((ext_vector_type(4)));

#define GLD16(gp, lp)                                                          \
  __builtin_amdgcn_global_load_lds(                                            \
      (const __attribute__((address_space(1))) void*)(gp),                     \
      (__attribute__((address_space(3))) void*)(lp), 16, 0, 0)

// swizzled fragment load: row-major [128][128] bf16 tile, 16B-group XOR swizzle
__device__ __forceinline__ bf16x8 ldfrag(const __bf16* buf, int row, int kg)
{
  return *(const bf16x8*)(buf + row * 128 + ((kg ^ (row & 7)) << 3));
}

// ---------------------------------------------------------------------------
// merged f32 -> bf16 conversion for x, Wq|Wk|Wv|Wgate (into Wcat), Wo.
// 29,360,128 elems, 4/thread -> 28672 blocks.
// ---------------------------------------------------------------------------
__global__ __launch_bounds__(256)
void convert_all(const float* __restrict__ x,  const float* __restrict__ Wq,
                 const float* __restrict__ Wk, const float* __restrict__ Wv,
                 const float* __restrict__ Wg, const float* __restrict__ Wo,
                 __bf16* __restrict__ xbf, __bf16* __restrict__ Wcat,
                 __bf16* __restrict__ Wob)
{
  const int i = (blockIdx.x * 256 + threadIdx.x) * 4;
  const int XN = 8388608, WN = 4194304;
  const float* src;
  __bf16* dst;
  int off;
  if (i < XN) { src = x; dst = xbf; off = i; }
  else if (i < XN + 4 * WN) {
    const int j = i - XN;
    const int seg = j >> 22;
    src = seg == 0 ? Wq : seg == 1 ? Wk : seg == 2 ? Wv : Wg;
    dst = Wcat + ((size_t)seg << 22);
    off = j & (WN - 1);
  } else { src = Wo; dst = Wob; off = i - XN - 4 * WN; }
  const float4 v = *(const float4*)(src + off);
  bf16x4 o;
  o[0] = (__bf16)v.x; o[1] = (__bf16)v.y; o[2] = (__bf16)v.z; o[3] = (__bf16)v.w;
  *(bf16x4*)(dst + off) = o;
}

// ---------------------------------------------------------------------------
// beta = sigmoid(x @ Wbeta^T), x fp32 (B*T, E), Wbeta (16, E).
// ---------------------------------------------------------------------------
__global__ __launch_bounds__(256)
void beta_ker(const float* __restrict__ x, const float* __restrict__ Wb,
              float* __restrict__ betab)
{
  __shared__ float wsb[16 * 1024];   // 64 KB
  const int tid = threadIdx.x;
  const int w = tid >> 6, lane = tid & 63;
  const int row = blockIdx.x * 4 + w;           // < B*T = 4096
  const float* xrow = x + (size_t)row * EE;

  float acc[16] = {};
#pragma unroll
  for (int kt = 0; kt < 2; ++kt) {
    __syncthreads();
#pragma unroll
    for (int it = 0; it < 16; ++it) {
      const int i = tid + it * 256;
      const int h = i >> 8, kq = i & 255;
      *(float4*)&wsb[h * 1024 + kq * 4] =
          *(const float4*)(Wb + (size_t)h * EE + kt * 1024 + kq * 4);
    }
    __syncthreads();
#pragma unroll
    for (int j = 0; j < 4; ++j) {
      const int kof = lane * 4 + j * 256;
      const float4 xv = *(const float4*)(xrow + kt * 1024 + kof);
#pragma unroll
      for (int h = 0; h < 16; ++h) {
        const float4 wv = *(const float4*)&wsb[h * 1024 + kof];
        acc[h] += xv.x * wv.x + xv.y * wv.y + xv.z * wv.z + xv.w * wv.w;
      }
    }
  }
#pragma unroll
  for (int h = 0; h < 16; ++h) {
#pragma unroll
    for (int off = 32; off; off >>= 1)
      acc[h] += __shfl_xor(acc[h], off, 64);
  }
#pragma unroll
  for (int h = 0; h < 16; ++h)
    if (lane == h)
      betab[(size_t)row * HH + h] = 1.f / (1.f + expf(-acc[h]));
}

// ---------------------------------------------------------------------------
// 256x256 deep-pipelined bf16 GEMM (QKV+gate merged), K=2048, BK=64.
// 8 waves (2Mx4N), per-wave C = 128x64. LDS = 3 A-bufs + 2 B-bufs = 160 KiB.
// A and B both staged 2 K-tiles ahead; single counted vmcnt(8) per K-tile.
// Epilogue routed through LDS for coalesced bf16x8 stores.
// ---------------------------------------------------------------------------
__global__ __launch_bounds__(512)
void gemm_big(const __bf16* __restrict__ A, const __bf16* __restrict__ Bm,
              __bf16* __restrict__ o0, __bf16* __restrict__ o1,
              __bf16* __restrict__ o2, __bf16* __restrict__ o3)
{
  __shared__ __attribute__((aligned(16))) unsigned char smem[163840];
  __bf16 (*ldsA)[256 * 64] = (__bf16(*)[256 * 64])smem;             // 3 x 32KB
  __bf16 (*ldsB)[256 * 64] = (__bf16(*)[256 * 64])(smem + 98304);   // 2 x 32KB

  const int tid = threadIdx.x;
  const int w = tid >> 6, l = tid & 63;
  const int wm = w >> 2, wn = w & 3;          // 2 x 4 wave grid
  const int m0 = blockIdx.y * 256, n0 = blockIdx.x * 256;
  const int NT = EE / 64;                     // 32 K-tiles

  const int sr0 = w * 8 + (l >> 3);           // staging dest row, 0..63
  const int skg = l & 7;                      // dest 16B chunk in 128B row
  const int fr = l & 15;
  const int fkg = l >> 4;                     // 0..3

#define STAGE_A(tile, half) do {                                               \
    const int b_ = (tile) % 3;                                                 \
    const int r0_ = sr0;                                                       \
    const int r1_ = 64 + sr0;                                                  \
    GLD16(A + (size_t)(m0 + (half) * 128 + r0_) * 2048 + (tile) * 64           \
              + ((skg ^ (r0_ & 7)) << 3),                                      \
          ldsA[b_] + ((half) * 128 + w * 8) * 64);                             \
    GLD16(A + (size_t)(m0 + (half) * 128 + r1_) * 2048 + (tile) * 64           \
              + ((skg ^ (r1_ & 7)) << 3),                                      \
          ldsA[b_] + ((half) * 128 + 64 + w * 8) * 64);                        \
  } while (0)

#define STAGE_B(tile, half) do {                                               \
    const int b_ = (tile) & 1;                                                 \
    const int r0_ = sr0;                                                       \
    const int r1_ = 64 + sr0;                                                  \
    GLD16(Bm + (size_t)(n0 + (half) * 128 + r0_) * 2048 + (tile) * 64          \
              + ((skg ^ (r0_ & 7)) << 3),                                      \
          ldsB[b_] + ((half) * 128 + w * 8) * 64);                             \
    GLD16(Bm + (size_t)(n0 + (half) * 128 + r1_) * 2048 + (tile) * 64          \
              + ((skg ^ (r1_ & 7)) << 3),                                      \
          ldsB[b_] + ((half) * 128 + 64 + w * 8) * 64);                        \
  } while (0)

#define LDA_FRAG(dst, ab, q, mf, ks) do {                                      \
    const int row_ = wm * 128 + (q) * 32 + (mf) * 16 + fr;                     \
    const int kg_ = (ks) * 4 + fkg;                                            \
    dst = *(const bf16x8*)&ldsA[ab][row_ * 64 + ((kg_ ^ (row_ & 7)) << 3)];    \
  } while (0)
#define LDB_FRAG(dst, bb, nf, ks) do {                                         \
    const int row_ = wn * 64 + (nf) * 16 + fr;                                 \
    const int kg_ = (ks) * 4 + fkg;                                            \
    dst = *(const bf16x8*)&ldsB[bb][row_ * 64 + ((kg_ ^ (row_ & 7)) << 3)];    \
  } while (0)

  f32x4 acc[8][4] = {};

  // prologue: tiles 0 and 1 fully staged (16 loads); tile 0 must be resident.
  STAGE_A(0, 0); STAGE_A(0, 1); STAGE_B(0, 0); STAGE_B(0, 1);
  STAGE_A(1, 0); STAGE_A(1, 1); STAGE_B(1, 0); STAGE_B(1, 1);
  asm volatile("s_waitcnt vmcnt(8)" ::: "memory");
  __syncthreads();

  int abuf = 0;
  for (int t = 0; t < NT; ++t) {
    const int bbuf = t & 1;
    bf16x8 bfr[4][2];

    // ---- phase q0: all B frags + A quadrant 0; stage A0(t+2)
    {
#pragma unroll
      for (int nf = 0; nf < 4; ++nf)
#pragma unroll
        for (int ks = 0; ks < 2; ++ks) LDB_FRAG(bfr[nf][ks], bbuf, nf, ks);
      bf16x8 af[2][2];
#pragma unroll
      for (int mf = 0; mf < 2; ++mf)
#pragma unroll
        for (int ks = 0; ks < 2; ++ks) LDA_FRAG(af[mf][ks], abuf, 0, mf, ks);
      if (t + 2 < NT) STAGE_A(t + 2, 0);
      __builtin_amdgcn_s_barrier();
      __builtin_amdgcn_s_setprio(1);
#pragma unroll
      for (int mf = 0; mf < 2; ++mf)
#pragma unroll
        for (int nf = 0; nf < 4; ++nf)
#pragma unroll
          for (int ks = 0; ks < 2; ++ks)
            acc[mf][nf] = __builtin_amdgcn_mfma_f32_16x16x32_bf16(
                af[mf][ks], bfr[nf][ks], acc[mf][nf], 0, 0, 0);
      __builtin_amdgcn_s_setprio(0);
      __builtin_amdgcn_s_barrier();
    }

    // ---- phases q1..q3
#pragma unroll
    for (int q = 1; q < 4; ++q) {
      bf16x8 af[2][2];
#pragma unroll
      for (int mf = 0; mf < 2; ++mf)
#pragma unroll
        for (int ks = 0; ks < 2; ++ks) LDA_FRAG(af[mf][ks], abuf, q, mf, ks);
      if (q == 1) {
        if (t + 2 < NT) STAGE_A(t + 2, 1);
      } else if (q == 2) {
        if (t + 2 < NT) STAGE_B(t + 2, 0);
      } else {
        if (t + 2 < NT) STAGE_B(t + 2, 1);
        if (t == NT - 2) asm volatile("s_waitcnt vmcnt(0)" ::: "memory");
        else             asm volatile("s_waitcnt vmcnt(8)" ::: "memory");
      }
      __builtin_amdgcn_s_barrier();
      __builtin_amdgcn_s_setprio(1);
#pragma unroll
      for (int mf = 0; mf < 2; ++mf)
#pragma unroll
        for (int nf = 0; nf < 4; ++nf)
#pragma unroll
          for (int ks = 0; ks < 2; ++ks)
            acc[2 * q + mf][nf] = __builtin_amdgcn_mfma_f32_16x16x32_bf16(
                af[mf][ks], bfr[nf][ks], acc[2 * q + mf][nf], 0, 0, 0);
      __builtin_amdgcn_s_setprio(0);
      __builtin_amdgcn_s_barrier();
    }
    abuf = (abuf + 1 == 3) ? 0 : abuf + 1;
  }

  // epilogue through LDS: per-wave 128x72 padded tile, coalesced bf16x8 stores
  __syncthreads();
  const int proj = n0 >> 11;
  const int nb = n0 & 2047;
  __bf16* outp = proj == 0 ? o0 : proj == 1 ? o1 : proj == 2 ? o2 : o3;
  __bf16* ep = (__bf16*)smem + (size_t)w * 9216;
  const int crow = (l >> 4) * 4;
#pragma unroll
  for (int mf2 = 0; mf2 < 8; ++mf2)
#pragma unroll
    for (int nf = 0; nf < 4; ++nf)
#pragma unroll
      for (int r = 0; r < 4; ++r) {
        const int row = mf2 * 16 + crow + r;
        float vv = acc[mf2][nf][r];
        if (proj == 3) vv = 1.f / (1.f + expf(-vv));
        ep[row * 72 + nf * 16 + fr] = (__bf16)vv;
      }
#pragma unroll
  for (int it = 0; it < 16; ++it) {
    const int row = it * 8 + (l >> 3);
    const int c8 = (l & 7) * 8;
    const bf16x8 v8 = *(const bf16x8*)&ep[row * 72 + c8];
    *(bf16x8*)(outp + (size_t)(m0 + wm * 128 + row) * 2048 + nb + wn * 64 + c8) = v8;
  }
#undef STAGE_A
#undef STAGE_B
#undef LDA_FRAG
#undef LDB_FRAG
}

// ---------------------------------------------------------------------------
// bf16 MFMA GEMM, NT (m97 structure) — used for the Wo GEMM.
// ---------------------------------------------------------------------------
template <int ACT, typename OT>
__global__ __launch_bounds__(256)
void gemm_bf16(const __bf16* __restrict__ A, const __bf16* __restrict__ Bm,
               OT* __restrict__ Cm, int M, int N, int K)
{
  __shared__ __attribute__((aligned(16))) __bf16 As[128 * 32];
  __shared__ __attribute__((aligned(16))) __bf16 Bs[128 * 32];

  const int tid  = threadIdx.x;
  const int w    = tid >> 6;
  const int lane = tid & 63;
  const int m0 = blockIdx.y * 128, n0 = blockIdx.x * 128;
  const int wm = w >> 1, wn = w & 1;

  const int srow = lane >> 2;
  const int sk   = (lane & 3) * 8;
  const __bf16* aA0 = A  + (size_t)(m0 + w * 32 + srow) * K + sk;
  const __bf16* aA1 = aA0 + (size_t)16 * K;
  const __bf16* aB0 = Bm + (size_t)(n0 + w * 32 + srow) * K + sk;
  const __bf16* aB1 = aB0 + (size_t)16 * K;
  __bf16* lA0 = As + (w * 2 + 0) * 512;
  __bf16* lA1 = As + (w * 2 + 1) * 512;
  __bf16* lB0 = Bs + (w * 2 + 0) * 512;
  __bf16* lB1 = Bs + (w * 2 + 1) * 512;

  const int fr = lane & 15;
  const int fk = (lane >> 4) * 8;
  const __bf16* rA = As + (size_t)(wm * 64 + fr) * 32 + fk;
  const __bf16* rB = Bs + (size_t)(wn * 64 + fr) * 32 + fk;

  f32x4 acc[4][4] = {};

  for (int k0 = 0; k0 < K; k0 += 32) {
    __syncthreads();
    GLD16(aA0, lA0); GLD16(aA1, lA1);
    GLD16(aB0, lB0); GLD16(aB1, lB1);
    aA0 += 32; aA1 += 32; aB0 += 32; aB1 += 32;
    asm volatile("s_waitcnt vmcnt(0)" ::: "memory");
    __syncthreads();

    bf16x8 af[4], bfr[4];
#pragma unroll
    for (int i = 0; i < 4; ++i) af[i]  = *(const bf16x8*)(rA + i * 512);
#pragma unroll
    for (int j = 0; j < 4; ++j) bfr[j] = *(const bf16x8*)(rB + j * 512);
#pragma unroll
    for (int i = 0; i < 4; ++i)
#pragma unroll
      for (int j = 0; j < 4; ++j)
        acc[i][j] = __builtin_amdgcn_mfma_f32_16x16x32_bf16(af[i], bfr[j], acc[i][j], 0, 0, 0);
  }

  const int crow0 = (lane >> 4) * 4;
#pragma unroll
  for (int i = 0; i < 4; ++i) {
#pragma unroll
    for (int j = 0; j < 4; ++j) {
      const int n = n0 + wn * 64 + j * 16 + fr;
#pragma unroll
      for (int r = 0; r < 4; ++r) {
        const int m = m0 + wm * 64 + i * 16 + crow0 + r;
        float vv = acc[i][j][r];
        if (ACT == 1) vv = 1.f / (1.f + expf(-vv));
        Cm[(size_t)m * N + n] = (OT)vv;
      }
    }
  }
}

// ---------------------------------------------------------------------------
// merged causal dwconv(K=4)+silu for q,k,v. grid (4096, 3).
// ---------------------------------------------------------------------------
__global__ __launch_bounds__(256)
void conv_all(const __bf16* __restrict__ u0, const __bf16* __restrict__ u1,
              const __bf16* __restrict__ u2, const float* __restrict__ w0,
              const float* __restrict__ w1, const float* __restrict__ w2,
              __bf16* __restrict__ d0, __bf16* __restrict__ d1,
              __bf16* __restrict__ d2, float qscale)
{
  const int which = blockIdx.y;
  const __bf16* u = which == 0 ? u0 : which == 1 ? u1 : u2;
  const float* wconv = which == 0 ? w0 : which == 1 ? w1 : w2;
  __bf16* out = which == 0 ? d0 : which == 1 ? d1 : d2;
  const float scale = which == 0 ? qscale : 1.f;

  const int idx = blockIdx.x * 256 + threadIdx.x;   // over B*T*C/8
  const int c8 = (idx & (CC / 8 - 1)) * 8;
  const int t  = (idx >> 8) & (TT - 1);
  const int b  = idx >> 19;
  const size_t base = ((size_t)(b * TT + t)) * CC + c8;

  const bf16x8 z = {};
  const bf16x8 uu0 = *(const bf16x8*)(u + base);
  const bf16x8 uu1 = (t >= 1) ? *(const bf16x8*)(u + base - CC)     : z;
  const bf16x8 uu2 = (t >= 2) ? *(const bf16x8*)(u + base - 2 * CC) : z;
  const bf16x8 uu3 = (t >= 3) ? *(const bf16x8*)(u + base - 3 * CC) : z;

  bf16x8 o;
#pragma unroll
  for (int jj = 0; jj < 8; ++jj) {
    const float4 wv = *(const float4*)(wconv + (size_t)(c8 + jj) * 4);
    const float vv = wv.x * (float)uu3[jj] + wv.y * (float)uu2[jj]
                   + wv.z * (float)uu1[jj] + wv.w * (float)uu0[jj];
    o[jj] = (__bf16)(vv / (1.f + expf(-vv)) * scale);
  }
  *(bf16x8*)(out + base) = o;
}

// ---------------------------------------------------------------------------
// bf16 transpose (B,T,C[h,d]) -> (B,H,D,T) for k and v in one launch.
// grid (TT/64, DD/64, 2*BB*HH): z>=32 -> v.
// ---------------------------------------------------------------------------
__global__ __launch_bounds__(256)
void tr_kv(const __bf16* __restrict__ ksrc, const __bf16* __restrict__ vsrc,
           __bf16* __restrict__ kdst, __bf16* __restrict__ vdst)
{
  const int t0 = blockIdx.x * 64, d0 = blockIdx.y * 64;
  const int zz = blockIdx.z;
  const int bh = zz & 31, b = bh >> 4, h = bh & 15;
  const __bf16* src = (zz >= 32) ? vsrc : ksrc;
  __bf16* dst = (zz >= 32) ? vdst : kdst;
  const int tid = threadIdx.x;
  __shared__ __attribute__((aligned(16))) __bf16 tile[64][72];

#pragma unroll
  for (int it = 0; it < 2; ++it) {
    const int idx = tid + it * 256;
    const int tl = idx >> 3, g = idx & 7;
    const bf16x8 v = *(const bf16x8*)(src + ((size_t)(b * TT + t0 + tl)) * CC + h * DD + d0 + g * 8);
    *(bf16x8*)&tile[tl][g * 8] = v;
  }
  __syncthreads();
#pragma unroll
  for (int it = 0; it < 2; ++it) {
    const int idx = tid + it * 256;
    const int dl = idx >> 3, g = idx & 7;
    bf16x8 o;
#pragma unroll
    for (int jj = 0; jj < 8; ++jj) o[jj] = tile[g * 8 + jj][dl];
    *(bf16x8*)(dst + ((size_t)(bh * DD + d0 + dl)) * TT + t0 + g * 8) = o;
  }
}

// ---------------------------------------------------------------------------
// fp32 128x128 transpose per bh. grid (2,2,BB*HH).
// ---------------------------------------------------------------------------
__global__ __launch_bounds__(256)
void tr_f32(const float* __restrict__ in, float* __restrict__ out)
{
  const int r0 = blockIdx.x * 64, c0 = blockIdx.y * 64;
  const int bh = blockIdx.z;
  const int tid = threadIdx.x;
  __shared__ float tile[64][65];

#pragma unroll
  for (int it = 0; it < 4; ++it) {
    const int idx = tid + it * 256;
    const int rl = idx >> 4, g = idx & 15;
    const float4 v = *(const float4*)(in + (size_t)bh * 16384 + (r0 + rl) * 128 + c0 + g * 4);
    tile[rl][g * 4 + 0] = v.x; tile[rl][g * 4 + 1] = v.y;
    tile[rl][g * 4 + 2] = v.z; tile[rl][g * 4 + 3] = v.w;
  }
  __syncthreads();
#pragma unroll
  for (int it = 0; it < 4; ++it) {
    const int idx = tid + it * 256;
    const int cl = idx >> 4, g = idx & 15;
    float4 o;
    o.x = tile[g * 4 + 0][cl]; o.y = tile[g * 4 + 1][cl];
    o.z = tile[g * 4 + 2][cl]; o.w = tile[g * 4 + 3][cl];
    *(float4*)(out + (size_t)bh * 16384 + (c0 + cl) * 128 + r0 + g * 4) = o;
  }
}

// ---------------------------------------------------------------------------
// Phase A (MFMA): contribT[e][d] = sum_s (w_s k_s[d]) v_s[e];  decay out.
// ---------------------------------------------------------------------------
__global__ __launch_bounds__(256)
void phaseA_mfma(const __bf16* __restrict__ kT, const __bf16* __restrict__ vT,
                 const float* __restrict__ beta, float* __restrict__ contribT,
                 float* __restrict__ decay)
{
  const int c = blockIdx.x, h = blockIdx.y, b = blockIdx.z;
  const int bh = b * HH + h;
  const int tid = threadIdx.x;
  const int w = tid >> 6, lane = tid & 63;
  const int wm = w >> 1, wn = w & 1;

  __shared__ __attribute__((aligned(16))) __bf16 bufVT[128 * 128];
  __shared__ __attribute__((aligned(16))) __bf16 bufKW[128 * 128];
  __shared__ float lc[CHUNK], bsh[CHUNK], wgt[CHUNK];

  {
    const __bf16* vbase = vT + ((size_t)bh * DD) * TT + c * CHUNK;
#pragma unroll
    for (int jj = 0; jj < 8; ++jj) {
      const int row = w * 32 + jj * 4 + (lane >> 4);
      const int g = lane & 15;
      GLD16(vbase + (size_t)row * TT + ((g ^ (row & 7)) << 3),
            bufVT + (w * 32 + jj * 4) * 128);
    }
  }

  if (tid < CHUNK) {
    const float bv = beta[(size_t)(b * TT + c * CHUNK + tid) * HH + h];
    bsh[tid] = bv;
    lc[tid] = log1pf(-bv);
  }
  __syncthreads();
  for (int off = 1; off < CHUNK; off <<= 1) {
    float add = 0.f;
    if (tid < CHUNK && tid >= off) add = lc[tid - off];
    __syncthreads();
    if (tid < CHUNK) lc[tid] += add;
    __syncthreads();
  }
  const float lend = lc[CHUNK - 1];
  if (tid < CHUNK) wgt[tid] = bsh[tid] * expf(lend - lc[tid]);
  if (tid == 0) decay[(size_t)bh * NC + c] = expf(lend);
  __syncthreads();

  {
    const __bf16* kbase = kT + ((size_t)bh * DD) * TT + c * CHUNK;
#pragma unroll
    for (int it = 0; it < 8; ++it) {
      const int idx = tid + it * 256;
      const int d = idx >> 4, g = idx & 15;
      const bf16x8 kv = *(const bf16x8*)(kbase + (size_t)d * TT + g * 8);
      bf16x8 o;
#pragma unroll
      for (int jj = 0; jj < 8; ++jj)
        o[jj] = (__bf16)((float)kv[jj] * wgt[g * 8 + jj]);
      *(bf16x8*)(bufKW + d * 128 + ((g ^ (d & 7)) << 3)) = o;
    }
  }
  asm volatile("s_waitcnt vmcnt(0)" ::: "memory");
  __syncthreads();

  f32x4 acc[4][4] = {};
#pragma unroll
  for (int ks = 0; ks < 4; ++ks) {
    bf16x8 a[4], bq[4];
    const int kg = ks * 4 + (lane >> 4);
#pragma unroll
    for (int f = 0; f < 4; ++f) a[f]  = ldfrag(bufVT, wm * 64 + f * 16 + (lane & 15), kg);
#pragma unroll
    for (int f = 0; f < 4; ++f) bq[f] = ldfrag(bufKW, wn * 64 + f * 16 + (lane & 15), kg);
#pragma unroll
    for (int i = 0; i < 4; ++i)
#pragma unroll
      for (int j = 0; j < 4; ++j)
        acc[i][j] = __builtin_amdgcn_mfma_f32_16x16x32_bf16(a[i], bq[j], acc[i][j], 0, 0, 0);
  }

  float* cp = contribT + ((size_t)(bh * NC + c) << 14);
  const int crow = (lane >> 4) * 4;
#pragma unroll
  for (int i = 0; i < 4; ++i)
#pragma unroll
    for (int j = 0; j < 4; ++j) {
      const int dd = wn * 64 + j * 16 + (lane & 15);
#pragma unroll
      for (int r = 0; r < 4; ++r) {
        const int e = wm * 64 + i * 16 + crow + r;
        cp[(size_t)e * 128 + dd] = acc[i][j][r];
      }
    }
}

// ---------------------------------------------------------------------------
// Phase B (transposed space).
// ---------------------------------------------------------------------------
__global__ __launch_bounds__(256)
void phaseB_T(const float* __restrict__ state0T, const float* __restrict__ contribT,
              const float* __restrict__ decay, __bf16* __restrict__ statesT,
              float* __restrict__ stateOutT)
{
  const size_t gid = (size_t)blockIdx.x * 256 + threadIdx.x;
  const int bh = (int)(gid >> 14);
  float s = state0T[gid];
  const float* dc = decay + (size_t)bh * NC;
  const int ed = (int)(gid & 16383);
#pragma unroll
  for (int c = 0; c < NC; ++c) {
    const size_t off = ((size_t)(bh * NC + c) << 14) + ed;
    statesT[off] = (__bf16)s;
    s = fmaf(dc[c], s, contribT[off]);
  }
  stateOutT[gid] = s;
}

// ---------------------------------------------------------------------------
// Phase C (MFMA) + fused GroupNorm partial stats.
// ---------------------------------------------------------------------------
__global__ __launch_bounds__(256)
void phaseC_mfma(const __bf16* __restrict__ qb, const __bf16* __restrict__ kb,
                 const __bf16* __restrict__ vT, const float* __restrict__ beta,
                 const __bf16* __restrict__ statesT, float* __restrict__ att,
                 float* __restrict__ partials)
{
  const int c = blockIdx.x, h = blockIdx.y, b = blockIdx.z;
  const int bh = b * HH + h;
  const int tid = threadIdx.x;
  const int w = tid >> 6, lane = tid & 63;
  const int wm = w >> 1, wn = w & 1;

  __shared__ __attribute__((aligned(16))) __bf16 bufQ[128 * 128];
  __shared__ __attribute__((aligned(16))) __bf16 bufB[128 * 128];
  __shared__ float lc[CHUNK], bsh[CHUNK];
  __shared__ float s1[256], s2[256];

  {
    const __bf16* qbase = qb + ((size_t)(b * TT + c * CHUNK)) * CC + h * DD;
    const __bf16* kbase = kb + ((size_t)(b * TT + c * CHUNK)) * CC + h * DD;
#pragma unroll
    for (int jj = 0; jj < 8; ++jj) {
      const int row = w * 32 + jj * 4 + (lane >> 4);
      const int g = lane & 15;
      GLD16(qbase + (size_t)row * CC + ((g ^ (row & 7)) << 3),
            bufQ + (w * 32 + jj * 4) * 128);
      GLD16(kbase + (size_t)row * CC + ((g ^ (row & 7)) << 3),
            bufB + (w * 32 + jj * 4) * 128);
    }
  }

  if (tid < CHUNK) {
    const float bv = beta[(size_t)(b * TT + c * CHUNK + tid) * HH + h];
    bsh[tid] = bv;
    lc[tid] = log1pf(-bv);
  }
  __syncthreads();
  for (int off = 1; off < CHUNK; off <<= 1) {
    float add = 0.f;
    if (tid < CHUNK && tid >= off) add = lc[tid - off];
    __syncthreads();
    if (tid < CHUNK) lc[tid] += add;
    __syncthreads();
  }

  asm volatile("s_waitcnt vmcnt(0)" ::: "memory");
  __syncthreads();

  // S = Q K^T
  f32x4 accS[4][4] = {};
#pragma unroll
  for (int ks = 0; ks < 4; ++ks) {
    bf16x8 a[4], bq[4];
    const int kg = ks * 4 + (lane >> 4);
#pragma unroll
    for (int f = 0; f < 4; ++f) a[f]  = ldfrag(bufQ, wm * 64 + f * 16 + (lane & 15), kg);
#pragma unroll
    for (int f = 0; f < 4; ++f) bq[f] = ldfrag(bufB, wn * 64 + f * 16 + (lane & 15), kg);
#pragma unroll
    for (int i = 0; i < 4; ++i)
#pragma unroll
      for (int j = 0; j < 4; ++j)
        accS[i][j] = __builtin_amdgcn_mfma_f32_16x16x32_bf16(a[i], bq[j], accS[i][j], 0, 0, 0);
  }

  __syncthreads();
  {
    const __bf16* sbase = statesT + ((size_t)(bh * NC + c) << 14);
#pragma unroll
    for (int jj = 0; jj < 8; ++jj) {
      const int row = w * 32 + jj * 4 + (lane >> 4);
      const int g = lane & 15;
      GLD16(sbase + (size_t)row * 128 + ((g ^ (row & 7)) << 3),
            bufB + (w * 32 + jj * 4) * 128);
    }
  }
  asm volatile("s_waitcnt vmcnt(0)" ::: "memory");
  __syncthreads();

  // accO = Q S0T, scaled by e^{lc_t}
  f32x4 accO[4][4] = {};
#pragma unroll
  for (int ks = 0; ks < 4; ++ks) {
    bf16x8 a[4], bq[4];
    const int kg = ks * 4 + (lane >> 4);
#pragma unroll
    for (int f = 0; f < 4; ++f) a[f]  = ldfrag(bufQ, wm * 64 + f * 16 + (lane & 15), kg);
#pragma unroll
    for (int f = 0; f < 4; ++f) bq[f] = ldfrag(bufB, wn * 64 + f * 16 + (lane & 15), kg);
#pragma unroll
    for (int i = 0; i < 4; ++i)
#pragma unroll
      for (int j = 0; j < 4; ++j)
        accO[i][j] = __builtin_amdgcn_mfma_f32_16x16x32_bf16(a[i], bq[j], accO[i][j], 0, 0, 0);
  }
  const int crow = (lane >> 4) * 4;
#pragma unroll
  for (int i = 0; i < 4; ++i)
#pragma unroll
    for (int r = 0; r < 4; ++r) {
      const float el = expf(lc[wm * 64 + i * 16 + crow + r]);
#pragma unroll
      for (int j = 0; j < 4; ++j) accO[i][j][r] *= el;
    }

  __syncthreads();
  {
    const __bf16* vbase = vT + ((size_t)bh * DD) * TT + c * CHUNK;
#pragma unroll
    for (int jj = 0; jj < 8; ++jj) {
      const int row = w * 32 + jj * 4 + (lane >> 4);
      const int g = lane & 15;
      GLD16(vbase + (size_t)row * TT + ((g ^ (row & 7)) << 3),
            bufB + (w * 32 + jj * 4) * 128);
    }
  }
  {
    float lcs[4], bss[4];
#pragma unroll
    for (int j = 0; j < 4; ++j) {
      const int s = wn * 64 + j * 16 + (lane & 15);
      lcs[j] = lc[s]; bss[j] = bsh[s];
    }
#pragma unroll
    for (int i = 0; i < 4; ++i)
#pragma unroll
      for (int r = 0; r < 4; ++r) {
        const int t = wm * 64 + i * 16 + crow + r;
        const float lct = lc[t];
#pragma unroll
        for (int j = 0; j < 4; ++j) {
          const int s = wn * 64 + j * 16 + (lane & 15);
          float p = 0.f;
          if (s <= t) p = accS[i][j][r] * bss[j] * expf(lct - lcs[j]);
          bufQ[t * 128 + (((s >> 3) ^ (t & 7)) << 3) + (s & 7)] = (__bf16)p;
        }
      }
  }
  asm volatile("s_waitcnt vmcnt(0)" ::: "memory");
  __syncthreads();

  // accO += P V^T
#pragma unroll
  for (int ks = 0; ks < 4; ++ks) {
    bf16x8 a[4], bq[4];
    const int kg = ks * 4 + (lane >> 4);
#pragma unroll
    for (int f = 0; f < 4; ++f) a[f]  = ldfrag(bufQ, wm * 64 + f * 16 + (lane & 15), kg);
#pragma unroll
    for (int f = 0; f < 4; ++f) bq[f] = ldfrag(bufB, wn * 64 + f * 16 + (lane & 15), kg);
#pragma unroll
    for (int i = 0; i < 4; ++i)
#pragma unroll
      for (int j = 0; j < 4; ++j)
        accO[i][j] = __builtin_amdgcn_mfma_f32_16x16x32_bf16(a[i], bq[j], accO[i][j], 0, 0, 0);
  }

  // epilogue: store att + accumulate GN partial stats
  float lsum = 0.f, lsq = 0.f;
  float* obase = att + ((size_t)(b * TT + c * CHUNK)) * CC + h * DD;
#pragma unroll
  for (int i = 0; i < 4; ++i)
#pragma unroll
    for (int j = 0; j < 4; ++j) {
      const int e = wn * 64 + j * 16 + (lane & 15);
#pragma unroll
      for (int r = 0; r < 4; ++r) {
        const int t = wm * 64 + i * 16 + crow + r;
        const float vv = accO[i][j][r];
        obase[(size_t)t * CC + e] = vv;
        lsum += vv;
        lsq  += vv * vv;
      }
    }
  s1[tid] = lsum; s2[tid] = lsq;
  __syncthreads();
  for (int off = 128; off; off >>= 1) {
    if (tid < off) { s1[tid] += s1[tid + off]; s2[tid] += s2[tid + off]; }
    __syncthreads();
  }
  if (tid == 0) {
    partials[(size_t)(bh * NC + c) * 2]     = s1[0];
    partials[(size_t)(bh * NC + c) * 2 + 1] = s2[0];
  }
}

// ---------------------------------------------------------------------------
// combine GN partials -> stats. grid (BB*HH), 64 threads.
// ---------------------------------------------------------------------------
__global__ __launch_bounds__(64)
void gn_combine(const float* __restrict__ partials, float* __restrict__ stats)
{
  const int bh = blockIdx.x;
  const int lane = threadIdx.x;
  float s = 0.f, q = 0.f;
  if (lane < NC) {
    s = partials[(size_t)(bh * NC + lane) * 2];
    q = partials[(size_t)(bh * NC + lane) * 2 + 1];
  }
#pragma unroll
  for (int off = 8; off; off >>= 1) {
    s += __shfl_xor(s, off, 64);
    q += __shfl_xor(q, off, 64);
  }
  if (lane == 0) {
    const float n = (float)(TT * DD);
    const float mean = s / n;
    const float var = q / n - mean * mean;
    stats[bh * 2] = mean;
    stats[bh * 2 + 1] = rsqrtf(var + GN_EPS);
  }
}

// ---------------------------------------------------------------------------
// normalize + gate (bf16 gate) -> bf16.
// ---------------------------------------------------------------------------
__global__ __launch_bounds__(256)
void norm_gate(const float* __restrict__ att, const __bf16* __restrict__ gate,
               const float* __restrict__ stats, __bf16* __restrict__ g)
{
  const size_t gid = ((size_t)blockIdx.x * 256 + threadIdx.x) * 4;
  if (gid >= (size_t)BB * TT * CC) return;
  const int cpos = (int)(gid % CC);
  const int b = (int)(gid / ((size_t)TT * CC));
  const int bh = b * HH + (cpos >> 7);
  const float mean = stats[bh * 2], rstd = stats[bh * 2 + 1];
  const float4 a = *(const float4*)(att + gid);
  const bf16x4 gt = *(const bf16x4*)(gate + gid);
  bf16x4 o;
  o[0] = (__bf16)((a.x - mean) * rstd * (float)gt[0]);
  o[1] = (__bf16)((a.y - mean) * rstd * (float)gt[1]);
  o[2] = (__bf16)((a.z - mean) * rstd * (float)gt[2]);
  o[3] = (__bf16)((a.w - mean) * rstd * (float)gt[3]);
  *(bf16x4*)(g + gid) = o;
}

// ---------------------------------------------------------------------------
extern "C" void kernel_launch(void* const* d_in, const int* in_sizes, int n_in,
                              void* d_out, int out_size, void* d_ws, size_t ws_size,
                              hipStream_t stream)
{
  const float* x      = (const float*)d_in[0];
  const float* st0    = (const float*)d_in[1];
  const float* Wq     = (const float*)d_in[2];
  const float* Wk     = (const float*)d_in[3];
  const float* Wv     = (const float*)d_in[4];
  const float* Wbeta  = (const float*)d_in[5];
  const float* Wgate  = (const float*)d_in[6];
  const float* Wo     = (const float*)d_in[7];
  const float* wqc    = (const float*)d_in[8];
  const float* wkc    = (const float*)d_in[9];
  const float* wvc    = (const float*)d_in[10];

  float* ws = (float*)d_ws;
  __bf16* qbf  = (__bf16*)(ws + 0);           // 8.4M bf16
  __bf16* kbf  = (__bf16*)(ws + 4194304);     // 8.4M bf16
  __bf16* vbf  = (__bf16*)(ws + 8388608);     // -> statesT later
  __bf16* u_v  = (__bf16*)(ws + 12582912);    // pre-act v; -> kT -> gbf
  __bf16* kT   = (__bf16*)(ws + 12582912);
  __bf16* gbf  = (__bf16*)(ws + 12582912);
  __bf16* vT   = (__bf16*)(ws + 16777216);
  __bf16* xbf  = (__bf16*)(ws + 20971520);    // dead after gemm_big
  float* contribT = ws + 20971520;            // 8.4M f, overlays xbf + Wcat[0:4.2M]
  __bf16* Wcat = (__bf16*)(ws + 25165824);    // 16.8M bf16 (8192x2048), dead after gemm_big
  __bf16* gatebuf = (__bf16*)(ws + 33554432); // 8.4M bf16, alive GEMM -> norm_gate
  __bf16* statesT = (__bf16*)(ws + 8388608);
  float* betab    = ws + 37748736;            // 65536
  float* decay    = ws + 37814272;            // 512
  float* stats    = ws + 37814784;            // 64
  float* partials = ws + 37814848;            // 1024
  float* state0T  = ws + 37815872;            // 524288
  float* stateOutT= ws + 38340160;            // 524288
  __bf16* Wob  = (__bf16*)(ws + 38864448);    // 4.2M bf16 -> end 40961536 f

  float* y_out  = (float*)d_out;
  float* st_out = (float*)d_out + (size_t)BB * TT * EE;
  __bf16* u_q = (__bf16*)d_out;               // floats [0, 4.2M)
  __bf16* u_k = (__bf16*)d_out + 8388608;     // floats [4.2M, 8.4M)
  float* att = y_out;

  const dim3 blk(256);
  const dim3 gBig(8192 / 256, (BB * TT) / 256);    // 32 x 16 = 512 blocks
  const dim3 gB(CC / 128, (BB * TT) / 128);        // Wo GEMM
  const dim3 gKV(TT / 64, DD / 64, 2 * BB * HH);
  const dim3 gTrS(2, 2, BB * HH);
  const dim3 gScan(NC, HH, BB);
  const float qscale = 0.08838834764831845f;

  // all f32->bf16 conversions in one launch
  convert_all<<<dim3(28672), blk, 0, stream>>>(x, Wq, Wk, Wv, Wgate, Wo,
                                               xbf, Wcat, Wob);

  // beta (fp32)
  beta_ker<<<dim3((BB * TT) / 4), blk, 0, stream>>>(x, Wbeta, betab);

  // merged QKV+gate projection (256^2 pipelined, 3-deep A prefetch)
  gemm_big<<<gBig, dim3(512), 0, stream>>>(xbf, Wcat, u_q, u_k, u_v, gatebuf);

  // conv/silu for q,k,v in one launch
  conv_all<<<dim3(4096, 3), blk, 0, stream>>>(u_q, u_k, u_v, wqc, wkc, wvc,
                                              qbf, kbf, vbf, qscale);

  // k,v transposes -> (B,H,D,T) in one launch
  tr_kv<<<gKV, blk, 0, stream>>>(kbf, vbf, kT, vT);

  // state0 transpose -> [bh][e][d]
  tr_f32<<<gTrS, blk, 0, stream>>>(st0, state0T);

  // chunked delta scan (MFMA)
  phaseA_mfma<<<gScan, blk, 0, stream>>>(kT, vT, betab, contribT, decay);
  phaseB_T<<<dim3((BB * HH * DD * DD) / 256), blk, 0, stream>>>(state0T, contribT, decay, statesT, stateOutT);
  tr_f32<<<gTrS, blk, 0, stream>>>(stateOutT, st_out);
  phaseC_mfma<<<gScan, blk, 0, stream>>>(qbf, kbf, vT, betab, statesT, att, partials);

  // groupnorm combine + normalize*gate -> bf16
  gn_combine<<<dim3(BB * HH), dim3(64), 0, stream>>>(partials, stats);
  norm_gate<<<dim3((BB * TT * CC) / (256 * 4)), blk, 0, stream>>>(att, gatebuf, stats, gbf);

  // y = g @ Wo^T
  gemm_bf16<0, float><<<gB, blk, 0, stream>>>(gbf, Wob, y_out, BB * TT, EE, CC);
}

// Round 8
// 332.916 us; speedup vs baseline: 9.2508x; 1.1519x over previous
//
#include <hip/hip_runtime.h>
#include <hip/hip_bf16.h>
#include <math.h>

#define BB 2
#define TT 2048
#define EE 2048
#define HH 16
#define DD 128
#define CC 2048
#define KCONV 4
#define CHUNK 128
#define NC 16          // TT / CHUNK
#define GN_EPS 1e-5f

typedef __bf16 bf16x8 __attribute__((ext_vector_type(8)));
typedef __bf16 bf16x4 __attribute__((ext_vector_type(4)));
typedef float  f32x4  __attribute__((ext_vector_type(4)));

#define GLD16(gp, lp)                                                          \
  __builtin_amdgcn_global_load_lds(                                            \
      (const __attribute__((address_space(1))) void*)(gp),                     \
      (__attribute__((address_space(3))) void*)(lp), 16, 0, 0)

// swizzled fragment load: row-major [128][128] bf16 tile, 16B-group XOR swizzle
__device__ __forceinline__ bf16x8 ldfrag(const __bf16* buf, int row, int kg)
{
  return *(const bf16x8*)(buf + row * 128 + ((kg ^ (row & 7)) << 3));
}

// ---------------------------------------------------------------------------
// merged f32 -> bf16 conversion for x, Wq|Wk|Wv|Wgate (into Wcat), Wo.
// ---------------------------------------------------------------------------
__global__ __launch_bounds__(256)
void convert_all(const float* __restrict__ x,  const float* __restrict__ Wq,
                 const float* __restrict__ Wk, const float* __restrict__ Wv,
                 const float* __restrict__ Wg, const float* __restrict__ Wo,
                 __bf16* __restrict__ xbf, __bf16* __restrict__ Wcat,
                 __bf16* __restrict__ Wob)
{
  const int i = (blockIdx.x * 256 + threadIdx.x) * 4;
  const int XN = 8388608, WN = 4194304;
  const float* src;
  __bf16* dst;
  int off;
  if (i < XN) { src = x; dst = xbf; off = i; }
  else if (i < XN + 4 * WN) {
    const int j = i - XN;
    const int seg = j >> 22;
    src = seg == 0 ? Wq : seg == 1 ? Wk : seg == 2 ? Wv : Wg;
    dst = Wcat + ((size_t)seg << 22);
    off = j & (WN - 1);
  } else { src = Wo; dst = Wob; off = i - XN - 4 * WN; }
  const float4 v = *(const float4*)(src + off);
  bf16x4 o;
  o[0] = (__bf16)v.x; o[1] = (__bf16)v.y; o[2] = (__bf16)v.z; o[3] = (__bf16)v.w;
  *(bf16x4*)(dst + off) = o;
}

// ---------------------------------------------------------------------------
// beta = sigmoid(x @ Wbeta^T), x fp32 (B*T, E), Wbeta (16, E).
// ---------------------------------------------------------------------------
__global__ __launch_bounds__(256)
void beta_ker(const float* __restrict__ x, const float* __restrict__ Wb,
              float* __restrict__ betab)
{
  __shared__ float wsb[16 * 1024];   // 64 KB
  const int tid = threadIdx.x;
  const int w = tid >> 6, lane = tid & 63;
  const int row = blockIdx.x * 4 + w;           // < B*T = 4096
  const float* xrow = x + (size_t)row * EE;

  float acc[16] = {};
#pragma unroll
  for (int kt = 0; kt < 2; ++kt) {
    __syncthreads();
#pragma unroll
    for (int it = 0; it < 16; ++it) {
      const int i = tid + it * 256;
      const int h = i >> 8, kq = i & 255;
      *(float4*)&wsb[h * 1024 + kq * 4] =
          *(const float4*)(Wb + (size_t)h * EE + kt * 1024 + kq * 4);
    }
    __syncthreads();
#pragma unroll
    for (int j = 0; j < 4; ++j) {
      const int kof = lane * 4 + j * 256;
      const float4 xv = *(const float4*)(xrow + kt * 1024 + kof);
#pragma unroll
      for (int h = 0; h < 16; ++h) {
        const float4 wv = *(const float4*)&wsb[h * 1024 + kof];
        acc[h] += xv.x * wv.x + xv.y * wv.y + xv.z * wv.z + xv.w * wv.w;
      }
    }
  }
#pragma unroll
  for (int h = 0; h < 16; ++h) {
#pragma unroll
    for (int off = 32; off; off >>= 1)
      acc[h] += __shfl_xor(acc[h], off, 64);
  }
#pragma unroll
  for (int h = 0; h < 16; ++h)
    if (lane == h)
      betab[(size_t)row * HH + h] = 1.f / (1.f + expf(-acc[h]));
}

// ---------------------------------------------------------------------------
// 256x256 deep-pipelined bf16 GEMM (QKV+gate merged), K=2048, BK=64.
// 8 waves (2Mx4N). LDS = 3 A-bufs + 2 B-bufs = 160 KiB. ONE barrier per phase.
// Stage slots (hazard-proved): q0: B(t+1,1); q1: A(t+2,0); q2: A(t+2,1);
// q3: B(t+2,0) + vmcnt(6). Tile t+1's last load retires under q3's vmcnt(6).
// ---------------------------------------------------------------------------
__global__ __launch_bounds__(512)
void gemm_big(const __bf16* __restrict__ A, const __bf16* __restrict__ Bm,
              __bf16* __restrict__ o0, __bf16* __restrict__ o1,
              __bf16* __restrict__ o2, __bf16* __restrict__ o3)
{
  __shared__ __attribute__((aligned(16))) unsigned char smem[163840];
  __bf16 (*ldsA)[256 * 64] = (__bf16(*)[256 * 64])smem;             // 3 x 32KB
  __bf16 (*ldsB)[256 * 64] = (__bf16(*)[256 * 64])(smem + 98304);   // 2 x 32KB

  const int tid = threadIdx.x;
  const int w = tid >> 6, l = tid & 63;
  const int wm = w >> 2, wn = w & 3;          // 2 x 4 wave grid
  const int m0 = blockIdx.y * 256, n0 = blockIdx.x * 256;
  const int NT = EE / 64;                     // 32 K-tiles

  const int sr0 = w * 8 + (l >> 3);           // staging dest row, 0..63
  const int skg = l & 7;                      // dest 16B chunk in 128B row
  const int fr = l & 15;
  const int fkg = l >> 4;                     // 0..3

#define STAGE_A(tile, half) do {                                               \
    const int b_ = (tile) % 3;                                                 \
    const int r0_ = sr0;                                                       \
    const int r1_ = 64 + sr0;                                                  \
    GLD16(A + (size_t)(m0 + (half) * 128 + r0_) * 2048 + (tile) * 64           \
              + ((skg ^ (r0_ & 7)) << 3),                                      \
          ldsA[b_] + ((half) * 128 + w * 8) * 64);                             \
    GLD16(A + (size_t)(m0 + (half) * 128 + r1_) * 2048 + (tile) * 64           \
              + ((skg ^ (r1_ & 7)) << 3),                                      \
          ldsA[b_] + ((half) * 128 + 64 + w * 8) * 64);                        \
  } while (0)

#define STAGE_B(tile, half) do {                                               \
    const int b_ = (tile) & 1;                                                 \
    const int r0_ = sr0;                                                       \
    const int r1_ = 64 + sr0;                                                  \
    GLD16(Bm + (size_t)(n0 + (half) * 128 + r0_) * 2048 + (tile) * 64          \
              + ((skg ^ (r0_ & 7)) << 3),                                      \
          ldsB[b_] + ((half) * 128 + w * 8) * 64);                             \
    GLD16(Bm + (size_t)(n0 + (half) * 128 + r1_) * 2048 + (tile) * 64          \
              + ((skg ^ (r1_ & 7)) << 3),                                      \
          ldsB[b_] + ((half) * 128 + 64 + w * 8) * 64);                        \
  } while (0)

#define LDA_FRAG(dst, ab, q, mf, ks) do {                                      \
    const int row_ = wm * 128 + (q) * 32 + (mf) * 16 + fr;                     \
    const int kg_ = (ks) * 4 + fkg;                                            \
    dst = *(const bf16x8*)&ldsA[ab][row_ * 64 + ((kg_ ^ (row_ & 7)) << 3)];    \
  } while (0)
#define LDB_FRAG(dst, bb, nf, ks) do {                                         \
    const int row_ = wn * 64 + (nf) * 16 + fr;                                 \
    const int kg_ = (ks) * 4 + fkg;                                            \
    dst = *(const bf16x8*)&ldsB[bb][row_ * 64 + ((kg_ ^ (row_ & 7)) << 3)];    \
  } while (0)

  f32x4 acc[8][4] = {};

  // prologue: 14 loads; tile 0 resident after vmcnt(6)+barrier.
  STAGE_A(0, 0); STAGE_A(0, 1); STAGE_B(0, 0); STAGE_B(0, 1);
  STAGE_A(1, 0); STAGE_A(1, 1); STAGE_B(1, 0);
  asm volatile("s_waitcnt vmcnt(6)" ::: "memory");
  __builtin_amdgcn_s_barrier();

  for (int t = 0; t < NT; ++t) {
    const int abuf = t % 3;
    const int bbuf = t & 1;
    bf16x8 bfr[4][2];

    // ---- phase q0: all B frags + A quadrant 0; stage B(t+1,1)
    {
#pragma unroll
      for (int nf = 0; nf < 4; ++nf)
#pragma unroll
        for (int ks = 0; ks < 2; ++ks) LDB_FRAG(bfr[nf][ks], bbuf, nf, ks);
      bf16x8 af[2][2];
#pragma unroll
      for (int mf = 0; mf < 2; ++mf)
#pragma unroll
        for (int ks = 0; ks < 2; ++ks) LDA_FRAG(af[mf][ks], abuf, 0, mf, ks);
      if (t + 1 < NT) STAGE_B(t + 1, 1);
      __builtin_amdgcn_s_barrier();
      __builtin_amdgcn_s_setprio(1);
#pragma unroll
      for (int mf = 0; mf < 2; ++mf)
#pragma unroll
        for (int nf = 0; nf < 4; ++nf)
#pragma unroll
          for (int ks = 0; ks < 2; ++ks)
            acc[mf][nf] = __builtin_amdgcn_mfma_f32_16x16x32_bf16(
                af[mf][ks], bfr[nf][ks], acc[mf][nf], 0, 0, 0);
      __builtin_amdgcn_s_setprio(0);
    }

    // ---- phases q1..q3 (one barrier each)
#pragma unroll
    for (int q = 1; q < 4; ++q) {
      bf16x8 af[2][2];
#pragma unroll
      for (int mf = 0; mf < 2; ++mf)
#pragma unroll
        for (int ks = 0; ks < 2; ++ks) LDA_FRAG(af[mf][ks], abuf, q, mf, ks);
      if (q == 1) {
        if (t + 2 < NT) STAGE_A(t + 2, 0);
      } else if (q == 2) {
        if (t + 2 < NT) STAGE_A(t + 2, 1);
      } else {
        if (t + 2 < NT) STAGE_B(t + 2, 0);
        if (t == NT - 2)     asm volatile("s_waitcnt vmcnt(0)" ::: "memory");
        else if (t < NT - 2) asm volatile("s_waitcnt vmcnt(6)" ::: "memory");
      }
      __builtin_amdgcn_s_barrier();
      __builtin_amdgcn_s_setprio(1);
#pragma unroll
      for (int mf = 0; mf < 2; ++mf)
#pragma unroll
        for (int nf = 0; nf < 4; ++nf)
#pragma unroll
          for (int ks = 0; ks < 2; ++ks)
            acc[2 * q + mf][nf] = __builtin_amdgcn_mfma_f32_16x16x32_bf16(
                af[mf][ks], bfr[nf][ks], acc[2 * q + mf][nf], 0, 0, 0);
      __builtin_amdgcn_s_setprio(0);
    }
  }

  // epilogue through LDS: per-wave 128x72 padded tile, coalesced bf16x8 stores
  __syncthreads();
  const int proj = n0 >> 11;
  const int nb = n0 & 2047;
  __bf16* outp = proj == 0 ? o0 : proj == 1 ? o1 : proj == 2 ? o2 : o3;
  __bf16* ep = (__bf16*)smem + (size_t)w * 9216;
  const int crow = (l >> 4) * 4;
#pragma unroll
  for (int mf2 = 0; mf2 < 8; ++mf2)
#pragma unroll
    for (int nf = 0; nf < 4; ++nf)
#pragma unroll
      for (int r = 0; r < 4; ++r) {
        const int row = mf2 * 16 + crow + r;
        float vv = acc[mf2][nf][r];
        if (proj == 3) vv = 1.f / (1.f + expf(-vv));
        ep[row * 72 + nf * 16 + fr] = (__bf16)vv;
      }
#pragma unroll
  for (int it = 0; it < 16; ++it) {
    const int row = it * 8 + (l >> 3);
    const int c8 = (l & 7) * 8;
    const bf16x8 v8 = *(const bf16x8*)&ep[row * 72 + c8];
    *(bf16x8*)(outp + (size_t)(m0 + wm * 128 + row) * 2048 + nb + wn * 64 + c8) = v8;
  }
#undef STAGE_A
#undef STAGE_B
#undef LDA_FRAG
#undef LDB_FRAG
}

// ---------------------------------------------------------------------------
// Wo GEMM, pipelined: BM=128 x BN=256, grid (8,32)=256 blocks (1/CU).
// 8 waves (2Mx4N), per-wave C = 64x64. LDS: 3 A-bufs(16K) + 3 B-bufs(32K)=144K.
// 2 phases/K-tile x 16 MFMA; stage B(t+2)@q0, A(t+2)@q1, vmcnt(6)@q1.
// fp32 output routed through LDS for float4 stores.
// ---------------------------------------------------------------------------
__global__ __launch_bounds__(512)
void gemm_wo(const __bf16* __restrict__ A, const __bf16* __restrict__ Bm,
             float* __restrict__ Cm)
{
  __shared__ __attribute__((aligned(16))) unsigned char smem[147456];
  __bf16 (*ldsA)[128 * 64] = (__bf16(*)[128 * 64])smem;              // 3 x 16KB
  __bf16 (*ldsB)[256 * 64] = (__bf16(*)[256 * 64])(smem + 49152);    // 3 x 32KB

  const int tid = threadIdx.x;
  const int w = tid >> 6, l = tid & 63;
  const int wm = w >> 2, wn = w & 3;
  const int m0 = blockIdx.y * 128, n0 = blockIdx.x * 256;
  const int NT = CC / 64;                     // 32 K-tiles

  const int sr0 = w * 8 + (l >> 3);
  const int skg = l & 7;
  const int fr = l & 15;
  const int fkg = l >> 4;

#define STAGE_AW(tile) do {                                                    \
    const int b_ = (tile) % 3;                                                 \
    const int r0_ = sr0;                                                       \
    const int r1_ = 64 + sr0;                                                  \
    GLD16(A + (size_t)(m0 + r0_) * 2048 + (tile) * 64                          \
              + ((skg ^ (r0_ & 7)) << 3),                                      \
          ldsA[b_] + (w * 8) * 64);                                            \
    GLD16(A + (size_t)(m0 + r1_) * 2048 + (tile) * 64                          \
              + ((skg ^ (r1_ & 7)) << 3),                                      \
          ldsA[b_] + (64 + w * 8) * 64);                                       \
  } while (0)

#define STAGE_BW(tile, half) do {                                              \
    const int b_ = (tile) % 3;                                                 \
    const int r0_ = sr0;                                                       \
    const int r1_ = 64 + sr0;                                                  \
    GLD16(Bm + (size_t)(n0 + (half) * 128 + r0_) * 2048 + (tile) * 64          \
              + ((skg ^ (r0_ & 7)) << 3),                                      \
          ldsB[b_] + ((half) * 128 + w * 8) * 64);                             \
    GLD16(Bm + (size_t)(n0 + (half) * 128 + r1_) * 2048 + (tile) * 64          \
              + ((skg ^ (r1_ & 7)) << 3),                                      \
          ldsB[b_] + ((half) * 128 + 64 + w * 8) * 64);                        \
  } while (0)

#define LDA_FRAGW(dst, ab, mf, ks) do {                                        \
    const int row_ = wm * 64 + (mf) * 16 + fr;                                 \
    const int kg_ = (ks) * 4 + fkg;                                            \
    dst = *(const bf16x8*)&ldsA[ab][row_ * 64 + ((kg_ ^ (row_ & 7)) << 3)];    \
  } while (0)
#define LDB_FRAGW(dst, bb, nf, ks) do {                                        \
    const int row_ = wn * 64 + (nf) * 16 + fr;                                 \
    const int kg_ = (ks) * 4 + fkg;                                            \
    dst = *(const bf16x8*)&ldsB[bb][row_ * 64 + ((kg_ ^ (row_ & 7)) << 3)];    \
  } while (0)

  f32x4 acc[4][4] = {};

  // prologue: 12 loads; tile 0 = first 6.
  STAGE_BW(0, 0); STAGE_BW(0, 1); STAGE_AW(0);
  STAGE_BW(1, 0); STAGE_BW(1, 1); STAGE_AW(1);
  asm volatile("s_waitcnt vmcnt(6)" ::: "memory");
  __builtin_amdgcn_s_barrier();

  for (int t = 0; t < NT; ++t) {
    const int buf = t % 3;
    bf16x8 bfr[4][2];
    bf16x8 af[2][2];

    // ---- phase q0: B frags + A mf0-1; stage B(t+2, both halves)
#pragma unroll
    for (int nf = 0; nf < 4; ++nf)
#pragma unroll
      for (int ks = 0; ks < 2; ++ks) LDB_FRAGW(bfr[nf][ks], buf, nf, ks);
#pragma unroll
    for (int mf = 0; mf < 2; ++mf)
#pragma unroll
      for (int ks = 0; ks < 2; ++ks) LDA_FRAGW(af[mf][ks], buf, mf, ks);
    if (t + 2 < NT) { STAGE_BW(t + 2, 0); STAGE_BW(t + 2, 1); }
    __builtin_amdgcn_s_barrier();
    __builtin_amdgcn_s_setprio(1);
#pragma unroll
    for (int mf = 0; mf < 2; ++mf)
#pragma unroll
      for (int nf = 0; nf < 4; ++nf)
#pragma unroll
        for (int ks = 0; ks < 2; ++ks)
          acc[mf][nf] = __builtin_amdgcn_mfma_f32_16x16x32_bf16(
              af[mf][ks], bfr[nf][ks], acc[mf][nf], 0, 0, 0);
    __builtin_amdgcn_s_setprio(0);

    // ---- phase q1: A mf2-3; stage A(t+2); vmcnt
#pragma unroll
    for (int mf = 0; mf < 2; ++mf)
#pragma unroll
      for (int ks = 0; ks < 2; ++ks) LDA_FRAGW(af[mf][ks], buf, mf + 2, ks);
    if (t + 2 < NT) STAGE_AW(t + 2);
    if (t == NT - 2)     asm volatile("s_waitcnt vmcnt(0)" ::: "memory");
    else if (t < NT - 2) asm volatile("s_waitcnt vmcnt(6)" ::: "memory");
    __builtin_amdgcn_s_barrier();
    __builtin_amdgcn_s_setprio(1);
#pragma unroll
    for (int mf = 0; mf < 2; ++mf)
#pragma unroll
      for (int nf = 0; nf < 4; ++nf)
#pragma unroll
        for (int ks = 0; ks < 2; ++ks)
          acc[mf + 2][nf] = __builtin_amdgcn_mfma_f32_16x16x32_bf16(
              af[mf][ks], bfr[nf][ks], acc[mf + 2][nf], 0, 0, 0);
    __builtin_amdgcn_s_setprio(0);
  }

  // epilogue: per-wave 64x68 f32 tile in LDS -> float4 stores
  __syncthreads();
  float* ep = (float*)smem + (size_t)w * (64 * 68);
  const int crow = (l >> 4) * 4;
#pragma unroll
  for (int mf = 0; mf < 4; ++mf)
#pragma unroll
    for (int nf = 0; nf < 4; ++nf)
#pragma unroll
      for (int r = 0; r < 4; ++r)
        ep[(mf * 16 + crow + r) * 68 + nf * 16 + fr] = acc[mf][nf][r];
#pragma unroll
  for (int it = 0; it < 16; ++it) {
    const int row = it * 4 + (l >> 4);
    const int c4 = (l & 15) * 4;
    const float4 v4 = *(const float4*)&ep[row * 68 + c4];
    *(float4*)(Cm + (size_t)(m0 + wm * 64 + row) * 2048 + n0 + wn * 64 + c4) = v4;
  }
#undef STAGE_AW
#undef STAGE_BW
#undef LDA_FRAGW
#undef LDB_FRAGW
}

// ---------------------------------------------------------------------------
// fused causal dwconv(K=4)+silu + (k,v) transpose.
// grid (TT/64, CC/64, 3*BB): which = z/BB (0:q 1:k 2:v), b = z%BB.
// q: row-major only; k: row-major + (B,H,D,T); v: (B,H,D,T) only.
// ---------------------------------------------------------------------------
__global__ __launch_bounds__(256)
void conv_tr(const __bf16* __restrict__ u_q, const __bf16* __restrict__ u_k,
             const __bf16* __restrict__ u_v, const float* __restrict__ wq,
             const float* __restrict__ wk, const float* __restrict__ wv,
             __bf16* __restrict__ qbf, __bf16* __restrict__ kbf,
             __bf16* __restrict__ kT, __bf16* __restrict__ vT, float qscale)
{
  const int t0 = blockIdx.x * 64, c0 = blockIdx.y * 64;
  const int which = blockIdx.z / BB, b = blockIdx.z % BB;
  const __bf16* u = which == 0 ? u_q : which == 1 ? u_k : u_v;
  const float* wc = which == 0 ? wq : which == 1 ? wk : wv;
  const float scale = which == 0 ? qscale : 1.f;
  const int tid = threadIdx.x;
  __shared__ __attribute__((aligned(16))) __bf16 tile[64][72];

#pragma unroll
  for (int it = 0; it < 2; ++it) {
    const int idx = tid + it * 256;
    const int tl = idx >> 3, g = idx & 7;
    const int t = t0 + tl;
    const int c8 = c0 + g * 8;
    const size_t base = ((size_t)(b * TT + t)) * CC + c8;
    const bf16x8 z = {};
    const bf16x8 uu0 = *(const bf16x8*)(u + base);
    const bf16x8 uu1 = (t >= 1) ? *(const bf16x8*)(u + base - CC)     : z;
    const bf16x8 uu2 = (t >= 2) ? *(const bf16x8*)(u + base - 2 * CC) : z;
    const bf16x8 uu3 = (t >= 3) ? *(const bf16x8*)(u + base - 3 * CC) : z;
    bf16x8 o;
#pragma unroll
    for (int jj = 0; jj < 8; ++jj) {
      const float4 wv4 = *(const float4*)(wc + (size_t)(c8 + jj) * 4);
      const float vv = wv4.x * (float)uu3[jj] + wv4.y * (float)uu2[jj]
                     + wv4.z * (float)uu1[jj] + wv4.w * (float)uu0[jj];
      o[jj] = (__bf16)(vv / (1.f + expf(-vv)) * scale);
    }
    if (which == 0) *(bf16x8*)(qbf + base) = o;
    if (which == 1) *(bf16x8*)(kbf + base) = o;
    if (which >= 1) *(bf16x8*)&tile[tl][g * 8] = o;
  }
  if (which >= 1) {
    __syncthreads();
    const int h = c0 >> 7, d0 = c0 & 127;
    const int bh = b * HH + h;
    __bf16* dst = (which == 1) ? kT : vT;
#pragma unroll
    for (int it = 0; it < 2; ++it) {
      const int idx = tid + it * 256;
      const int dl = idx >> 3, g = idx & 7;
      bf16x8 o;
#pragma unroll
      for (int jj = 0; jj < 8; ++jj) o[jj] = tile[g * 8 + jj][dl];
      *(bf16x8*)(dst + ((size_t)(bh * DD + d0 + dl)) * TT + t0 + g * 8) = o;
    }
  }
}

// ---------------------------------------------------------------------------
// fp32 128x128 transpose per bh. grid (2,2,BB*HH).
// ---------------------------------------------------------------------------
__global__ __launch_bounds__(256)
void tr_f32(const float* __restrict__ in, float* __restrict__ out)
{
  const int r0 = blockIdx.x * 64, c0 = blockIdx.y * 64;
  const int bh = blockIdx.z;
  const int tid = threadIdx.x;
  __shared__ float tile[64][65];

#pragma unroll
  for (int it = 0; it < 4; ++it) {
    const int idx = tid + it * 256;
    const int rl = idx >> 4, g = idx & 15;
    const float4 v = *(const float4*)(in + (size_t)bh * 16384 + (r0 + rl) * 128 + c0 + g * 4);
    tile[rl][g * 4 + 0] = v.x; tile[rl][g * 4 + 1] = v.y;
    tile[rl][g * 4 + 2] = v.z; tile[rl][g * 4 + 3] = v.w;
  }
  __syncthreads();
#pragma unroll
  for (int it = 0; it < 4; ++it) {
    const int idx = tid + it * 256;
    const int cl = idx >> 4, g = idx & 15;
    float4 o;
    o.x = tile[g * 4 + 0][cl]; o.y = tile[g * 4 + 1][cl];
    o.z = tile[g * 4 + 2][cl]; o.w = tile[g * 4 + 3][cl];
    *(float4*)(out + (size_t)bh * 16384 + (c0 + cl) * 128 + r0 + g * 4) = o;
  }
}

// ---------------------------------------------------------------------------
// Phase A (MFMA): contribT[e][d] = sum_s (w_s k_s[d]) v_s[e];  decay out.
// ---------------------------------------------------------------------------
__global__ __launch_bounds__(256)
void phaseA_mfma(const __bf16* __restrict__ kT, const __bf16* __restrict__ vT,
                 const float* __restrict__ beta, float* __restrict__ contribT,
                 float* __restrict__ decay)
{
  const int c = blockIdx.x, h = blockIdx.y, b = blockIdx.z;
  const int bh = b * HH + h;
  const int tid = threadIdx.x;
  const int w = tid >> 6, lane = tid & 63;
  const int wm = w >> 1, wn = w & 1;

  __shared__ __attribute__((aligned(16))) __bf16 bufVT[128 * 128];
  __shared__ __attribute__((aligned(16))) __bf16 bufKW[128 * 128];
  __shared__ float lc[CHUNK], bsh[CHUNK], wgt[CHUNK];

  {
    const __bf16* vbase = vT + ((size_t)bh * DD) * TT + c * CHUNK;
#pragma unroll
    for (int jj = 0; jj < 8; ++jj) {
      const int row = w * 32 + jj * 4 + (lane >> 4);
      const int g = lane & 15;
      GLD16(vbase + (size_t)row * TT + ((g ^ (row & 7)) << 3),
            bufVT + (w * 32 + jj * 4) * 128);
    }
  }

  if (tid < CHUNK) {
    const float bv = beta[(size_t)(b * TT + c * CHUNK + tid) * HH + h];
    bsh[tid] = bv;
    lc[tid] = log1pf(-bv);
  }
  __syncthreads();
  for (int off = 1; off < CHUNK; off <<= 1) {
    float add = 0.f;
    if (tid < CHUNK && tid >= off) add = lc[tid - off];
    __syncthreads();
    if (tid < CHUNK) lc[tid] += add;
    __syncthreads();
  }
  const float lend = lc[CHUNK - 1];
  if (tid < CHUNK) wgt[tid] = bsh[tid] * expf(lend - lc[tid]);
  if (tid == 0) decay[(size_t)bh * NC + c] = expf(lend);
  __syncthreads();

  {
    const __bf16* kbase = kT + ((size_t)bh * DD) * TT + c * CHUNK;
#pragma unroll
    for (int it = 0; it < 8; ++it) {
      const int idx = tid + it * 256;
      const int d = idx >> 4, g = idx & 15;
      const bf16x8 kv = *(const bf16x8*)(kbase + (size_t)d * TT + g * 8);
      bf16x8 o;
#pragma unroll
      for (int jj = 0; jj < 8; ++jj)
        o[jj] = (__bf16)((float)kv[jj] * wgt[g * 8 + jj]);
      *(bf16x8*)(bufKW + d * 128 + ((g ^ (d & 7)) << 3)) = o;
    }
  }
  asm volatile("s_waitcnt vmcnt(0)" ::: "memory");
  __syncthreads();

  f32x4 acc[4][4] = {};
#pragma unroll
  for (int ks = 0; ks < 4; ++ks) {
    bf16x8 a[4], bq[4];
    const int kg = ks * 4 + (lane >> 4);
#pragma unroll
    for (int f = 0; f < 4; ++f) a[f]  = ldfrag(bufVT, wm * 64 + f * 16 + (lane & 15), kg);
#pragma unroll
    for (int f = 0; f < 4; ++f) bq[f] = ldfrag(bufKW, wn * 64 + f * 16 + (lane & 15), kg);
#pragma unroll
    for (int i = 0; i < 4; ++i)
#pragma unroll
      for (int j = 0; j < 4; ++j)
        acc[i][j] = __builtin_amdgcn_mfma_f32_16x16x32_bf16(a[i], bq[j], acc[i][j], 0, 0, 0);
  }

  float* cp = contribT + ((size_t)(bh * NC + c) << 14);
  const int crow = (lane >> 4) * 4;
#pragma unroll
  for (int i = 0; i < 4; ++i)
#pragma unroll
    for (int j = 0; j < 4; ++j) {
      const int dd = wn * 64 + j * 16 + (lane & 15);
#pragma unroll
      for (int r = 0; r < 4; ++r) {
        const int e = wm * 64 + i * 16 + crow + r;
        cp[(size_t)e * 128 + dd] = acc[i][j][r];
      }
    }
}

// ---------------------------------------------------------------------------
// Phase B (transposed space).
// ---------------------------------------------------------------------------
__global__ __launch_bounds__(256)
void phaseB_T(const float* __restrict__ state0T, const float* __restrict__ contribT,
              const float* __restrict__ decay, __bf16* __restrict__ statesT,
              float* __restrict__ stateOutT)
{
  const size_t gid = (size_t)blockIdx.x * 256 + threadIdx.x;
  const int bh = (int)(gid >> 14);
  float s = state0T[gid];
  const float* dc = decay + (size_t)bh * NC;
  const int ed = (int)(gid & 16383);
#pragma unroll
  for (int c = 0; c < NC; ++c) {
    const size_t off = ((size_t)(bh * NC + c) << 14) + ed;
    statesT[off] = (__bf16)s;
    s = fmaf(dc[c], s, contribT[off]);
  }
  stateOutT[gid] = s;
}

// ---------------------------------------------------------------------------
// Phase C (MFMA) + fused GroupNorm partial stats.
// ---------------------------------------------------------------------------
__global__ __launch_bounds__(256)
void phaseC_mfma(const __bf16* __restrict__ qb, const __bf16* __restrict__ kb,
                 const __bf16* __restrict__ vT, const float* __restrict__ beta,
                 const __bf16* __restrict__ statesT, float* __restrict__ att,
                 float* __restrict__ partials)
{
  const int c = blockIdx.x, h = blockIdx.y, b = blockIdx.z;
  const int bh = b * HH + h;
  const int tid = threadIdx.x;
  const int w = tid >> 6, lane = tid & 63;
  const int wm = w >> 1, wn = w & 1;

  __shared__ __attribute__((aligned(16))) __bf16 bufQ[128 * 128];
  __shared__ __attribute__((aligned(16))) __bf16 bufB[128 * 128];
  __shared__ float lc[CHUNK], bsh[CHUNK];
  __shared__ float s1[256], s2[256];

  {
    const __bf16* qbase = qb + ((size_t)(b * TT + c * CHUNK)) * CC + h * DD;
    const __bf16* kbase = kb + ((size_t)(b * TT + c * CHUNK)) * CC + h * DD;
#pragma unroll
    for (int jj = 0; jj < 8; ++jj) {
      const int row = w * 32 + jj * 4 + (lane >> 4);
      const int g = lane & 15;
      GLD16(qbase + (size_t)row * CC + ((g ^ (row & 7)) << 3),
            bufQ + (w * 32 + jj * 4) * 128);
      GLD16(kbase + (size_t)row * CC + ((g ^ (row & 7)) << 3),
            bufB + (w * 32 + jj * 4) * 128);
    }
  }

  if (tid < CHUNK) {
    const float bv = beta[(size_t)(b * TT + c * CHUNK + tid) * HH + h];
    bsh[tid] = bv;
    lc[tid] = log1pf(-bv);
  }
  __syncthreads();
  for (int off = 1; off < CHUNK; off <<= 1) {
    float add = 0.f;
    if (tid < CHUNK && tid >= off) add = lc[tid - off];
    __syncthreads();
    if (tid < CHUNK) lc[tid] += add;
    __syncthreads();
  }

  asm volatile("s_waitcnt vmcnt(0)" ::: "memory");
  __syncthreads();

  // S = Q K^T
  f32x4 accS[4][4] = {};
#pragma unroll
  for (int ks = 0; ks < 4; ++ks) {
    bf16x8 a[4], bq[4];
    const int kg = ks * 4 + (lane >> 4);
#pragma unroll
    for (int f = 0; f < 4; ++f) a[f]  = ldfrag(bufQ, wm * 64 + f * 16 + (lane & 15), kg);
#pragma unroll
    for (int f = 0; f < 4; ++f) bq[f] = ldfrag(bufB, wn * 64 + f * 16 + (lane & 15), kg);
#pragma unroll
    for (int i = 0; i < 4; ++i)
#pragma unroll
      for (int j = 0; j < 4; ++j)
        accS[i][j] = __builtin_amdgcn_mfma_f32_16x16x32_bf16(a[i], bq[j], accS[i][j], 0, 0, 0);
  }

  __syncthreads();
  {
    const __bf16* sbase = statesT + ((size_t)(bh * NC + c) << 14);
#pragma unroll
    for (int jj = 0; jj < 8; ++jj) {
      const int row = w * 32 + jj * 4 + (lane >> 4);
      const int g = lane & 15;
      GLD16(sbase + (size_t)row * 128 + ((g ^ (row & 7)) << 3),
            bufB + (w * 32 + jj * 4) * 128);
    }
  }
  asm volatile("s_waitcnt vmcnt(0)" ::: "memory");
  __syncthreads();

  // accO = Q S0T, scaled by e^{lc_t}
  f32x4 accO[4][4] = {};
#pragma unroll
  for (int ks = 0; ks < 4; ++ks) {
    bf16x8 a[4], bq[4];
    const int kg = ks * 4 + (lane >> 4);
#pragma unroll
    for (int f = 0; f < 4; ++f) a[f]  = ldfrag(bufQ, wm * 64 + f * 16 + (lane & 15), kg);
#pragma unroll
    for (int f = 0; f < 4; ++f) bq[f] = ldfrag(bufB, wn * 64 + f * 16 + (lane & 15), kg);
#pragma unroll
    for (int i = 0; i < 4; ++i)
#pragma unroll
      for (int j = 0; j < 4; ++j)
        accO[i][j] = __builtin_amdgcn_mfma_f32_16x16x32_bf16(a[i], bq[j], accO[i][j], 0, 0, 0);
  }
  const int crow = (lane >> 4) * 4;
#pragma unroll
  for (int i = 0; i < 4; ++i)
#pragma unroll
    for (int r = 0; r < 4; ++r) {
      const float el = expf(lc[wm * 64 + i * 16 + crow + r]);
#pragma unroll
      for (int j = 0; j < 4; ++j) accO[i][j][r] *= el;
    }

  __syncthreads();
  {
    const __bf16* vbase = vT + ((size_t)bh * DD) * TT + c * CHUNK;
#pragma unroll
    for (int jj = 0; jj < 8; ++jj) {
      const int row = w * 32 + jj * 4 + (lane >> 4);
      const int g = lane & 15;
      GLD16(vbase + (size_t)row * TT + ((g ^ (row & 7)) << 3),
            bufB + (w * 32 + jj * 4) * 128);
    }
  }
  {
    float lcs[4], bss[4];
#pragma unroll
    for (int j = 0; j < 4; ++j) {
      const int s = wn * 64 + j * 16 + (lane & 15);
      lcs[j] = lc[s]; bss[j] = bsh[s];
    }
#pragma unroll
    for (int i = 0; i < 4; ++i)
#pragma unroll
      for (int r = 0; r < 4; ++r) {
        const int t = wm * 64 + i * 16 + crow + r;
        const float lct = lc[t];
#pragma unroll
        for (int j = 0; j < 4; ++j) {
          const int s = wn * 64 + j * 16 + (lane & 15);
          float p = 0.f;
          if (s <= t) p = accS[i][j][r] * bss[j] * expf(lct - lcs[j]);
          bufQ[t * 128 + (((s >> 3) ^ (t & 7)) << 3) + (s & 7)] = (__bf16)p;
        }
      }
  }
  asm volatile("s_waitcnt vmcnt(0)" ::: "memory");
  __syncthreads();

  // accO += P V^T
#pragma unroll
  for (int ks = 0; ks < 4; ++ks) {
    bf16x8 a[4], bq[4];
    const int kg = ks * 4 + (lane >> 4);
#pragma unroll
    for (int f = 0; f < 4; ++f) a[f]  = ldfrag(bufQ, wm * 64 + f * 16 + (lane & 15), kg);
#pragma unroll
    for (int f = 0; f < 4; ++f) bq[f] = ldfrag(bufB, wn * 64 + f * 16 + (lane & 15), kg);
#pragma unroll
    for (int i = 0; i < 4; ++i)
#pragma unroll
      for (int j = 0; j < 4; ++j)
        accO[i][j] = __builtin_amdgcn_mfma_f32_16x16x32_bf16(a[i], bq[j], accO[i][j], 0, 0, 0);
  }

  // epilogue: store att + accumulate GN partial stats
  float lsum = 0.f, lsq = 0.f;
  float* obase = att + ((size_t)(b * TT + c * CHUNK)) * CC + h * DD;
#pragma unroll
  for (int i = 0; i < 4; ++i)
#pragma unroll
    for (int j = 0; j < 4; ++j) {
      const int e = wn * 64 + j * 16 + (lane & 15);
#pragma unroll
      for (int r = 0; r < 4; ++r) {
        const int t = wm * 64 + i * 16 + crow + r;
        const float vv = accO[i][j][r];
        obase[(size_t)t * CC + e] = vv;
        lsum += vv;
        lsq  += vv * vv;
      }
    }
  s1[tid] = lsum; s2[tid] = lsq;
  __syncthreads();
  for (int off = 128; off; off >>= 1) {
    if (tid < off) { s1[tid] += s1[tid + off]; s2[tid] += s2[tid + off]; }
    __syncthreads();
  }
  if (tid == 0) {
    partials[(size_t)(bh * NC + c) * 2]     = s1[0];
    partials[(size_t)(bh * NC + c) * 2 + 1] = s2[0];
  }
}

// ---------------------------------------------------------------------------
// combine GN partials -> stats. grid (BB*HH), 64 threads.
// ---------------------------------------------------------------------------
__global__ __launch_bounds__(64)
void gn_combine(const float* __restrict__ partials, float* __restrict__ stats)
{
  const int bh = blockIdx.x;
  const int lane = threadIdx.x;
  float s = 0.f, q = 0.f;
  if (lane < NC) {
    s = partials[(size_t)(bh * NC + lane) * 2];
    q = partials[(size_t)(bh * NC + lane) * 2 + 1];
  }
#pragma unroll
  for (int off = 8; off; off >>= 1) {
    s += __shfl_xor(s, off, 64);
    q += __shfl_xor(q, off, 64);
  }
  if (lane == 0) {
    const float n = (float)(TT * DD);
    const float mean = s / n;
    const float var = q / n - mean * mean;
    stats[bh * 2] = mean;
    stats[bh * 2 + 1] = rsqrtf(var + GN_EPS);
  }
}

// ---------------------------------------------------------------------------
// normalize + gate (bf16 gate) -> bf16.
// ---------------------------------------------------------------------------
__global__ __launch_bounds__(256)
void norm_gate(const float* __restrict__ att, const __bf16* __restrict__ gate,
               const float* __restrict__ stats, __bf16* __restrict__ g)
{
  const size_t gid = ((size_t)blockIdx.x * 256 + threadIdx.x) * 4;
  if (gid >= (size_t)BB * TT * CC) return;
  const int cpos = (int)(gid % CC);
  const int b = (int)(gid / ((size_t)TT * CC));
  const int bh = b * HH + (cpos >> 7);
  const float mean = stats[bh * 2], rstd = stats[bh * 2 + 1];
  const float4 a = *(const float4*)(att + gid);
  const bf16x4 gt = *(const bf16x4*)(gate + gid);
  bf16x4 o;
  o[0] = (__bf16)((a.x - mean) * rstd * (float)gt[0]);
  o[1] = (__bf16)((a.y - mean) * rstd * (float)gt[1]);
  o[2] = (__bf16)((a.z - mean) * rstd * (float)gt[2]);
  o[3] = (__bf16)((a.w - mean) * rstd * (float)gt[3]);
  *(bf16x4*)(g + gid) = o;
}

// ---------------------------------------------------------------------------
extern "C" void kernel_launch(void* const* d_in, const int* in_sizes, int n_in,
                              void* d_out, int out_size, void* d_ws, size_t ws_size,
                              hipStream_t stream)
{
  const float* x      = (const float*)d_in[0];
  const float* st0    = (const float*)d_in[1];
  const float* Wq     = (const float*)d_in[2];
  const float* Wk     = (const float*)d_in[3];
  const float* Wv     = (const float*)d_in[4];
  const float* Wbeta  = (const float*)d_in[5];
  const float* Wgate  = (const float*)d_in[6];
  const float* Wo     = (const float*)d_in[7];
  const float* wqc    = (const float*)d_in[8];
  const float* wkc    = (const float*)d_in[9];
  const float* wvc    = (const float*)d_in[10];

  float* ws = (float*)d_ws;
  __bf16* qbf  = (__bf16*)(ws + 0);           // 8.4M bf16
  __bf16* kbf  = (__bf16*)(ws + 4194304);     // 8.4M bf16
  __bf16* u_v  = (__bf16*)(ws + 8388608);     // pre-act v; -> statesT after conv
  __bf16* statesT = (__bf16*)(ws + 8388608);  // (phaseB; u_v dead by then)
  __bf16* kT   = (__bf16*)(ws + 12582912);    // -> gbf after phaseC
  __bf16* gbf  = (__bf16*)(ws + 12582912);
  __bf16* vT   = (__bf16*)(ws + 16777216);
  __bf16* xbf  = (__bf16*)(ws + 20971520);    // dead after gemm_big
  float* contribT = ws + 20971520;            // 8.4M f, overlays xbf + Wcat[0:4.2M]
  __bf16* Wcat = (__bf16*)(ws + 25165824);    // 16.8M bf16 (8192x2048), dead after gemm_big
  __bf16* gatebuf = (__bf16*)(ws + 33554432); // 8.4M bf16, alive GEMM -> norm_gate
  float* betab    = ws + 37748736;            // 65536
  float* decay    = ws + 37814272;            // 512
  float* stats    = ws + 37814784;            // 64
  float* partials = ws + 37814848;            // 1024
  float* state0T  = ws + 37815872;            // 524288
  float* stateOutT= ws + 38340160;            // 524288
  __bf16* Wob  = (__bf16*)(ws + 38864448);    // 4.2M bf16 -> end 40961536 f

  float* y_out  = (float*)d_out;
  float* st_out = (float*)d_out + (size_t)BB * TT * EE;
  __bf16* u_q = (__bf16*)d_out;               // bf16 [0, 8388608)
  __bf16* u_k = (__bf16*)d_out + 8388608;     // bf16 [8388608, 16777216)
  float* att = y_out;

  const dim3 blk(256);
  const dim3 gBig(8192 / 256, (BB * TT) / 256);    // 32 x 16 = 512 blocks
  const dim3 gWo(EE / 256, (BB * TT) / 128);       // 8 x 32 = 256 blocks
  const dim3 gConv(TT / 64, CC / 64, 3 * BB);      // 32 x 32 x 6
  const dim3 gTrS(2, 2, BB * HH);
  const dim3 gScan(NC, HH, BB);
  const float qscale = 0.08838834764831845f;

  // all f32->bf16 conversions in one launch
  convert_all<<<dim3(28672), blk, 0, stream>>>(x, Wq, Wk, Wv, Wgate, Wo,
                                               xbf, Wcat, Wob);

  // beta (fp32)
  beta_ker<<<dim3((BB * TT) / 4), blk, 0, stream>>>(x, Wbeta, betab);

  // merged QKV+gate projection (256^2 pipelined, one barrier/phase)
  gemm_big<<<gBig, dim3(512), 0, stream>>>(xbf, Wcat, u_q, u_k, u_v, gatebuf);

  // conv/silu + k,v transposes, fused
  conv_tr<<<gConv, blk, 0, stream>>>(u_q, u_k, u_v, wqc, wkc, wvc,
                                     qbf, kbf, kT, vT, qscale);

  // state0 transpose -> [bh][e][d]
  tr_f32<<<gTrS, blk, 0, stream>>>(st0, state0T);

  // chunked delta scan (MFMA)
  phaseA_mfma<<<gScan, blk, 0, stream>>>(kT, vT, betab, contribT, decay);
  phaseB_T<<<dim3((BB * HH * DD * DD) / 256), blk, 0, stream>>>(state0T, contribT, decay, statesT, stateOutT);
  tr_f32<<<gTrS, blk, 0, stream>>>(stateOutT, st_out);
  phaseC_mfma<<<gScan, blk, 0, stream>>>(qbf, kbf, vT, betab, statesT, att, partials);

  // groupnorm combine + normalize*gate -> bf16
  gn_combine<<<dim3(BB * HH), dim3(64), 0, stream>>>(partials, stats);
  norm_gate<<<dim3((BB * TT * CC) / (256 * 4)), blk, 0, stream>>>(att, gatebuf, stats, gbf);

  // y = g @ Wo^T (pipelined 128x256 structure, 256 blocks)
  gemm_wo<<<gWo, dim3(512), 0, stream>>>(gbf, Wob, y_out);
}